// Round 5
// baseline (867.783 us; speedup 1.0000x reference)
//
#include <hip/hip_runtime.h>
#include <hip/hip_bf16.h>

// Problem dims
#define Bn 2
#define Tn 4
#define NCc 3
#define NKc 16
#define Hc 180
#define Wc 320
#define HWc (Hc * Wc)          // 57600
#define NPIX (Bn * HWc)        // 115200
#define CIN_LSTM 19            // NC + NK
#define GATES 64               // 4*NK
#define CIN_D 64               // T*NK
#define TAPS_L (CIN_LSTM * 9)  // 171
#define TAPS_D (CIN_D * 9)     // 576
#define TAPS_O (NKc * 9)       // 144

typedef __hip_bfloat16 bf16;

__device__ __forceinline__ float getv(const float* p, long i) { return p[i]; }
__device__ __forceinline__ float getv(const bf16* p, long i) {
    unsigned int u = ((unsigned int)((const unsigned short*)p)[i]) << 16;
    return __uint_as_float(u);
}
__device__ __forceinline__ void putv(float* p, long i, float v) { p[i] = v; }
__device__ __forceinline__ void putv(bf16* p, long i, float v) { p[i] = __float2bfloat16(v); }
__device__ __forceinline__ float sigm(float x) { return 1.0f / (1.0f + __expf(-x)); }
__device__ __forceinline__ float tanh_(float x) { return 1.0f - 2.0f / (__expf(2.0f * x) + 1.0f); }

__device__ __forceinline__ void load4(const float* row, int x0, float* d) {
    const float4 v = *(const float4*)(row + x0);
    d[0] = v.x; d[1] = v.y; d[2] = v.z; d[3] = v.w;
}
__device__ __forceinline__ void load4(const bf16* row, int x0, float* d) {
    ushort4 u = *(const ushort4*)((const unsigned short*)row + x0);
    d[0] = __uint_as_float(((unsigned int)u.x) << 16);
    d[1] = __uint_as_float(((unsigned int)u.y) << 16);
    d[2] = __uint_as_float(((unsigned int)u.z) << 16);
    d[3] = __uint_as_float(((unsigned int)u.w) << 16);
}

// ---------------------------------------------------------------------------
// XCD-aware bijective chunked swizzle (T1, m204 formula). Proven R17:
// k_offmod FETCH 85 -> 15.4 MB. Keep everywhere.
// ---------------------------------------------------------------------------
__device__ __forceinline__ int xcd_chunked(int i, int nwg) {
    int q = nwg >> 3, r = nwg & 7;
    int xcd = i & 7, idx = i >> 3;
    return (xcd < r ? xcd * (q + 1) : r * (q + 1) + (xcd - r) * q) + idx;
}

// ---------------------------------------------------------------------------
// Dtype probe (bf16 vs float32 inputs) -> flag in d_ws.
// ---------------------------------------------------------------------------
__global__ void __launch_bounds__(256) k_detect(const void* lstm_w_raw, int* flag)
{
    __shared__ int bad;
    if (threadIdx.x == 0) bad = 0;
    __syncthreads();
    const unsigned short* u = (const unsigned short*)lstm_w_raw;
    int local = 0;
    for (int i = threadIdx.x; i < GATES * TAPS_L; i += 256) {
        unsigned int f32 = ((unsigned int)u[i]) << 16;
        float v = __uint_as_float(f32);
        if (!(fabsf(v) <= 64.0f)) local = 1;
    }
    if (local) atomicOr(&bad, 1);
    __syncthreads();
    if (threadIdx.x == 0) flag[0] = bad ? 0 : 1;
}

// ---------------------------------------------------------------------------
// ConvLSTM step (R13 body + R17 swizzle).  ROUND-18: __launch_bounds__(256,3)
// — LDS (43.8 KB) caps residency at 3 blocks/CU anyway; the default compiler
// heuristic allocated ~52 VGPRs chasing unobtainable occupancy, serializing
// the 12 row-loads per cin into load-wait-use chains (the ~90% stall).
// 3 waves/EU -> ~168-VGPR budget lets the scheduler batch loads in flight.
// ---------------------------------------------------------------------------
template <typename S>
__device__ __forceinline__ void conv_plane2r(
    const S* __restrict__ src, int cin, int y0, int x0, int kc,
    const float* __restrict__ sw, float (&acc)[2][4][4])
{
    float xs[4][6];  // rows y0-1 .. y0+2
#pragma unroll
    for (int r = 0; r < 4; r++) {
        int yy = y0 - 1 + r;
        if (yy >= 0 && yy < Hc) {
            const S* row = src + (long)yy * Wc;
            xs[r][0] = (x0 > 0) ? getv(row, x0 - 1) : 0.0f;
            load4(row, x0, &xs[r][1]);
            xs[r][5] = (x0 + 4 < Wc) ? getv(row, x0 + 4) : 0.0f;
        } else {
#pragma unroll
            for (int j = 0; j < 6; j++) xs[r][j] = 0.0f;
        }
    }
#pragma unroll
    for (int ky = 0; ky < 3; ky++) {
#pragma unroll
        for (int kx = 0; kx < 3; kx++) {
            int tap = (cin * 3 + ky) * 3 + kx;
            const float4 wq = *(const float4*)&sw[(tap * 16 + kc) * 4];
#pragma unroll
            for (int px = 0; px < 4; px++) {
                float v0 = xs[ky][px + kx];      // output row y0
                float v1 = xs[ky + 1][px + kx];  // output row y0+1
                acc[0][0][px] += wq.x * v0;  acc[1][0][px] += wq.x * v1;
                acc[0][1][px] += wq.y * v0;  acc[1][1][px] += wq.y * v1;
                acc[0][2][px] += wq.z * v0;  acc[1][2][px] += wq.z * v1;
                acc[0][3][px] += wq.w * v0;  acc[1][3][px] += wq.w * v1;
            }
        }
    }
}

template <typename T>
__device__ __forceinline__ void lstm2r_body(
    const T* __restrict__ X, const T* __restrict__ lstm_w, const T* __restrict__ lstm_b,
    const T* __restrict__ Wci, const T* __restrict__ Wcf, const T* __restrict__ Wco,
    float* __restrict__ c_buf, float* __restrict__ xcat, int t,
    float* sw, float* sb)
{
    for (int i = threadIdx.x; i < GATES * TAPS_L; i += 256) {
        int co = i / TAPS_L, tap = i - co * TAPS_L;
        int kc = co & 15, g = co >> 4;
        sw[(tap * 16 + kc) * 4 + g] = getv(lstm_w, i);
    }
    if (threadIdx.x < GATES) sb[threadIdx.x] = getv(lstm_b, threadIdx.x);
    __syncthreads();

    int blk = xcd_chunked(blockIdx.x, Bn * 90 * 5);  // 900; row-sharers same XCD
    int seg = blk % 5; int rem = blk / 5;
    int yp = rem % 90; int b = rem / 90;
    int y0 = yp * 2;
    int kc = threadIdx.x >> 4, pl = threadIdx.x & 15;
    int x0 = seg * 64 + pl * 4;

    float acc[2][4][4];  // [row][gate][px]
#pragma unroll
    for (int px = 0; px < 4; px++) {
#pragma unroll
        for (int r = 0; r < 2; r++) {
            acc[r][0][px] = sb[kc];
            acc[r][1][px] = sb[16 + kc];
            acc[r][2][px] = sb[32 + kc];
            acc[r][3][px] = sb[48 + kc];
        }
    }

    const T* xt = X + (long)(b * Tn + t) * NCc * HWc;
#pragma unroll
    for (int cin = 0; cin < NCc; cin++)
        conv_plane2r(xt + (long)cin * HWc, cin, y0, x0, kc, sw, acc);
    if (t > 0) {
        const float* hp = xcat + ((long)b * CIN_D + (t - 1) * NKc) * HWc;
#pragma unroll 1
        for (int cin = 0; cin < NKc; cin++)
            conv_plane2r(hp + (long)cin * HWc, cin + NCc, y0, x0, kc, sw, acc);
    }

#pragma unroll
    for (int r = 0; r < 2; r++) {
        int y = y0 + r;
        long pbase = (long)y * Wc + x0;
        float* cb = c_buf + (long)(b * NKc + kc) * HWc + pbase;
        float cprev[4];
        if (t > 0) {
            const float4 cv = *(const float4*)cb;
            cprev[0] = cv.x; cprev[1] = cv.y; cprev[2] = cv.z; cprev[3] = cv.w;
        } else {
            cprev[0] = cprev[1] = cprev[2] = cprev[3] = 0.0f;
        }
        float wci[4], wcf[4], wco[4];
        load4(Wci + (long)kc * HWc + pbase, 0, wci);
        load4(Wcf + (long)kc * HWc + pbase, 0, wcf);
        load4(Wco + (long)kc * HWc + pbase, 0, wco);

        float cn4[4], h4[4];
#pragma unroll
        for (int px = 0; px < 4; px++) {
            float ii = sigm(acc[r][0][px] + wci[px] * cprev[px]);
            float ff = sigm(acc[r][1][px] + wcf[px] * cprev[px]);
            float cn = ff * cprev[px] + ii * tanh_(acc[r][2][px]);
            float oo = sigm(acc[r][3][px] + wco[px] * cn);
            cn4[px] = cn; h4[px] = oo * tanh_(cn);
        }
        *(float4*)cb = make_float4(cn4[0], cn4[1], cn4[2], cn4[3]);
        *(float4*)(xcat + ((long)b * CIN_D + t * NKc + kc) * HWc + pbase) =
            make_float4(h4[0], h4[1], h4[2], h4[3]);
    }
}

__global__ void __launch_bounds__(256, 3) k_lstm2(
    const void* X, const void* lstm_w, const void* lstm_b,
    const void* Wci, const void* Wcf, const void* Wco,
    const int* __restrict__ flag,
    float* c_buf, float* xcat, int t)
{
    __shared__ float sw[TAPS_L * GATES];  // 43.8 KB
    __shared__ float sb[GATES];
    if (flag[0])
        lstm2r_body<bf16>((const bf16*)X, (const bf16*)lstm_w, (const bf16*)lstm_b,
                          (const bf16*)Wci, (const bf16*)Wcf, (const bf16*)Wco,
                          c_buf, xcat, t, sw, sb);
    else
        lstm2r_body<float>((const float*)X, (const float*)lstm_w, (const float*)lstm_b,
                           (const float*)Wci, (const float*)Wcf, (const float*)Wco,
                           c_buf, xcat, t, sw, sb);
}

// ---------------------------------------------------------------------------
// offmod v6 (R13 body + R17 swizzle).  ROUND-18: __launch_bounds__(256,4)
// — LDS (36.9 KB) caps at 4 blocks/CU; 128-VGPR budget (vs compiler's 52)
// so the 9 xs loads per cin can batch in flight instead of serializing.
// ---------------------------------------------------------------------------
template <typename T>
__device__ __forceinline__ void offmod6_body(
    const float* __restrict__ xcat,
    const T* __restrict__ off_w, const T* __restrict__ off_b,
    const T* __restrict__ mod_w, const T* __restrict__ mod_b,
    float* __restrict__ offbuf, float* __restrict__ maskbuf,
    float* sw, float* sb)
{
    int rb = xcd_chunked(blockIdx.x, 900);
    int type = rb & 1;
    int chunk = rb >> 1;
    const int nslot = type ? 12 : 16;

    for (int i = threadIdx.x; i < TAPS_D * nslot; i += 256) {
        int tap = i / nslot, j = i - tap * nslot;
        int o = type ? 16 + j : j;
        float v = 0.0f;
        if (o < 18) v = getv(off_w, (long)o * TAPS_D + tap);
        else if (o < 27) v = getv(mod_w, (long)(o - 18) * TAPS_D + tap);
        sw[tap * nslot + j] = v;
    }
    if (threadIdx.x < nslot) {
        int o = (type ? 16 : 0) + threadIdx.x;
        sb[threadIdx.x] = (o < 18) ? getv(off_b, o)
                        : (o < 27 ? getv(mod_b, o - 18) : 0.0f);
    }
    __syncthreads();

    int og = threadIdx.x >> 6, lane = threadIdx.x & 63;
    long p0 = ((long)chunk * 64 + lane) * 4;
    int b = (int)(p0 / HWc);
    int p = (int)(p0 - (long)b * HWc);
    int y = p / Wc, x0 = p - (p / Wc) * Wc;

    const int per = type ? 3 : 4;
    int jbase = og * per;

    float acc[4][4];
#pragma unroll
    for (int j = 0; j < 4; j++) {
        float bv = (j < per) ? sb[jbase + j] : 0.0f;
#pragma unroll
        for (int px = 0; px < 4; px++) acc[j][px] = bv;
    }

    const float* xb = xcat + (long)b * CIN_D * HWc;
    if (type == 0) {
#pragma unroll 2
        for (int cin = 0; cin < CIN_D; cin++) {
            const float* xc = xb + (long)cin * HWc;
#pragma unroll
            for (int ky = 0; ky < 3; ky++) {
                int yy = y + ky - 1;
                if (yy < 0 || yy >= Hc) continue;
                const float* row = xc + (long)yy * Wc;
                float xs[6];
                xs[0] = (x0 > 0) ? row[x0 - 1] : 0.0f;
                load4(row, x0, &xs[1]);
                xs[5] = (x0 + 4 < Wc) ? row[x0 + 4] : 0.0f;
#pragma unroll
                for (int kx = 0; kx < 3; kx++) {
                    int tap = (cin * 3 + ky) * 3 + kx;
                    const float4 wq = *(const float4*)&sw[tap * 16 + jbase];
#pragma unroll
                    for (int px = 0; px < 4; px++) {
                        float v = xs[px + kx];
                        acc[0][px] += wq.x * v;
                        acc[1][px] += wq.y * v;
                        acc[2][px] += wq.z * v;
                        acc[3][px] += wq.w * v;
                    }
                }
            }
        }
    } else {
#pragma unroll 2
        for (int cin = 0; cin < CIN_D; cin++) {
            const float* xc = xb + (long)cin * HWc;
#pragma unroll
            for (int ky = 0; ky < 3; ky++) {
                int yy = y + ky - 1;
                if (yy < 0 || yy >= Hc) continue;
                const float* row = xc + (long)yy * Wc;
                float xs[6];
                xs[0] = (x0 > 0) ? row[x0 - 1] : 0.0f;
                load4(row, x0, &xs[1]);
                xs[5] = (x0 + 4 < Wc) ? row[x0 + 4] : 0.0f;
#pragma unroll
                for (int kx = 0; kx < 3; kx++) {
                    int tap = (cin * 3 + ky) * 3 + kx;
                    const float* wp = &sw[tap * 12 + jbase];
                    float w0 = wp[0], w1 = wp[1], w2 = wp[2];
#pragma unroll
                    for (int px = 0; px < 4; px++) {
                        float v = xs[px + kx];
                        acc[0][px] += w0 * v;
                        acc[1][px] += w1 * v;
                        acc[2][px] += w2 * v;
                    }
                }
            }
        }
    }

    long pbase = (long)y * Wc + x0;
#pragma unroll
    for (int j = 0; j < 4; j++) {
        if (j >= per) break;
        int o = (type ? 16 : 0) + jbase + j;
        if (o >= 27) break;
        if (o < 18) {
            *(float4*)(offbuf + ((long)b * 18 + o) * HWc + pbase) =
                make_float4(acc[j][0], acc[j][1], acc[j][2], acc[j][3]);
        } else {
            *(float4*)(maskbuf + ((long)b * 9 + (o - 18)) * HWc + pbase) =
                make_float4(2.0f * sigm(acc[j][0]), 2.0f * sigm(acc[j][1]),
                            2.0f * sigm(acc[j][2]), 2.0f * sigm(acc[j][3]));
        }
    }
}

__global__ void __launch_bounds__(256, 4) k_offmod(
    const float* xcat, const void* off_w, const void* off_b,
    const void* mod_w, const void* mod_b, const int* __restrict__ flag,
    float* offbuf, float* maskbuf)
{
    __shared__ float sw[TAPS_D * 16];  // 36.9 KB (type A); type B uses 27.6 KB
    __shared__ float sb[16];
    if (flag[0])
        offmod6_body<bf16>(xcat, (const bf16*)off_w, (const bf16*)off_b,
                           (const bf16*)mod_w, (const bf16*)mod_b, offbuf, maskbuf, sw, sb);
    else
        offmod6_body<float>(xcat, (const float*)off_w, (const float*)off_b,
                            (const float*)mod_w, (const float*)mod_b, offbuf, maskbuf, sw, sb);
}

// ---------------------------------------------------------------------------
// deform v3 (R11 body + R17 swizzle).  ROUND-18: __launch_bounds__(256,4).
// ---------------------------------------------------------------------------
template <typename T>
__device__ __forceinline__ void deform3_body(
    const float* __restrict__ xcat, const float* __restrict__ offbuf,
    const float* __restrict__ maskbuf,
    const T* __restrict__ def_w, const T* __restrict__ def_b,
    float* __restrict__ dcout, float* sw, float* sb)
{
    for (int i = threadIdx.x; i < NKc * TAPS_D; i += 256) {
        int co = i / TAPS_D;
        int tap = i - co * TAPS_D;
        sw[tap * NKc + co] = getv(def_w, i);
    }
    if (threadIdx.x < NKc) sb[threadIdx.x] = getv(def_b, threadIdx.x);
    __syncthreads();

    int idx = xcd_chunked(blockIdx.x, NPIX / 256) * 256 + threadIdx.x;
    int b = idx / HWc;
    int p = idx - b * HWc;
    int y = p / Wc, x = p - (p / Wc) * Wc;

    float w00[9], w01[9], w10[9], w11[9];
    int i00[9], i01[9], i10[9], i11[9];
#pragma unroll
    for (int k = 0; k < 9; k++) {
        int ky = k / 3, kx = k - (k / 3) * 3;
        float dy = offbuf[((long)b * 18 + 2 * k) * HWc + p];
        float dx = offbuf[((long)b * 18 + 2 * k + 1) * HWc + p];
        float m = maskbuf[((long)b * 9 + k) * HWc + p];
        float py = (float)(y - 1 + ky) + dy;
        float px = (float)(x - 1 + kx) + dx;
        float y0f = floorf(py), x0f = floorf(px);
        int y0 = (int)y0f, x0 = (int)x0f;
        float wy1 = py - y0f, wx1 = px - x0f;
        float a00 = (1.0f - wy1) * (1.0f - wx1) * m;
        float a01 = (1.0f - wy1) * wx1 * m;
        float a10 = wy1 * (1.0f - wx1) * m;
        float a11 = wy1 * wx1 * m;
        bool vy0 = (y0 >= 0) && (y0 < Hc);
        bool vy1 = (y0 + 1 >= 0) && (y0 + 1 < Hc);
        bool vx0 = (x0 >= 0) && (x0 < Wc);
        bool vx1 = (x0 + 1 >= 0) && (x0 + 1 < Wc);
        w00[k] = (vy0 && vx0) ? a00 : 0.0f;
        w01[k] = (vy0 && vx1) ? a01 : 0.0f;
        w10[k] = (vy1 && vx0) ? a10 : 0.0f;
        w11[k] = (vy1 && vx1) ? a11 : 0.0f;
        int yc0 = min(max(y0, 0), Hc - 1);
        int yc1 = min(max(y0 + 1, 0), Hc - 1);
        int xc0 = min(max(x0, 0), Wc - 1);
        int xc1 = min(max(x0 + 1, 0), Wc - 1);
        i00[k] = yc0 * Wc + xc0; i01[k] = yc0 * Wc + xc1;
        i10[k] = yc1 * Wc + xc0; i11[k] = yc1 * Wc + xc1;
    }

    float acc[NKc];
#pragma unroll
    for (int i = 0; i < NKc; i++) acc[i] = sb[i];

    const float* xb = xcat + (long)b * CIN_D * HWc;
#pragma unroll 1
    for (int cin = 0; cin < CIN_D; cin++) {
        const float* xc = xb + (long)cin * HWc;
        float s[9];
#pragma unroll
        for (int k = 0; k < 9; k++)
            s[k] = w00[k] * xc[i00[k]] + w01[k] * xc[i01[k]] +
                   w10[k] * xc[i10[k]] + w11[k] * xc[i11[k]];
#pragma unroll
        for (int k = 0; k < 9; k++) {
            const float* wrow = &sw[(cin * 9 + k) * NKc];
#pragma unroll
            for (int co = 0; co < NKc; co++) acc[co] += wrow[co] * s[k];
        }
    }

#pragma unroll
    for (int co = 0; co < NKc; co++)
        dcout[((long)b * NKc + co) * HWc + p] = acc[co];
}

__global__ void __launch_bounds__(256, 4) k_deform(
    const float* xcat, const float* offbuf, const float* maskbuf,
    const void* def_w, const void* def_b, const int* __restrict__ flag,
    float* dcout)
{
    __shared__ float sw[TAPS_D * NKc];  // 36.9 KB
    __shared__ float sb[NKc];
    if (flag[0])
        deform3_body<bf16>(xcat, offbuf, maskbuf, (const bf16*)def_w, (const bf16*)def_b,
                           dcout, sw, sb);
    else
        deform3_body<float>(xcat, offbuf, maskbuf, (const float*)def_w, (const float*)def_b,
                            dcout, sw, sb);
}

// ---------------------------------------------------------------------------
// outconv v5 (R12 body + R17 swizzle).  ROUND-18: __launch_bounds__(256,4).
// ---------------------------------------------------------------------------
template <typename T>
__device__ __forceinline__ void outconv6_body(
    const float* __restrict__ dcout, const T* __restrict__ out_w,
    const T* __restrict__ out_b, T* __restrict__ out, float* sw, float* sb)
{
    int rb = xcd_chunked(blockIdx.x, 900);
    int type = rb & 1;
    int chunk = rb >> 1;

    for (int i = threadIdx.x; i < 24 * TAPS_O; i += 256) {
        int o = i / TAPS_O, tap = i - o * TAPS_O;
        int slot = (o / 6) * 8 + (o % 6);
        sw[tap * 32 + slot] = getv(out_w, (long)(type * 24 + o) * TAPS_O + tap);
    }
    if (threadIdx.x < 24) sb[threadIdx.x] = getv(out_b, type * 24 + threadIdx.x);
    __syncthreads();

    int og = threadIdx.x >> 6, lane = threadIdx.x & 63;
    long p0 = ((long)chunk * 64 + lane) * 4;
    int b = (int)(p0 / HWc);
    int p = (int)(p0 - (long)b * HWc);
    int y = p / Wc, x0 = p - (p / Wc) * Wc;

    float acc[6][4];
#pragma unroll
    for (int j = 0; j < 6; j++) {
        float bv = sb[og * 6 + j];
#pragma unroll
        for (int px = 0; px < 4; px++) acc[j][px] = bv;
    }

    const float* xb = dcout + (long)b * NKc * HWc;
#pragma unroll 2
    for (int cin = 0; cin < NKc; cin++) {
        const float* xc = xb + (long)cin * HWc;
#pragma unroll
        for (int ky = 0; ky < 3; ky++) {
            int yy = y + ky - 1;
            if (yy < 0 || yy >= Hc) continue;
            const float* row = xc + (long)yy * Wc;
            float xs[6];
            xs[0] = (x0 > 0) ? row[x0 - 1] : 0.0f;
            load4(row, x0, &xs[1]);
            xs[5] = (x0 + 4 < Wc) ? row[x0 + 4] : 0.0f;
#pragma unroll
            for (int kx = 0; kx < 3; kx++) {
                int tap = (cin * 3 + ky) * 3 + kx;
                const float* wp = &sw[tap * 32 + og * 8];
                const float4 w0 = *(const float4*)wp;
                const float2 w1 = *(const float2*)(wp + 4);
#pragma unroll
                for (int px = 0; px < 4; px++) {
                    float v = xs[px + kx];
                    acc[0][px] += w0.x * v;  acc[1][px] += w0.y * v;
                    acc[2][px] += w0.z * v;  acc[3][px] += w0.w * v;
                    acc[4][px] += w1.x * v;  acc[5][px] += w1.y * v;
                }
            }
        }
    }

#pragma unroll
    for (int j = 0; j < 6; j++) {
        int co = type * 24 + og * 6 + j;
        int cc = co >> 4;
        int r = co & 15;
        int ii = r >> 2, jj = r & 3;
        long ob = (((long)b * 3 + cc) * (Hc * 4) + (y * 4 + ii)) * (long)(Wc * 4);
#pragma unroll
        for (int px = 0; px < 4; px++) {
            float v = fminf(fmaxf(acc[j][px], 0.0f), 255.0f);
            putv(out, ob + (x0 + px) * 4 + jj, v);
        }
    }
}

__global__ void __launch_bounds__(256, 4) k_outconv(
    const float* dcout, const void* out_w, const void* out_b,
    const int* __restrict__ flag, void* out)
{
    __shared__ float sw[TAPS_O * 32];  // 18.4 KB
    __shared__ float sb[24];
    if (flag[0])
        outconv6_body<bf16>(dcout, (const bf16*)out_w, (const bf16*)out_b, (bf16*)out, sw, sb);
    else
        outconv6_body<float>(dcout, (const float*)out_w, (const float*)out_b, (float*)out, sw, sb);
}

extern "C" void kernel_launch(void* const* d_in, const int* in_sizes, int n_in,
                              void* d_out, int out_size, void* d_ws, size_t ws_size,
                              hipStream_t stream) {
    const void* X      = d_in[0];
    const void* lstm_w = d_in[1];
    const void* lstm_b = d_in[2];
    const void* Wci    = d_in[3];
    const void* Wcf    = d_in[4];
    const void* Wco    = d_in[5];
    const void* off_w  = d_in[6];
    const void* off_b  = d_in[7];
    const void* mod_w  = d_in[8];
    const void* mod_b  = d_in[9];
    const void* def_w  = d_in[10];
    const void* def_b  = d_in[11];
    const void* out_w  = d_in[12];
    const void* out_b  = d_in[13];

    int* flag = (int*)d_ws;
    float* W = (float*)d_ws + 64;
    size_t o = 0;
    float* c_buf   = W + o; o += (size_t)Bn * NKc * HWc;
    float* xcat    = W + o; o += (size_t)Bn * CIN_D * HWc;
    float* offbuf  = W + o; o += (size_t)Bn * 18 * HWc;
    float* maskbuf = W + o; o += (size_t)Bn * 9 * HWc;
    float* dcout   = W + o; o += (size_t)Bn * NKc * HWc;

    dim3 blk(256);
    dim3 gridP(NPIX / 256);           // 450
    dim3 gridL2(Bn * (Hc / 2) * 5);   // 900: 2-row lstm blocks
    dim3 gridC2(2 * (NPIX / 4 / 64)); // 900

    k_detect<<<1, blk, 0, stream>>>(lstm_w, flag);
    for (int t = 0; t < Tn; t++) {
        k_lstm2<<<gridL2, blk, 0, stream>>>(X, lstm_w, lstm_b, Wci, Wcf, Wco,
                                            flag, c_buf, xcat, t);
    }
    k_offmod<<<gridC2, blk, 0, stream>>>(xcat, off_w, off_b, mod_w, mod_b, flag,
                                         offbuf, maskbuf);
    k_deform<<<gridP, blk, 0, stream>>>(xcat, offbuf, maskbuf, def_w, def_b, flag, dcout);
    k_outconv<<<gridC2, blk, 0, stream>>>(dcout, out_w, out_b, flag, d_out);
}

// Round 6
// 714.391 us; speedup vs baseline: 1.2147x; 1.2147x over previous
//
#include <hip/hip_runtime.h>
#include <hip/hip_bf16.h>

// Problem dims
#define Bn 2
#define Tn 4
#define NCc 3
#define NKc 16
#define Hc 180
#define Wc 320
#define HWc (Hc * Wc)          // 57600
#define NPIX (Bn * HWc)        // 115200
#define CIN_LSTM 19            // NC + NK
#define GATES 64               // 4*NK
#define CIN_D 64               // T*NK
#define TAPS_L (CIN_LSTM * 9)  // 171
#define TAPS_D (CIN_D * 9)     // 576
#define TAPS_O (NKc * 9)       // 144

typedef __hip_bfloat16 bf16;

__device__ __forceinline__ float getv(const float* p, long i) { return p[i]; }
__device__ __forceinline__ float getv(const bf16* p, long i) {
    unsigned int u = ((unsigned int)((const unsigned short*)p)[i]) << 16;
    return __uint_as_float(u);
}
__device__ __forceinline__ void putv(float* p, long i, float v) { p[i] = v; }
__device__ __forceinline__ void putv(bf16* p, long i, float v) { p[i] = __float2bfloat16(v); }
__device__ __forceinline__ float sigm(float x) { return 1.0f / (1.0f + __expf(-x)); }
__device__ __forceinline__ float tanh_(float x) { return 1.0f - 2.0f / (__expf(2.0f * x) + 1.0f); }

__device__ __forceinline__ void load4(const float* row, int x0, float* d) {
    const float4 v = *(const float4*)(row + x0);
    d[0] = v.x; d[1] = v.y; d[2] = v.z; d[3] = v.w;
}
__device__ __forceinline__ void load4(const bf16* row, int x0, float* d) {
    ushort4 u = *(const ushort4*)((const unsigned short*)row + x0);
    d[0] = __uint_as_float(((unsigned int)u.x) << 16);
    d[1] = __uint_as_float(((unsigned int)u.y) << 16);
    d[2] = __uint_as_float(((unsigned int)u.z) << 16);
    d[3] = __uint_as_float(((unsigned int)u.w) << 16);
}

// ---------------------------------------------------------------------------
// XCD-aware bijective chunked swizzle (T1, m204 formula). Proven R17:
// k_offmod FETCH 85 -> 15.4 MB. Keep everywhere.
// ---------------------------------------------------------------------------
__device__ __forceinline__ int xcd_chunked(int i, int nwg) {
    int q = nwg >> 3, r = nwg & 7;
    int xcd = i & 7, idx = i >> 3;
    return (xcd < r ? xcd * (q + 1) : r * (q + 1) + (xcd - r) * q) + idx;
}

// ---------------------------------------------------------------------------
// Dtype probe (bf16 vs float32 inputs) -> flag in d_ws.
// ---------------------------------------------------------------------------
__global__ void __launch_bounds__(256) k_detect(const void* lstm_w_raw, int* flag)
{
    __shared__ int bad;
    if (threadIdx.x == 0) bad = 0;
    __syncthreads();
    const unsigned short* u = (const unsigned short*)lstm_w_raw;
    int local = 0;
    for (int i = threadIdx.x; i < GATES * TAPS_L; i += 256) {
        unsigned int f32 = ((unsigned int)u[i]) << 16;
        float v = __uint_as_float(f32);
        if (!(fabsf(v) <= 64.0f)) local = 1;
    }
    if (local) atomicOr(&bad, 1);
    __syncthreads();
    if (threadIdx.x == 0) flag[0] = bad ? 0 : 1;
}

// ---------------------------------------------------------------------------
// ConvLSTM step.  ROUND-19: REGISTER-STAGED WEIGHTS — all 9 tap-quads for
// the cin are ds_read up-front (one lgkm wait), then 288 FMAs run with no
// memory dependency.  Previous form waited on ONE b128 per 32 FMAs: ~120cy
// LDS latency per 64cy of issue = the ~60% stall every probe kept showing.
// No launch_bounds (R18: caps regress, they don't raise VGPR usage).
// ---------------------------------------------------------------------------
template <typename S>
__device__ __forceinline__ void conv_plane2r(
    const S* __restrict__ src, int cin, int y0, int x0, int kc,
    const float* __restrict__ sw, float (&acc)[2][4][4])
{
    float xs[4][6];  // rows y0-1 .. y0+2
#pragma unroll
    for (int r = 0; r < 4; r++) {
        int yy = y0 - 1 + r;
        if (yy >= 0 && yy < Hc) {
            const S* row = src + (long)yy * Wc;
            xs[r][0] = (x0 > 0) ? getv(row, x0 - 1) : 0.0f;
            load4(row, x0, &xs[r][1]);
            xs[r][5] = (x0 + 4 < Wc) ? getv(row, x0 + 4) : 0.0f;
        } else {
#pragma unroll
            for (int j = 0; j < 6; j++) xs[r][j] = 0.0f;
        }
    }
    float4 wq[9];   // register-staged weight quads, single lgkm wait at use
#pragma unroll
    for (int t9 = 0; t9 < 9; t9++)
        wq[t9] = *(const float4*)&sw[(((cin * 9 + t9) * 16) + kc) * 4];
#pragma unroll
    for (int ky = 0; ky < 3; ky++) {
#pragma unroll
        for (int kx = 0; kx < 3; kx++) {
            const float4 w = wq[ky * 3 + kx];
#pragma unroll
            for (int px = 0; px < 4; px++) {
                float v0 = xs[ky][px + kx];      // output row y0
                float v1 = xs[ky + 1][px + kx];  // output row y0+1
                acc[0][0][px] += w.x * v0;  acc[1][0][px] += w.x * v1;
                acc[0][1][px] += w.y * v0;  acc[1][1][px] += w.y * v1;
                acc[0][2][px] += w.z * v0;  acc[1][2][px] += w.z * v1;
                acc[0][3][px] += w.w * v0;  acc[1][3][px] += w.w * v1;
            }
        }
    }
}

template <typename T>
__device__ __forceinline__ void lstm2r_body(
    const T* __restrict__ X, const T* __restrict__ lstm_w, const T* __restrict__ lstm_b,
    const T* __restrict__ Wci, const T* __restrict__ Wcf, const T* __restrict__ Wco,
    float* __restrict__ c_buf, float* __restrict__ xcat, int t,
    float* sw, float* sb)
{
    for (int i = threadIdx.x; i < GATES * TAPS_L; i += 256) {
        int co = i / TAPS_L, tap = i - co * TAPS_L;
        int kc = co & 15, g = co >> 4;
        sw[(tap * 16 + kc) * 4 + g] = getv(lstm_w, i);
    }
    if (threadIdx.x < GATES) sb[threadIdx.x] = getv(lstm_b, threadIdx.x);
    __syncthreads();

    int blk = xcd_chunked(blockIdx.x, Bn * 90 * 5);  // 900; row-sharers same XCD
    int seg = blk % 5; int rem = blk / 5;
    int yp = rem % 90; int b = rem / 90;
    int y0 = yp * 2;
    int kc = threadIdx.x >> 4, pl = threadIdx.x & 15;
    int x0 = seg * 64 + pl * 4;

    float acc[2][4][4];  // [row][gate][px]
#pragma unroll
    for (int px = 0; px < 4; px++) {
#pragma unroll
        for (int r = 0; r < 2; r++) {
            acc[r][0][px] = sb[kc];
            acc[r][1][px] = sb[16 + kc];
            acc[r][2][px] = sb[32 + kc];
            acc[r][3][px] = sb[48 + kc];
        }
    }

    const T* xt = X + (long)(b * Tn + t) * NCc * HWc;
#pragma unroll 1
    for (int cin = 0; cin < NCc; cin++)
        conv_plane2r(xt + (long)cin * HWc, cin, y0, x0, kc, sw, acc);
    if (t > 0) {
        const float* hp = xcat + ((long)b * CIN_D + (t - 1) * NKc) * HWc;
#pragma unroll 1
        for (int cin = 0; cin < NKc; cin++)
            conv_plane2r(hp + (long)cin * HWc, cin + NCc, y0, x0, kc, sw, acc);
    }

#pragma unroll
    for (int r = 0; r < 2; r++) {
        int y = y0 + r;
        long pbase = (long)y * Wc + x0;
        float* cb = c_buf + (long)(b * NKc + kc) * HWc + pbase;
        float cprev[4];
        if (t > 0) {
            const float4 cv = *(const float4*)cb;
            cprev[0] = cv.x; cprev[1] = cv.y; cprev[2] = cv.z; cprev[3] = cv.w;
        } else {
            cprev[0] = cprev[1] = cprev[2] = cprev[3] = 0.0f;
        }
        float wci[4], wcf[4], wco[4];
        load4(Wci + (long)kc * HWc + pbase, 0, wci);
        load4(Wcf + (long)kc * HWc + pbase, 0, wcf);
        load4(Wco + (long)kc * HWc + pbase, 0, wco);

        float cn4[4], h4[4];
#pragma unroll
        for (int px = 0; px < 4; px++) {
            float ii = sigm(acc[r][0][px] + wci[px] * cprev[px]);
            float ff = sigm(acc[r][1][px] + wcf[px] * cprev[px]);
            float cn = ff * cprev[px] + ii * tanh_(acc[r][2][px]);
            float oo = sigm(acc[r][3][px] + wco[px] * cn);
            cn4[px] = cn; h4[px] = oo * tanh_(cn);
        }
        *(float4*)cb = make_float4(cn4[0], cn4[1], cn4[2], cn4[3]);
        *(float4*)(xcat + ((long)b * CIN_D + t * NKc + kc) * HWc + pbase) =
            make_float4(h4[0], h4[1], h4[2], h4[3]);
    }
}

__global__ void __launch_bounds__(256) k_lstm2(
    const void* X, const void* lstm_w, const void* lstm_b,
    const void* Wci, const void* Wcf, const void* Wco,
    const int* __restrict__ flag,
    float* c_buf, float* xcat, int t)
{
    __shared__ float sw[TAPS_L * GATES];  // 43.8 KB
    __shared__ float sb[GATES];
    if (flag[0])
        lstm2r_body<bf16>((const bf16*)X, (const bf16*)lstm_w, (const bf16*)lstm_b,
                          (const bf16*)Wci, (const bf16*)Wcf, (const bf16*)Wco,
                          c_buf, xcat, t, sw, sb);
    else
        lstm2r_body<float>((const float*)X, (const float*)lstm_w, (const float*)lstm_b,
                           (const float*)Wci, (const float*)Wcf, (const float*)Wco,
                           c_buf, xcat, t, sw, sb);
}

// ---------------------------------------------------------------------------
// offmod v10 (ROUND-19): R13 math + R17 swizzle + register-staged weights.
// Per cin: hoist xs[3][6] row loads, ds_read all 9 weight quads into regs
// (ONE lgkm wait), then 144 dep-free FMAs.
// ---------------------------------------------------------------------------
template <typename T>
__device__ __forceinline__ void offmod6_body(
    const float* __restrict__ xcat,
    const T* __restrict__ off_w, const T* __restrict__ off_b,
    const T* __restrict__ mod_w, const T* __restrict__ mod_b,
    float* __restrict__ offbuf, float* __restrict__ maskbuf,
    float* sw, float* sb)
{
    int rb = xcd_chunked(blockIdx.x, 900);
    int type = rb & 1;
    int chunk = rb >> 1;
    const int nslot = type ? 12 : 16;

    for (int i = threadIdx.x; i < TAPS_D * nslot; i += 256) {
        int tap = i / nslot, j = i - tap * nslot;
        int o = type ? 16 + j : j;
        float v = 0.0f;
        if (o < 18) v = getv(off_w, (long)o * TAPS_D + tap);
        else if (o < 27) v = getv(mod_w, (long)(o - 18) * TAPS_D + tap);
        sw[tap * nslot + j] = v;
    }
    if (threadIdx.x < nslot) {
        int o = (type ? 16 : 0) + threadIdx.x;
        sb[threadIdx.x] = (o < 18) ? getv(off_b, o)
                        : (o < 27 ? getv(mod_b, o - 18) : 0.0f);
    }
    __syncthreads();

    int og = threadIdx.x >> 6, lane = threadIdx.x & 63;
    long p0 = ((long)chunk * 64 + lane) * 4;
    int b = (int)(p0 / HWc);
    int p = (int)(p0 - (long)b * HWc);
    int y = p / Wc, x0 = p - (p / Wc) * Wc;

    const int per = type ? 3 : 4;
    int jbase = og * per;

    float acc[4][4];
#pragma unroll
    for (int j = 0; j < 4; j++) {
        float bv = (j < per) ? sb[jbase + j] : 0.0f;
#pragma unroll
        for (int px = 0; px < 4; px++) acc[j][px] = bv;
    }

    const float* xb = xcat + (long)b * CIN_D * HWc;
    if (type == 0) {
#pragma unroll 1
        for (int cin = 0; cin < CIN_D; cin++) {
            const float* xc = xb + (long)cin * HWc;
            float xs[3][6];
#pragma unroll
            for (int ky = 0; ky < 3; ky++) {
                int yy = y + ky - 1;
                if (yy >= 0 && yy < Hc) {
                    const float* row = xc + (long)yy * Wc;
                    xs[ky][0] = (x0 > 0) ? row[x0 - 1] : 0.0f;
                    load4(row, x0, &xs[ky][1]);
                    xs[ky][5] = (x0 + 4 < Wc) ? row[x0 + 4] : 0.0f;
                } else {
#pragma unroll
                    for (int j = 0; j < 6; j++) xs[ky][j] = 0.0f;
                }
            }
            float4 wr[9];
#pragma unroll
            for (int t9 = 0; t9 < 9; t9++)
                wr[t9] = *(const float4*)&sw[(cin * 9 + t9) * 16 + jbase];
#pragma unroll
            for (int ky = 0; ky < 3; ky++) {
#pragma unroll
                for (int kx = 0; kx < 3; kx++) {
                    const float4 wq = wr[ky * 3 + kx];
#pragma unroll
                    for (int px = 0; px < 4; px++) {
                        float v = xs[ky][px + kx];
                        acc[0][px] += wq.x * v;
                        acc[1][px] += wq.y * v;
                        acc[2][px] += wq.z * v;
                        acc[3][px] += wq.w * v;
                    }
                }
            }
        }
    } else {
#pragma unroll 1
        for (int cin = 0; cin < CIN_D; cin++) {
            const float* xc = xb + (long)cin * HWc;
            float xs[3][6];
#pragma unroll
            for (int ky = 0; ky < 3; ky++) {
                int yy = y + ky - 1;
                if (yy >= 0 && yy < Hc) {
                    const float* row = xc + (long)yy * Wc;
                    xs[ky][0] = (x0 > 0) ? row[x0 - 1] : 0.0f;
                    load4(row, x0, &xs[ky][1]);
                    xs[ky][5] = (x0 + 4 < Wc) ? row[x0 + 4] : 0.0f;
                } else {
#pragma unroll
                    for (int j = 0; j < 6; j++) xs[ky][j] = 0.0f;
                }
            }
            float3 wr[9];
#pragma unroll
            for (int t9 = 0; t9 < 9; t9++) {
                const float* wp = &sw[(cin * 9 + t9) * 12 + jbase];
                wr[t9] = make_float3(wp[0], wp[1], wp[2]);
            }
#pragma unroll
            for (int ky = 0; ky < 3; ky++) {
#pragma unroll
                for (int kx = 0; kx < 3; kx++) {
                    const float3 wq = wr[ky * 3 + kx];
#pragma unroll
                    for (int px = 0; px < 4; px++) {
                        float v = xs[ky][px + kx];
                        acc[0][px] += wq.x * v;
                        acc[1][px] += wq.y * v;
                        acc[2][px] += wq.z * v;
                    }
                }
            }
        }
    }

    long pbase = (long)y * Wc + x0;
#pragma unroll
    for (int j = 0; j < 4; j++) {
        if (j >= per) break;
        int o = (type ? 16 : 0) + jbase + j;
        if (o >= 27) break;
        if (o < 18) {
            *(float4*)(offbuf + ((long)b * 18 + o) * HWc + pbase) =
                make_float4(acc[j][0], acc[j][1], acc[j][2], acc[j][3]);
        } else {
            *(float4*)(maskbuf + ((long)b * 9 + (o - 18)) * HWc + pbase) =
                make_float4(2.0f * sigm(acc[j][0]), 2.0f * sigm(acc[j][1]),
                            2.0f * sigm(acc[j][2]), 2.0f * sigm(acc[j][3]));
        }
    }
}

__global__ void __launch_bounds__(256) k_offmod(
    const float* xcat, const void* off_w, const void* off_b,
    const void* mod_w, const void* mod_b, const int* __restrict__ flag,
    float* offbuf, float* maskbuf)
{
    __shared__ float sw[TAPS_D * 16];  // 36.9 KB (type A); type B uses 27.6 KB
    __shared__ float sb[16];
    if (flag[0])
        offmod6_body<bf16>(xcat, (const bf16*)off_w, (const bf16*)off_b,
                           (const bf16*)mod_w, (const bf16*)mod_b, offbuf, maskbuf, sw, sb);
    else
        offmod6_body<float>(xcat, (const float*)off_w, (const float*)off_b,
                            (const float*)mod_w, (const float*)mod_b, offbuf, maskbuf, sw, sb);
}

// ---------------------------------------------------------------------------
// deform v3 (R11 body + R17 swizzle; R18 launch_bounds REVERTED — it forced
// VGPR 64, spawned 1.9M LDS bank conflicts and +70us).
// ---------------------------------------------------------------------------
template <typename T>
__device__ __forceinline__ void deform3_body(
    const float* __restrict__ xcat, const float* __restrict__ offbuf,
    const float* __restrict__ maskbuf,
    const T* __restrict__ def_w, const T* __restrict__ def_b,
    float* __restrict__ dcout, float* sw, float* sb)
{
    for (int i = threadIdx.x; i < NKc * TAPS_D; i += 256) {
        int co = i / TAPS_D;
        int tap = i - co * TAPS_D;
        sw[tap * NKc + co] = getv(def_w, i);
    }
    if (threadIdx.x < NKc) sb[threadIdx.x] = getv(def_b, threadIdx.x);
    __syncthreads();

    int idx = xcd_chunked(blockIdx.x, NPIX / 256) * 256 + threadIdx.x;
    int b = idx / HWc;
    int p = idx - b * HWc;
    int y = p / Wc, x = p - (p / Wc) * Wc;

    float w00[9], w01[9], w10[9], w11[9];
    int i00[9], i01[9], i10[9], i11[9];
#pragma unroll
    for (int k = 0; k < 9; k++) {
        int ky = k / 3, kx = k - (k / 3) * 3;
        float dy = offbuf[((long)b * 18 + 2 * k) * HWc + p];
        float dx = offbuf[((long)b * 18 + 2 * k + 1) * HWc + p];
        float m = maskbuf[((long)b * 9 + k) * HWc + p];
        float py = (float)(y - 1 + ky) + dy;
        float px = (float)(x - 1 + kx) + dx;
        float y0f = floorf(py), x0f = floorf(px);
        int y0 = (int)y0f, x0 = (int)x0f;
        float wy1 = py - y0f, wx1 = px - x0f;
        float a00 = (1.0f - wy1) * (1.0f - wx1) * m;
        float a01 = (1.0f - wy1) * wx1 * m;
        float a10 = wy1 * (1.0f - wx1) * m;
        float a11 = wy1 * wx1 * m;
        bool vy0 = (y0 >= 0) && (y0 < Hc);
        bool vy1 = (y0 + 1 >= 0) && (y0 + 1 < Hc);
        bool vx0 = (x0 >= 0) && (x0 < Wc);
        bool vx1 = (x0 + 1 >= 0) && (x0 + 1 < Wc);
        w00[k] = (vy0 && vx0) ? a00 : 0.0f;
        w01[k] = (vy0 && vx1) ? a01 : 0.0f;
        w10[k] = (vy1 && vx0) ? a10 : 0.0f;
        w11[k] = (vy1 && vx1) ? a11 : 0.0f;
        int yc0 = min(max(y0, 0), Hc - 1);
        int yc1 = min(max(y0 + 1, 0), Hc - 1);
        int xc0 = min(max(x0, 0), Wc - 1);
        int xc1 = min(max(x0 + 1, 0), Wc - 1);
        i00[k] = yc0 * Wc + xc0; i01[k] = yc0 * Wc + xc1;
        i10[k] = yc1 * Wc + xc0; i11[k] = yc1 * Wc + xc1;
    }

    float acc[NKc];
#pragma unroll
    for (int i = 0; i < NKc; i++) acc[i] = sb[i];

    const float* xb = xcat + (long)b * CIN_D * HWc;
#pragma unroll 1
    for (int cin = 0; cin < CIN_D; cin++) {
        const float* xc = xb + (long)cin * HWc;
        float s[9];
#pragma unroll
        for (int k = 0; k < 9; k++)
            s[k] = w00[k] * xc[i00[k]] + w01[k] * xc[i01[k]] +
                   w10[k] * xc[i10[k]] + w11[k] * xc[i11[k]];
#pragma unroll
        for (int k = 0; k < 9; k++) {
            const float* wrow = &sw[(cin * 9 + k) * NKc];
#pragma unroll
            for (int co = 0; co < NKc; co++) acc[co] += wrow[co] * s[k];
        }
    }

#pragma unroll
    for (int co = 0; co < NKc; co++)
        dcout[((long)b * NKc + co) * HWc + p] = acc[co];
}

__global__ void __launch_bounds__(256) k_deform(
    const float* xcat, const float* offbuf, const float* maskbuf,
    const void* def_w, const void* def_b, const int* __restrict__ flag,
    float* dcout)
{
    __shared__ float sw[TAPS_D * NKc];  // 36.9 KB
    __shared__ float sb[NKc];
    if (flag[0])
        deform3_body<bf16>(xcat, offbuf, maskbuf, (const bf16*)def_w, (const bf16*)def_b,
                           dcout, sw, sb);
    else
        deform3_body<float>(xcat, offbuf, maskbuf, (const float*)def_w, (const float*)def_b,
                            dcout, sw, sb);
}

// ---------------------------------------------------------------------------
// outconv v8 (ROUND-19): R12 math + R17 swizzle + register-staged weights
// (9x float4 + 9x float2, one wait) + hoisted xs rows.
// ---------------------------------------------------------------------------
template <typename T>
__device__ __forceinline__ void outconv6_body(
    const float* __restrict__ dcout, const T* __restrict__ out_w,
    const T* __restrict__ out_b, T* __restrict__ out, float* sw, float* sb)
{
    int rb = xcd_chunked(blockIdx.x, 900);
    int type = rb & 1;
    int chunk = rb >> 1;

    for (int i = threadIdx.x; i < 24 * TAPS_O; i += 256) {
        int o = i / TAPS_O, tap = i - o * TAPS_O;
        int slot = (o / 6) * 8 + (o % 6);
        sw[tap * 32 + slot] = getv(out_w, (long)(type * 24 + o) * TAPS_O + tap);
    }
    if (threadIdx.x < 24) sb[threadIdx.x] = getv(out_b, type * 24 + threadIdx.x);
    __syncthreads();

    int og = threadIdx.x >> 6, lane = threadIdx.x & 63;
    long p0 = ((long)chunk * 64 + lane) * 4;
    int b = (int)(p0 / HWc);
    int p = (int)(p0 - (long)b * HWc);
    int y = p / Wc, x0 = p - (p / Wc) * Wc;

    float acc[6][4];
#pragma unroll
    for (int j = 0; j < 6; j++) {
        float bv = sb[og * 6 + j];
#pragma unroll
        for (int px = 0; px < 4; px++) acc[j][px] = bv;
    }

    const float* xb = dcout + (long)b * NKc * HWc;
#pragma unroll 1
    for (int cin = 0; cin < NKc; cin++) {
        const float* xc = xb + (long)cin * HWc;
        float xs[3][6];
#pragma unroll
        for (int ky = 0; ky < 3; ky++) {
            int yy = y + ky - 1;
            if (yy >= 0 && yy < Hc) {
                const float* row = xc + (long)yy * Wc;
                xs[ky][0] = (x0 > 0) ? row[x0 - 1] : 0.0f;
                load4(row, x0, &xs[ky][1]);
                xs[ky][5] = (x0 + 4 < Wc) ? row[x0 + 4] : 0.0f;
            } else {
#pragma unroll
                for (int j = 0; j < 6; j++) xs[ky][j] = 0.0f;
            }
        }
        float4 wa[9]; float2 wb[9];
#pragma unroll
        for (int t9 = 0; t9 < 9; t9++) {
            const float* wp = &sw[(cin * 9 + t9) * 32 + og * 8];
            wa[t9] = *(const float4*)wp;
            wb[t9] = *(const float2*)(wp + 4);
        }
#pragma unroll
        for (int ky = 0; ky < 3; ky++) {
#pragma unroll
            for (int kx = 0; kx < 3; kx++) {
                const float4 w0 = wa[ky * 3 + kx];
                const float2 w1 = wb[ky * 3 + kx];
#pragma unroll
                for (int px = 0; px < 4; px++) {
                    float v = xs[ky][px + kx];
                    acc[0][px] += w0.x * v;  acc[1][px] += w0.y * v;
                    acc[2][px] += w0.z * v;  acc[3][px] += w0.w * v;
                    acc[4][px] += w1.x * v;  acc[5][px] += w1.y * v;
                }
            }
        }
    }

#pragma unroll
    for (int j = 0; j < 6; j++) {
        int co = type * 24 + og * 6 + j;
        int cc = co >> 4;
        int r = co & 15;
        int ii = r >> 2, jj = r & 3;
        long ob = (((long)b * 3 + cc) * (Hc * 4) + (y * 4 + ii)) * (long)(Wc * 4);
#pragma unroll
        for (int px = 0; px < 4; px++) {
            float v = fminf(fmaxf(acc[j][px], 0.0f), 255.0f);
            putv(out, ob + (x0 + px) * 4 + jj, v);
        }
    }
}

__global__ void __launch_bounds__(256) k_outconv(
    const float* dcout, const void* out_w, const void* out_b,
    const int* __restrict__ flag, void* out)
{
    __shared__ float sw[TAPS_O * 32];  // 18.4 KB
    __shared__ float sb[24];
    if (flag[0])
        outconv6_body<bf16>(dcout, (const bf16*)out_w, (const bf16*)out_b, (bf16*)out, sw, sb);
    else
        outconv6_body<float>(dcout, (const float*)out_w, (const float*)out_b, (float*)out, sw, sb);
}

extern "C" void kernel_launch(void* const* d_in, const int* in_sizes, int n_in,
                              void* d_out, int out_size, void* d_ws, size_t ws_size,
                              hipStream_t stream) {
    const void* X      = d_in[0];
    const void* lstm_w = d_in[1];
    const void* lstm_b = d_in[2];
    const void* Wci    = d_in[3];
    const void* Wcf    = d_in[4];
    const void* Wco    = d_in[5];
    const void* off_w  = d_in[6];
    const void* off_b  = d_in[7];
    const void* mod_w  = d_in[8];
    const void* mod_b  = d_in[9];
    const void* def_w  = d_in[10];
    const void* def_b  = d_in[11];
    const void* out_w  = d_in[12];
    const void* out_b  = d_in[13];

    int* flag = (int*)d_ws;
    float* W = (float*)d_ws + 64;
    size_t o = 0;
    float* c_buf   = W + o; o += (size_t)Bn * NKc * HWc;
    float* xcat    = W + o; o += (size_t)Bn * CIN_D * HWc;
    float* offbuf  = W + o; o += (size_t)Bn * 18 * HWc;
    float* maskbuf = W + o; o += (size_t)Bn * 9 * HWc;
    float* dcout   = W + o; o += (size_t)Bn * NKc * HWc;

    dim3 blk(256);
    dim3 gridP(NPIX / 256);           // 450
    dim3 gridL2(Bn * (Hc / 2) * 5);   // 900: 2-row lstm blocks
    dim3 gridC2(2 * (NPIX / 4 / 64)); // 900

    k_detect<<<1, blk, 0, stream>>>(lstm_w, flag);
    for (int t = 0; t < Tn; t++) {
        k_lstm2<<<gridL2, blk, 0, stream>>>(X, lstm_w, lstm_b, Wci, Wcf, Wco,
                                            flag, c_buf, xcat, t);
    }
    k_offmod<<<gridC2, blk, 0, stream>>>(xcat, off_w, off_b, mod_w, mod_b, flag,
                                         offbuf, maskbuf);
    k_deform<<<gridP, blk, 0, stream>>>(xcat, offbuf, maskbuf, def_w, def_b, flag, dcout);
    k_outconv<<<gridC2, blk, 0, stream>>>(dcout, out_w, out_b, flag, d_out);
}

// Round 7
// 707.199 us; speedup vs baseline: 1.2271x; 1.0102x over previous
//
#include <hip/hip_runtime.h>
#include <hip/hip_bf16.h>

// Problem dims
#define Bn 2
#define Tn 4
#define NCc 3
#define NKc 16
#define Hc 180
#define Wc 320
#define HWc (Hc * Wc)          // 57600
#define NPIX (Bn * HWc)        // 115200
#define CIN_LSTM 19            // NC + NK
#define GATES 64               // 4*NK
#define CIN_D 64               // T*NK
#define TAPS_L (CIN_LSTM * 9)  // 171
#define TAPS_D (CIN_D * 9)     // 576
#define TAPS_O (NKc * 9)       // 144

typedef __hip_bfloat16 bf16;

__device__ __forceinline__ float getv(const float* p, long i) { return p[i]; }
__device__ __forceinline__ float getv(const bf16* p, long i) {
    unsigned int u = ((unsigned int)((const unsigned short*)p)[i]) << 16;
    return __uint_as_float(u);
}
__device__ __forceinline__ void putv(float* p, long i, float v) { p[i] = v; }
__device__ __forceinline__ void putv(bf16* p, long i, float v) { p[i] = __float2bfloat16(v); }
__device__ __forceinline__ float sigm(float x) { return 1.0f / (1.0f + __expf(-x)); }
__device__ __forceinline__ float tanh_(float x) { return 1.0f - 2.0f / (__expf(2.0f * x) + 1.0f); }

__device__ __forceinline__ void load4(const float* row, int x0, float* d) {
    const float4 v = *(const float4*)(row + x0);
    d[0] = v.x; d[1] = v.y; d[2] = v.z; d[3] = v.w;
}
__device__ __forceinline__ void load4(const bf16* row, int x0, float* d) {
    ushort4 u = *(const ushort4*)((const unsigned short*)row + x0);
    d[0] = __uint_as_float(((unsigned int)u.x) << 16);
    d[1] = __uint_as_float(((unsigned int)u.y) << 16);
    d[2] = __uint_as_float(((unsigned int)u.z) << 16);
    d[3] = __uint_as_float(((unsigned int)u.w) << 16);
}

// ---------------------------------------------------------------------------
// XCD-aware bijective chunked swizzle (T1, m204 formula). Proven R17:
// k_offmod FETCH 85 -> 15.4 MB. Keep everywhere.
// ---------------------------------------------------------------------------
__device__ __forceinline__ int xcd_chunked(int i, int nwg) {
    int q = nwg >> 3, r = nwg & 7;
    int xcd = i & 7, idx = i >> 3;
    return (xcd < r ? xcd * (q + 1) : r * (q + 1) + (xcd - r) * q) + idx;
}

// ---------------------------------------------------------------------------
// Dtype probe (bf16 vs float32 inputs) -> flag in d_ws.
// ---------------------------------------------------------------------------
__global__ void __launch_bounds__(256) k_detect(const void* lstm_w_raw, int* flag)
{
    __shared__ int bad;
    if (threadIdx.x == 0) bad = 0;
    __syncthreads();
    const unsigned short* u = (const unsigned short*)lstm_w_raw;
    int local = 0;
    for (int i = threadIdx.x; i < GATES * TAPS_L; i += 256) {
        unsigned int f32 = ((unsigned int)u[i]) << 16;
        float v = __uint_as_float(f32);
        if (!(fabsf(v) <= 64.0f)) local = 1;
    }
    if (local) atomicOr(&bad, 1);
    __syncthreads();
    if (threadIdx.x == 0) flag[0] = bad ? 0 : 1;
}

// ---------------------------------------------------------------------------
// ConvLSTM step (R19 proven form: register-staged weights, swizzle).
// ---------------------------------------------------------------------------
template <typename S>
__device__ __forceinline__ void conv_plane2r(
    const S* __restrict__ src, int cin, int y0, int x0, int kc,
    const float* __restrict__ sw, float (&acc)[2][4][4])
{
    float xs[4][6];  // rows y0-1 .. y0+2
#pragma unroll
    for (int r = 0; r < 4; r++) {
        int yy = y0 - 1 + r;
        if (yy >= 0 && yy < Hc) {
            const S* row = src + (long)yy * Wc;
            xs[r][0] = (x0 > 0) ? getv(row, x0 - 1) : 0.0f;
            load4(row, x0, &xs[r][1]);
            xs[r][5] = (x0 + 4 < Wc) ? getv(row, x0 + 4) : 0.0f;
        } else {
#pragma unroll
            for (int j = 0; j < 6; j++) xs[r][j] = 0.0f;
        }
    }
    float4 wq[9];   // register-staged weight quads
#pragma unroll
    for (int t9 = 0; t9 < 9; t9++)
        wq[t9] = *(const float4*)&sw[(((cin * 9 + t9) * 16) + kc) * 4];
#pragma unroll
    for (int ky = 0; ky < 3; ky++) {
#pragma unroll
        for (int kx = 0; kx < 3; kx++) {
            const float4 w = wq[ky * 3 + kx];
#pragma unroll
            for (int px = 0; px < 4; px++) {
                float v0 = xs[ky][px + kx];      // output row y0
                float v1 = xs[ky + 1][px + kx];  // output row y0+1
                acc[0][0][px] += w.x * v0;  acc[1][0][px] += w.x * v1;
                acc[0][1][px] += w.y * v0;  acc[1][1][px] += w.y * v1;
                acc[0][2][px] += w.z * v0;  acc[1][2][px] += w.z * v1;
                acc[0][3][px] += w.w * v0;  acc[1][3][px] += w.w * v1;
            }
        }
    }
}

template <typename T>
__device__ __forceinline__ void lstm2r_body(
    const T* __restrict__ X, const T* __restrict__ lstm_w, const T* __restrict__ lstm_b,
    const T* __restrict__ Wci, const T* __restrict__ Wcf, const T* __restrict__ Wco,
    float* __restrict__ c_buf, float* __restrict__ xcat, int t,
    float* sw, float* sb)
{
    for (int i = threadIdx.x; i < GATES * TAPS_L; i += 256) {
        int co = i / TAPS_L, tap = i - co * TAPS_L;
        int kc = co & 15, g = co >> 4;
        sw[(tap * 16 + kc) * 4 + g] = getv(lstm_w, i);
    }
    if (threadIdx.x < GATES) sb[threadIdx.x] = getv(lstm_b, threadIdx.x);
    __syncthreads();

    int blk = xcd_chunked(blockIdx.x, Bn * 90 * 5);  // 900; row-sharers same XCD
    int seg = blk % 5; int rem = blk / 5;
    int yp = rem % 90; int b = rem / 90;
    int y0 = yp * 2;
    int kc = threadIdx.x >> 4, pl = threadIdx.x & 15;
    int x0 = seg * 64 + pl * 4;

    float acc[2][4][4];  // [row][gate][px]
#pragma unroll
    for (int px = 0; px < 4; px++) {
#pragma unroll
        for (int r = 0; r < 2; r++) {
            acc[r][0][px] = sb[kc];
            acc[r][1][px] = sb[16 + kc];
            acc[r][2][px] = sb[32 + kc];
            acc[r][3][px] = sb[48 + kc];
        }
    }

    const T* xt = X + (long)(b * Tn + t) * NCc * HWc;
#pragma unroll 1
    for (int cin = 0; cin < NCc; cin++)
        conv_plane2r(xt + (long)cin * HWc, cin, y0, x0, kc, sw, acc);
    if (t > 0) {
        const float* hp = xcat + ((long)b * CIN_D + (t - 1) * NKc) * HWc;
#pragma unroll 1
        for (int cin = 0; cin < NKc; cin++)
            conv_plane2r(hp + (long)cin * HWc, cin + NCc, y0, x0, kc, sw, acc);
    }

#pragma unroll
    for (int r = 0; r < 2; r++) {
        int y = y0 + r;
        long pbase = (long)y * Wc + x0;
        float* cb = c_buf + (long)(b * NKc + kc) * HWc + pbase;
        float cprev[4];
        if (t > 0) {
            const float4 cv = *(const float4*)cb;
            cprev[0] = cv.x; cprev[1] = cv.y; cprev[2] = cv.z; cprev[3] = cv.w;
        } else {
            cprev[0] = cprev[1] = cprev[2] = cprev[3] = 0.0f;
        }
        float wci[4], wcf[4], wco[4];
        load4(Wci + (long)kc * HWc + pbase, 0, wci);
        load4(Wcf + (long)kc * HWc + pbase, 0, wcf);
        load4(Wco + (long)kc * HWc + pbase, 0, wco);

        float cn4[4], h4[4];
#pragma unroll
        for (int px = 0; px < 4; px++) {
            float ii = sigm(acc[r][0][px] + wci[px] * cprev[px]);
            float ff = sigm(acc[r][1][px] + wcf[px] * cprev[px]);
            float cn = ff * cprev[px] + ii * tanh_(acc[r][2][px]);
            float oo = sigm(acc[r][3][px] + wco[px] * cn);
            cn4[px] = cn; h4[px] = oo * tanh_(cn);
        }
        *(float4*)cb = make_float4(cn4[0], cn4[1], cn4[2], cn4[3]);
        *(float4*)(xcat + ((long)b * CIN_D + t * NKc + kc) * HWc + pbase) =
            make_float4(h4[0], h4[1], h4[2], h4[3]);
    }
}

__global__ void __launch_bounds__(256) k_lstm2(
    const void* X, const void* lstm_w, const void* lstm_b,
    const void* Wci, const void* Wcf, const void* Wco,
    const int* __restrict__ flag,
    float* c_buf, float* xcat, int t)
{
    __shared__ float sw[TAPS_L * GATES];  // 43.8 KB
    __shared__ float sb[GATES];
    if (flag[0])
        lstm2r_body<bf16>((const bf16*)X, (const bf16*)lstm_w, (const bf16*)lstm_b,
                          (const bf16*)Wci, (const bf16*)Wcf, (const bf16*)Wco,
                          c_buf, xcat, t, sw, sb);
    else
        lstm2r_body<float>((const float*)X, (const float*)lstm_w, (const float*)lstm_b,
                           (const float*)Wci, (const float*)Wcf, (const float*)Wco,
                           c_buf, xcat, t, sw, sb);
}

// ---------------------------------------------------------------------------
// offmod v11 (ROUND-20): FAT THREADS — 8 px/thread, 512-px chunks, grid 450.
// Per cin: 4 VMEM (2 aligned b128 + 2 halo scalars) feed 288 FMAs (3.2x
// fewer loads/FMA than 4px).  acc[4][8]+xs[3][10] = ~62 long-lived floats
// force the allocator to high VGPR, which is what finally lets loads batch
// (R19 falsifier: at 4px the compiler re-sank staged loads to VGPR=60).
// Waves drop 3600->1800 — acceptable: R14 proved the kernel isn't TLP-bound.
// ---------------------------------------------------------------------------
template <typename T>
__device__ __forceinline__ void offmod11_body(
    const float* __restrict__ xcat,
    const T* __restrict__ off_w, const T* __restrict__ off_b,
    const T* __restrict__ mod_w, const T* __restrict__ mod_b,
    float* __restrict__ offbuf, float* __restrict__ maskbuf,
    float* sw, float* sb)
{
    int rb = xcd_chunked(blockIdx.x, 450);
    int type = rb & 1;
    int chunk = rb >> 1;          // [0,225)
    const int nslot = type ? 12 : 16;

    for (int i = threadIdx.x; i < TAPS_D * nslot; i += 256) {
        int tap = i / nslot, j = i - tap * nslot;
        int o = type ? 16 + j : j;
        float v = 0.0f;
        if (o < 18) v = getv(off_w, (long)o * TAPS_D + tap);
        else if (o < 27) v = getv(mod_w, (long)(o - 18) * TAPS_D + tap);
        sw[tap * nslot + j] = v;
    }
    if (threadIdx.x < nslot) {
        int o = (type ? 16 : 0) + threadIdx.x;
        sb[threadIdx.x] = (o < 18) ? getv(off_b, o)
                        : (o < 27 ? getv(mod_b, o - 18) : 0.0f);
    }
    __syncthreads();

    int og = threadIdx.x >> 6, lane = threadIdx.x & 63;
    long p0 = (long)chunk * 512 + lane * 8;
    int b = (int)(p0 / HWc);
    int p = (int)(p0 - (long)b * HWc);
    int y = p / Wc, x0 = p - (p / Wc) * Wc;   // x0 multiple of 8

    const int per = type ? 3 : 4;
    int jbase = og * per;

    float acc[4][8];
#pragma unroll
    for (int j = 0; j < 4; j++) {
        float bv = (j < per) ? sb[jbase + j] : 0.0f;
#pragma unroll
        for (int px = 0; px < 8; px++) acc[j][px] = bv;
    }

    const float* xb = xcat + (long)b * CIN_D * HWc;
    if (type == 0) {
#pragma unroll 1
        for (int cin = 0; cin < CIN_D; cin++) {
            const float* xc = xb + (long)cin * HWc;
            float xs[3][10];   // px window [x0-1 .. x0+8]
#pragma unroll
            for (int ky = 0; ky < 3; ky++) {
                int yy = y + ky - 1;
                if (yy >= 0 && yy < Hc) {
                    const float* row = xc + (long)yy * Wc;
                    const float4 a = *(const float4*)(row + x0);
                    const float4 c = *(const float4*)(row + x0 + 4);
                    xs[ky][0] = (x0 > 0) ? row[x0 - 1] : 0.0f;
                    xs[ky][1] = a.x; xs[ky][2] = a.y; xs[ky][3] = a.z; xs[ky][4] = a.w;
                    xs[ky][5] = c.x; xs[ky][6] = c.y; xs[ky][7] = c.z; xs[ky][8] = c.w;
                    xs[ky][9] = (x0 + 8 < Wc) ? row[x0 + 8] : 0.0f;
                } else {
#pragma unroll
                    for (int j = 0; j < 10; j++) xs[ky][j] = 0.0f;
                }
            }
            float4 wr[9];
#pragma unroll
            for (int t9 = 0; t9 < 9; t9++)
                wr[t9] = *(const float4*)&sw[(cin * 9 + t9) * 16 + jbase];
#pragma unroll
            for (int ky = 0; ky < 3; ky++) {
#pragma unroll
                for (int kx = 0; kx < 3; kx++) {
                    const float4 wq = wr[ky * 3 + kx];
#pragma unroll
                    for (int px = 0; px < 8; px++) {
                        float v = xs[ky][px + kx];
                        acc[0][px] += wq.x * v;
                        acc[1][px] += wq.y * v;
                        acc[2][px] += wq.z * v;
                        acc[3][px] += wq.w * v;
                    }
                }
            }
        }
    } else {
#pragma unroll 1
        for (int cin = 0; cin < CIN_D; cin++) {
            const float* xc = xb + (long)cin * HWc;
            float xs[3][10];
#pragma unroll
            for (int ky = 0; ky < 3; ky++) {
                int yy = y + ky - 1;
                if (yy >= 0 && yy < Hc) {
                    const float* row = xc + (long)yy * Wc;
                    const float4 a = *(const float4*)(row + x0);
                    const float4 c = *(const float4*)(row + x0 + 4);
                    xs[ky][0] = (x0 > 0) ? row[x0 - 1] : 0.0f;
                    xs[ky][1] = a.x; xs[ky][2] = a.y; xs[ky][3] = a.z; xs[ky][4] = a.w;
                    xs[ky][5] = c.x; xs[ky][6] = c.y; xs[ky][7] = c.z; xs[ky][8] = c.w;
                    xs[ky][9] = (x0 + 8 < Wc) ? row[x0 + 8] : 0.0f;
                } else {
#pragma unroll
                    for (int j = 0; j < 10; j++) xs[ky][j] = 0.0f;
                }
            }
            float3 wr[9];
#pragma unroll
            for (int t9 = 0; t9 < 9; t9++) {
                const float* wp = &sw[(cin * 9 + t9) * 12 + jbase];
                wr[t9] = make_float3(wp[0], wp[1], wp[2]);
            }
#pragma unroll
            for (int ky = 0; ky < 3; ky++) {
#pragma unroll
                for (int kx = 0; kx < 3; kx++) {
                    const float3 wq = wr[ky * 3 + kx];
#pragma unroll
                    for (int px = 0; px < 8; px++) {
                        float v = xs[ky][px + kx];
                        acc[0][px] += wq.x * v;
                        acc[1][px] += wq.y * v;
                        acc[2][px] += wq.z * v;
                    }
                }
            }
        }
    }

    long pbase = (long)y * Wc + x0;
#pragma unroll
    for (int j = 0; j < 4; j++) {
        if (j >= per) break;
        int o = (type ? 16 : 0) + jbase + j;
        if (o >= 27) break;
        if (o < 18) {
            float* dst = offbuf + ((long)b * 18 + o) * HWc + pbase;
            *(float4*)dst = make_float4(acc[j][0], acc[j][1], acc[j][2], acc[j][3]);
            *(float4*)(dst + 4) = make_float4(acc[j][4], acc[j][5], acc[j][6], acc[j][7]);
        } else {
            float* dst = maskbuf + ((long)b * 9 + (o - 18)) * HWc + pbase;
            *(float4*)dst = make_float4(2.0f * sigm(acc[j][0]), 2.0f * sigm(acc[j][1]),
                                        2.0f * sigm(acc[j][2]), 2.0f * sigm(acc[j][3]));
            *(float4*)(dst + 4) = make_float4(2.0f * sigm(acc[j][4]), 2.0f * sigm(acc[j][5]),
                                              2.0f * sigm(acc[j][6]), 2.0f * sigm(acc[j][7]));
        }
    }
}

__global__ void __launch_bounds__(256) k_offmod(
    const float* xcat, const void* off_w, const void* off_b,
    const void* mod_w, const void* mod_b, const int* __restrict__ flag,
    float* offbuf, float* maskbuf)
{
    __shared__ float sw[TAPS_D * 16];  // 36.9 KB (type A); type B uses 27.6 KB
    __shared__ float sb[16];
    if (flag[0])
        offmod11_body<bf16>(xcat, (const bf16*)off_w, (const bf16*)off_b,
                            (const bf16*)mod_w, (const bf16*)mod_b, offbuf, maskbuf, sw, sb);
    else
        offmod11_body<float>(xcat, (const float*)off_w, (const float*)off_b,
                             (const float*)mod_w, (const float*)mod_b, offbuf, maskbuf, sw, sb);
}

// ---------------------------------------------------------------------------
// deform v3 (R11 body + R17 swizzle; no launch_bounds meddling).
// ---------------------------------------------------------------------------
template <typename T>
__device__ __forceinline__ void deform3_body(
    const float* __restrict__ xcat, const float* __restrict__ offbuf,
    const float* __restrict__ maskbuf,
    const T* __restrict__ def_w, const T* __restrict__ def_b,
    float* __restrict__ dcout, float* sw, float* sb)
{
    for (int i = threadIdx.x; i < NKc * TAPS_D; i += 256) {
        int co = i / TAPS_D;
        int tap = i - co * TAPS_D;
        sw[tap * NKc + co] = getv(def_w, i);
    }
    if (threadIdx.x < NKc) sb[threadIdx.x] = getv(def_b, threadIdx.x);
    __syncthreads();

    int idx = xcd_chunked(blockIdx.x, NPIX / 256) * 256 + threadIdx.x;
    int b = idx / HWc;
    int p = idx - b * HWc;
    int y = p / Wc, x = p - (p / Wc) * Wc;

    float w00[9], w01[9], w10[9], w11[9];
    int i00[9], i01[9], i10[9], i11[9];
#pragma unroll
    for (int k = 0; k < 9; k++) {
        int ky = k / 3, kx = k - (k / 3) * 3;
        float dy = offbuf[((long)b * 18 + 2 * k) * HWc + p];
        float dx = offbuf[((long)b * 18 + 2 * k + 1) * HWc + p];
        float m = maskbuf[((long)b * 9 + k) * HWc + p];
        float py = (float)(y - 1 + ky) + dy;
        float px = (float)(x - 1 + kx) + dx;
        float y0f = floorf(py), x0f = floorf(px);
        int y0 = (int)y0f, x0 = (int)x0f;
        float wy1 = py - y0f, wx1 = px - x0f;
        float a00 = (1.0f - wy1) * (1.0f - wx1) * m;
        float a01 = (1.0f - wy1) * wx1 * m;
        float a10 = wy1 * (1.0f - wx1) * m;
        float a11 = wy1 * wx1 * m;
        bool vy0 = (y0 >= 0) && (y0 < Hc);
        bool vy1 = (y0 + 1 >= 0) && (y0 + 1 < Hc);
        bool vx0 = (x0 >= 0) && (x0 < Wc);
        bool vx1 = (x0 + 1 >= 0) && (x0 + 1 < Wc);
        w00[k] = (vy0 && vx0) ? a00 : 0.0f;
        w01[k] = (vy0 && vx1) ? a01 : 0.0f;
        w10[k] = (vy1 && vx0) ? a10 : 0.0f;
        w11[k] = (vy1 && vx1) ? a11 : 0.0f;
        int yc0 = min(max(y0, 0), Hc - 1);
        int yc1 = min(max(y0 + 1, 0), Hc - 1);
        int xc0 = min(max(x0, 0), Wc - 1);
        int xc1 = min(max(x0 + 1, 0), Wc - 1);
        i00[k] = yc0 * Wc + xc0; i01[k] = yc0 * Wc + xc1;
        i10[k] = yc1 * Wc + xc0; i11[k] = yc1 * Wc + xc1;
    }

    float acc[NKc];
#pragma unroll
    for (int i = 0; i < NKc; i++) acc[i] = sb[i];

    const float* xb = xcat + (long)b * CIN_D * HWc;
#pragma unroll 1
    for (int cin = 0; cin < CIN_D; cin++) {
        const float* xc = xb + (long)cin * HWc;
        float s[9];
#pragma unroll
        for (int k = 0; k < 9; k++)
            s[k] = w00[k] * xc[i00[k]] + w01[k] * xc[i01[k]] +
                   w10[k] * xc[i10[k]] + w11[k] * xc[i11[k]];
#pragma unroll
        for (int k = 0; k < 9; k++) {
            const float* wrow = &sw[(cin * 9 + k) * NKc];
#pragma unroll
            for (int co = 0; co < NKc; co++) acc[co] += wrow[co] * s[k];
        }
    }

#pragma unroll
    for (int co = 0; co < NKc; co++)
        dcout[((long)b * NKc + co) * HWc + p] = acc[co];
}

__global__ void __launch_bounds__(256) k_deform(
    const float* xcat, const float* offbuf, const float* maskbuf,
    const void* def_w, const void* def_b, const int* __restrict__ flag,
    float* dcout)
{
    __shared__ float sw[TAPS_D * NKc];  // 36.9 KB
    __shared__ float sb[NKc];
    if (flag[0])
        deform3_body<bf16>(xcat, offbuf, maskbuf, (const bf16*)def_w, (const bf16*)def_b,
                           dcout, sw, sb);
    else
        deform3_body<float>(xcat, offbuf, maskbuf, (const float*)def_w, (const float*)def_b,
                            dcout, sw, sb);
}

// ---------------------------------------------------------------------------
// outconv v8 (R19 proven form: register-staged weights + hoisted xs rows).
// ---------------------------------------------------------------------------
template <typename T>
__device__ __forceinline__ void outconv6_body(
    const float* __restrict__ dcout, const T* __restrict__ out_w,
    const T* __restrict__ out_b, T* __restrict__ out, float* sw, float* sb)
{
    int rb = xcd_chunked(blockIdx.x, 900);
    int type = rb & 1;
    int chunk = rb >> 1;

    for (int i = threadIdx.x; i < 24 * TAPS_O; i += 256) {
        int o = i / TAPS_O, tap = i - o * TAPS_O;
        int slot = (o / 6) * 8 + (o % 6);
        sw[tap * 32 + slot] = getv(out_w, (long)(type * 24 + o) * TAPS_O + tap);
    }
    if (threadIdx.x < 24) sb[threadIdx.x] = getv(out_b, type * 24 + threadIdx.x);
    __syncthreads();

    int og = threadIdx.x >> 6, lane = threadIdx.x & 63;
    long p0 = ((long)chunk * 64 + lane) * 4;
    int b = (int)(p0 / HWc);
    int p = (int)(p0 - (long)b * HWc);
    int y = p / Wc, x0 = p - (p / Wc) * Wc;

    float acc[6][4];
#pragma unroll
    for (int j = 0; j < 6; j++) {
        float bv = sb[og * 6 + j];
#pragma unroll
        for (int px = 0; px < 4; px++) acc[j][px] = bv;
    }

    const float* xb = dcout + (long)b * NKc * HWc;
#pragma unroll 1
    for (int cin = 0; cin < NKc; cin++) {
        const float* xc = xb + (long)cin * HWc;
        float xs[3][6];
#pragma unroll
        for (int ky = 0; ky < 3; ky++) {
            int yy = y + ky - 1;
            if (yy >= 0 && yy < Hc) {
                const float* row = xc + (long)yy * Wc;
                xs[ky][0] = (x0 > 0) ? row[x0 - 1] : 0.0f;
                load4(row, x0, &xs[ky][1]);
                xs[ky][5] = (x0 + 4 < Wc) ? row[x0 + 4] : 0.0f;
            } else {
#pragma unroll
                for (int j = 0; j < 6; j++) xs[ky][j] = 0.0f;
            }
        }
        float4 wa[9]; float2 wb[9];
#pragma unroll
        for (int t9 = 0; t9 < 9; t9++) {
            const float* wp = &sw[(cin * 9 + t9) * 32 + og * 8];
            wa[t9] = *(const float4*)wp;
            wb[t9] = *(const float2*)(wp + 4);
        }
#pragma unroll
        for (int ky = 0; ky < 3; ky++) {
#pragma unroll
            for (int kx = 0; kx < 3; kx++) {
                const float4 w0 = wa[ky * 3 + kx];
                const float2 w1 = wb[ky * 3 + kx];
#pragma unroll
                for (int px = 0; px < 4; px++) {
                    float v = xs[ky][px + kx];
                    acc[0][px] += w0.x * v;  acc[1][px] += w0.y * v;
                    acc[2][px] += w0.z * v;  acc[3][px] += w0.w * v;
                    acc[4][px] += w1.x * v;  acc[5][px] += w1.y * v;
                }
            }
        }
    }

#pragma unroll
    for (int j = 0; j < 6; j++) {
        int co = type * 24 + og * 6 + j;
        int cc = co >> 4;
        int r = co & 15;
        int ii = r >> 2, jj = r & 3;
        long ob = (((long)b * 3 + cc) * (Hc * 4) + (y * 4 + ii)) * (long)(Wc * 4);
#pragma unroll
        for (int px = 0; px < 4; px++) {
            float v = fminf(fmaxf(acc[j][px], 0.0f), 255.0f);
            putv(out, ob + (x0 + px) * 4 + jj, v);
        }
    }
}

__global__ void __launch_bounds__(256) k_outconv(
    const float* dcout, const void* out_w, const void* out_b,
    const int* __restrict__ flag, void* out)
{
    __shared__ float sw[TAPS_O * 32];  // 18.4 KB
    __shared__ float sb[24];
    if (flag[0])
        outconv6_body<bf16>(dcout, (const bf16*)out_w, (const bf16*)out_b, (bf16*)out, sw, sb);
    else
        outconv6_body<float>(dcout, (const float*)out_w, (const float*)out_b, (float*)out, sw, sb);
}

extern "C" void kernel_launch(void* const* d_in, const int* in_sizes, int n_in,
                              void* d_out, int out_size, void* d_ws, size_t ws_size,
                              hipStream_t stream) {
    const void* X      = d_in[0];
    const void* lstm_w = d_in[1];
    const void* lstm_b = d_in[2];
    const void* Wci    = d_in[3];
    const void* Wcf    = d_in[4];
    const void* Wco    = d_in[5];
    const void* off_w  = d_in[6];
    const void* off_b  = d_in[7];
    const void* mod_w  = d_in[8];
    const void* mod_b  = d_in[9];
    const void* def_w  = d_in[10];
    const void* def_b  = d_in[11];
    const void* out_w  = d_in[12];
    const void* out_b  = d_in[13];

    int* flag = (int*)d_ws;
    float* W = (float*)d_ws + 64;
    size_t o = 0;
    float* c_buf   = W + o; o += (size_t)Bn * NKc * HWc;
    float* xcat    = W + o; o += (size_t)Bn * CIN_D * HWc;
    float* offbuf  = W + o; o += (size_t)Bn * 18 * HWc;
    float* maskbuf = W + o; o += (size_t)Bn * 9 * HWc;
    float* dcout   = W + o; o += (size_t)Bn * NKc * HWc;

    dim3 blk(256);
    dim3 gridP(NPIX / 256);           // 450
    dim3 gridL2(Bn * (Hc / 2) * 5);   // 900: 2-row lstm blocks
    dim3 gridOM(2 * (NPIX / 512));    // 450: fat-thread offmod (8px/lane)
    dim3 gridC2(2 * (NPIX / 4 / 64)); // 900

    k_detect<<<1, blk, 0, stream>>>(lstm_w, flag);
    for (int t = 0; t < Tn; t++) {
        k_lstm2<<<gridL2, blk, 0, stream>>>(X, lstm_w, lstm_b, Wci, Wcf, Wco,
                                            flag, c_buf, xcat, t);
    }
    k_offmod<<<gridOM, blk, 0, stream>>>(xcat, off_w, off_b, mod_w, mod_b, flag,
                                         offbuf, maskbuf);
    k_deform<<<gridP, blk, 0, stream>>>(xcat, offbuf, maskbuf, def_w, def_b, flag, dcout);
    k_outconv<<<gridC2, blk, 0, stream>>>(dcout, out_w, out_b, flag, d_out);
}

// Round 8
// 696.260 us; speedup vs baseline: 1.2463x; 1.0157x over previous
//
#include <hip/hip_runtime.h>
#include <hip/hip_bf16.h>

// Problem dims
#define Bn 2
#define Tn 4
#define NCc 3
#define NKc 16
#define Hc 180
#define Wc 320
#define HWc (Hc * Wc)          // 57600
#define NPIX (Bn * HWc)        // 115200
#define CIN_LSTM 19            // NC + NK
#define GATES 64               // 4*NK
#define CIN_D 64               // T*NK
#define TAPS_L (CIN_LSTM * 9)  // 171
#define TAPS_D (CIN_D * 9)     // 576
#define TAPS_O (NKc * 9)       // 144

typedef __hip_bfloat16 bf16;
typedef float f32x4 __attribute__((ext_vector_type(4)));

__device__ __forceinline__ float getv(const float* p, long i) { return p[i]; }
__device__ __forceinline__ float getv(const bf16* p, long i) {
    unsigned int u = ((unsigned int)((const unsigned short*)p)[i]) << 16;
    return __uint_as_float(u);
}
__device__ __forceinline__ void putv(float* p, long i, float v) { p[i] = v; }
__device__ __forceinline__ void putv(bf16* p, long i, float v) { p[i] = __float2bfloat16(v); }
__device__ __forceinline__ float sigm(float x) { return 1.0f / (1.0f + __expf(-x)); }
__device__ __forceinline__ float tanh_(float x) { return 1.0f - 2.0f / (__expf(2.0f * x) + 1.0f); }

__device__ __forceinline__ void load4(const float* row, int x0, float* d) {
    const float4 v = *(const float4*)(row + x0);
    d[0] = v.x; d[1] = v.y; d[2] = v.z; d[3] = v.w;
}
__device__ __forceinline__ void load4(const bf16* row, int x0, float* d) {
    ushort4 u = *(const ushort4*)((const unsigned short*)row + x0);
    d[0] = __uint_as_float(((unsigned int)u.x) << 16);
    d[1] = __uint_as_float(((unsigned int)u.y) << 16);
    d[2] = __uint_as_float(((unsigned int)u.z) << 16);
    d[3] = __uint_as_float(((unsigned int)u.w) << 16);
}

// ---------------------------------------------------------------------------
// XCD-aware bijective chunked swizzle (T1, m204 formula). Proven R17.
// ---------------------------------------------------------------------------
__device__ __forceinline__ int xcd_chunked(int i, int nwg) {
    int q = nwg >> 3, r = nwg & 7;
    int xcd = i & 7, idx = i >> 3;
    return (xcd < r ? xcd * (q + 1) : r * (q + 1) + (xcd - r) * q) + idx;
}

// ---------------------------------------------------------------------------
// ROUND-21: force-batched row loads.  Twelve global_loads issued in ONE asm
// blob with early-clobber outputs — the allocator must keep all 30 result
// VGPRs live, so the loads pipeline instead of the load-wait-use serial
// chain the compiler kept producing (R19: staged loads re-sunk at VGPR=60;
// R20 arithmetic: ~2100cy stall/cin = 12 loads x ~175cy serialized).
// Halos come from offset:-4 / offset:32 on the same base (reads clamp-row
// garbage at image edges; zeroed afterwards by 0/1 mask multiplies).
// ---------------------------------------------------------------------------
__device__ __forceinline__ void om_issue12(
    const float* p0, const float* p1, const float* p2,
    f32x4& a0, f32x4& b0, float& h00, float& h01,
    f32x4& a1, f32x4& b1, float& h10, float& h11,
    f32x4& a2, f32x4& b2, float& h20, float& h21)
{
    asm volatile(
        "global_load_dwordx4 %[A0], %[p0], off\n\t"
        "global_load_dwordx4 %[B0], %[p0], off offset:16\n\t"
        "global_load_dword   %[H00], %[p0], off offset:-4\n\t"
        "global_load_dword   %[H01], %[p0], off offset:32\n\t"
        "global_load_dwordx4 %[A1], %[p1], off\n\t"
        "global_load_dwordx4 %[B1], %[p1], off offset:16\n\t"
        "global_load_dword   %[H10], %[p1], off offset:-4\n\t"
        "global_load_dword   %[H11], %[p1], off offset:32\n\t"
        "global_load_dwordx4 %[A2], %[p2], off\n\t"
        "global_load_dwordx4 %[B2], %[p2], off offset:16\n\t"
        "global_load_dword   %[H20], %[p2], off offset:-4\n\t"
        "global_load_dword   %[H21], %[p2], off offset:32\n\t"
        : [A0]"=&v"(a0), [B0]"=&v"(b0), [H00]"=&v"(h00), [H01]"=&v"(h01),
          [A1]"=&v"(a1), [B1]"=&v"(b1), [H10]"=&v"(h10), [H11]"=&v"(h11),
          [A2]"=&v"(a2), [B2]"=&v"(b2), [H20]"=&v"(h20), [H21]"=&v"(h21)
        : [p0]"v"(p0), [p1]"v"(p1), [p2]"v"(p2));
}

__device__ __forceinline__ void om_wait()
{
    asm volatile("s_waitcnt vmcnt(0)" ::: "memory");
    __builtin_amdgcn_sched_barrier(0);   // rule #18: keep consumers below the wait
}

// ---------------------------------------------------------------------------
// Dtype probe (bf16 vs float32 inputs) -> flag in d_ws.
// ---------------------------------------------------------------------------
__global__ void __launch_bounds__(256) k_detect(const void* lstm_w_raw, int* flag)
{
    __shared__ int bad;
    if (threadIdx.x == 0) bad = 0;
    __syncthreads();
    const unsigned short* u = (const unsigned short*)lstm_w_raw;
    int local = 0;
    for (int i = threadIdx.x; i < GATES * TAPS_L; i += 256) {
        unsigned int f32 = ((unsigned int)u[i]) << 16;
        float v = __uint_as_float(f32);
        if (!(fabsf(v) <= 64.0f)) local = 1;
    }
    if (local) atomicOr(&bad, 1);
    __syncthreads();
    if (threadIdx.x == 0) flag[0] = bad ? 0 : 1;
}

// ---------------------------------------------------------------------------
// ConvLSTM step (R19 proven form: register-staged weights, swizzle).
// ---------------------------------------------------------------------------
template <typename S>
__device__ __forceinline__ void conv_plane2r(
    const S* __restrict__ src, int cin, int y0, int x0, int kc,
    const float* __restrict__ sw, float (&acc)[2][4][4])
{
    float xs[4][6];  // rows y0-1 .. y0+2
#pragma unroll
    for (int r = 0; r < 4; r++) {
        int yy = y0 - 1 + r;
        if (yy >= 0 && yy < Hc) {
            const S* row = src + (long)yy * Wc;
            xs[r][0] = (x0 > 0) ? getv(row, x0 - 1) : 0.0f;
            load4(row, x0, &xs[r][1]);
            xs[r][5] = (x0 + 4 < Wc) ? getv(row, x0 + 4) : 0.0f;
        } else {
#pragma unroll
            for (int j = 0; j < 6; j++) xs[r][j] = 0.0f;
        }
    }
    float4 wq[9];   // register-staged weight quads
#pragma unroll
    for (int t9 = 0; t9 < 9; t9++)
        wq[t9] = *(const float4*)&sw[(((cin * 9 + t9) * 16) + kc) * 4];
#pragma unroll
    for (int ky = 0; ky < 3; ky++) {
#pragma unroll
        for (int kx = 0; kx < 3; kx++) {
            const float4 w = wq[ky * 3 + kx];
#pragma unroll
            for (int px = 0; px < 4; px++) {
                float v0 = xs[ky][px + kx];      // output row y0
                float v1 = xs[ky + 1][px + kx];  // output row y0+1
                acc[0][0][px] += w.x * v0;  acc[1][0][px] += w.x * v1;
                acc[0][1][px] += w.y * v0;  acc[1][1][px] += w.y * v1;
                acc[0][2][px] += w.z * v0;  acc[1][2][px] += w.z * v1;
                acc[0][3][px] += w.w * v0;  acc[1][3][px] += w.w * v1;
            }
        }
    }
}

template <typename T>
__device__ __forceinline__ void lstm2r_body(
    const T* __restrict__ X, const T* __restrict__ lstm_w, const T* __restrict__ lstm_b,
    const T* __restrict__ Wci, const T* __restrict__ Wcf, const T* __restrict__ Wco,
    float* __restrict__ c_buf, float* __restrict__ xcat, int t,
    float* sw, float* sb)
{
    for (int i = threadIdx.x; i < GATES * TAPS_L; i += 256) {
        int co = i / TAPS_L, tap = i - co * TAPS_L;
        int kc = co & 15, g = co >> 4;
        sw[(tap * 16 + kc) * 4 + g] = getv(lstm_w, i);
    }
    if (threadIdx.x < GATES) sb[threadIdx.x] = getv(lstm_b, threadIdx.x);
    __syncthreads();

    int blk = xcd_chunked(blockIdx.x, Bn * 90 * 5);  // 900; row-sharers same XCD
    int seg = blk % 5; int rem = blk / 5;
    int yp = rem % 90; int b = rem / 90;
    int y0 = yp * 2;
    int kc = threadIdx.x >> 4, pl = threadIdx.x & 15;
    int x0 = seg * 64 + pl * 4;

    float acc[2][4][4];  // [row][gate][px]
#pragma unroll
    for (int px = 0; px < 4; px++) {
#pragma unroll
        for (int r = 0; r < 2; r++) {
            acc[r][0][px] = sb[kc];
            acc[r][1][px] = sb[16 + kc];
            acc[r][2][px] = sb[32 + kc];
            acc[r][3][px] = sb[48 + kc];
        }
    }

    const T* xt = X + (long)(b * Tn + t) * NCc * HWc;
#pragma unroll 1
    for (int cin = 0; cin < NCc; cin++)
        conv_plane2r(xt + (long)cin * HWc, cin, y0, x0, kc, sw, acc);
    if (t > 0) {
        const float* hp = xcat + ((long)b * CIN_D + (t - 1) * NKc) * HWc;
#pragma unroll 1
        for (int cin = 0; cin < NKc; cin++)
            conv_plane2r(hp + (long)cin * HWc, cin + NCc, y0, x0, kc, sw, acc);
    }

#pragma unroll
    for (int r = 0; r < 2; r++) {
        int y = y0 + r;
        long pbase = (long)y * Wc + x0;
        float* cb = c_buf + (long)(b * NKc + kc) * HWc + pbase;
        float cprev[4];
        if (t > 0) {
            const float4 cv = *(const float4*)cb;
            cprev[0] = cv.x; cprev[1] = cv.y; cprev[2] = cv.z; cprev[3] = cv.w;
        } else {
            cprev[0] = cprev[1] = cprev[2] = cprev[3] = 0.0f;
        }
        float wci[4], wcf[4], wco[4];
        load4(Wci + (long)kc * HWc + pbase, 0, wci);
        load4(Wcf + (long)kc * HWc + pbase, 0, wcf);
        load4(Wco + (long)kc * HWc + pbase, 0, wco);

        float cn4[4], h4[4];
#pragma unroll
        for (int px = 0; px < 4; px++) {
            float ii = sigm(acc[r][0][px] + wci[px] * cprev[px]);
            float ff = sigm(acc[r][1][px] + wcf[px] * cprev[px]);
            float cn = ff * cprev[px] + ii * tanh_(acc[r][2][px]);
            float oo = sigm(acc[r][3][px] + wco[px] * cn);
            cn4[px] = cn; h4[px] = oo * tanh_(cn);
        }
        *(float4*)cb = make_float4(cn4[0], cn4[1], cn4[2], cn4[3]);
        *(float4*)(xcat + ((long)b * CIN_D + t * NKc + kc) * HWc + pbase) =
            make_float4(h4[0], h4[1], h4[2], h4[3]);
    }
}

__global__ void __launch_bounds__(256) k_lstm2(
    const void* X, const void* lstm_w, const void* lstm_b,
    const void* Wci, const void* Wcf, const void* Wco,
    const int* __restrict__ flag,
    float* c_buf, float* xcat, int t)
{
    __shared__ float sw[TAPS_L * GATES];  // 43.8 KB
    __shared__ float sb[GATES];
    if (flag[0])
        lstm2r_body<bf16>((const bf16*)X, (const bf16*)lstm_w, (const bf16*)lstm_b,
                          (const bf16*)Wci, (const bf16*)Wcf, (const bf16*)Wco,
                          c_buf, xcat, t, sw, sb);
    else
        lstm2r_body<float>((const float*)X, (const float*)lstm_w, (const float*)lstm_b,
                           (const float*)Wci, (const float*)Wcf, (const float*)Wco,
                           c_buf, xcat, t, sw, sb);
}

// ---------------------------------------------------------------------------
// offmod v12 (ROUND-21): fat 8px threads (R20) + asm-batched row loads.
// ---------------------------------------------------------------------------
template <typename T>
__device__ __forceinline__ void offmod12_body(
    const float* __restrict__ xcat,
    const T* __restrict__ off_w, const T* __restrict__ off_b,
    const T* __restrict__ mod_w, const T* __restrict__ mod_b,
    float* __restrict__ offbuf, float* __restrict__ maskbuf,
    float* sw, float* sb)
{
    int rb = xcd_chunked(blockIdx.x, 450);
    int type = rb & 1;
    int chunk = rb >> 1;          // [0,225)
    const int nslot = type ? 12 : 16;

    for (int i = threadIdx.x; i < TAPS_D * nslot; i += 256) {
        int tap = i / nslot, j = i - tap * nslot;
        int o = type ? 16 + j : j;
        float v = 0.0f;
        if (o < 18) v = getv(off_w, (long)o * TAPS_D + tap);
        else if (o < 27) v = getv(mod_w, (long)(o - 18) * TAPS_D + tap);
        sw[tap * nslot + j] = v;
    }
    if (threadIdx.x < nslot) {
        int o = (type ? 16 : 0) + threadIdx.x;
        sb[threadIdx.x] = (o < 18) ? getv(off_b, o)
                        : (o < 27 ? getv(mod_b, o - 18) : 0.0f);
    }
    __syncthreads();

    int og = threadIdx.x >> 6, lane = threadIdx.x & 63;
    long p0 = (long)chunk * 512 + lane * 8;
    int b = (int)(p0 / HWc);
    int p = (int)(p0 - (long)b * HWc);
    int y = p / Wc, x0 = p - (p / Wc) * Wc;   // x0 multiple of 8

    const int per = type ? 3 : 4;
    int jbase = og * per;

    // Per-lane loop-invariant geometry: clamped row pointers + 0/1 masks.
    const float* xb = xcat + (long)b * CIN_D * HWc;
    long yo[3]; float vm[3];
#pragma unroll
    for (int ky = 0; ky < 3; ky++) {
        int yy = y + ky - 1;
        vm[ky] = (yy >= 0 && yy < Hc) ? 1.0f : 0.0f;
        yo[ky] = (long)min(max(yy, 0), Hc - 1) * Wc + x0;
    }
    const float m0 = (x0 > 0) ? 1.0f : 0.0f;
    const float m1 = (x0 + 8 < Wc) ? 1.0f : 0.0f;

    float acc[4][8];
#pragma unroll
    for (int j = 0; j < 4; j++) {
        float bv = (j < per) ? sb[jbase + j] : 0.0f;
#pragma unroll
        for (int px = 0; px < 8; px++) acc[j][px] = bv;
    }

    if (type == 0) {
#pragma unroll 1
        for (int cin = 0; cin < CIN_D; cin++) {
            const float* xc = xb + (long)cin * HWc;
            f32x4 a0, b0v, a1, b1v, a2, b2v;
            float h00, h01, h10, h11, h20, h21;
            om_issue12(xc + yo[0], xc + yo[1], xc + yo[2],
                       a0, b0v, h00, h01, a1, b1v, h10, h11, a2, b2v, h20, h21);
            float4 wr[9];
#pragma unroll
            for (int t9 = 0; t9 < 9; t9++)
                wr[t9] = *(const float4*)&sw[(cin * 9 + t9) * 16 + jbase];
            om_wait();
            float xs[3][10];
#pragma unroll
            for (int ky = 0; ky < 3; ky++) {
                const f32x4 a = (ky == 0) ? a0 : (ky == 1) ? a1 : a2;
                const f32x4 bb = (ky == 0) ? b0v : (ky == 1) ? b1v : b2v;
                const float hh0 = (ky == 0) ? h00 : (ky == 1) ? h10 : h20;
                const float hh1 = (ky == 0) ? h01 : (ky == 1) ? h11 : h21;
                xs[ky][0] = hh0 * vm[ky] * m0;
                xs[ky][1] = a.x * vm[ky]; xs[ky][2] = a.y * vm[ky];
                xs[ky][3] = a.z * vm[ky]; xs[ky][4] = a.w * vm[ky];
                xs[ky][5] = bb.x * vm[ky]; xs[ky][6] = bb.y * vm[ky];
                xs[ky][7] = bb.z * vm[ky]; xs[ky][8] = bb.w * vm[ky];
                xs[ky][9] = hh1 * vm[ky] * m1;
            }
#pragma unroll
            for (int ky = 0; ky < 3; ky++) {
#pragma unroll
                for (int kx = 0; kx < 3; kx++) {
                    const float4 wq = wr[ky * 3 + kx];
#pragma unroll
                    for (int px = 0; px < 8; px++) {
                        float v = xs[ky][px + kx];
                        acc[0][px] += wq.x * v;
                        acc[1][px] += wq.y * v;
                        acc[2][px] += wq.z * v;
                        acc[3][px] += wq.w * v;
                    }
                }
            }
        }
    } else {
#pragma unroll 1
        for (int cin = 0; cin < CIN_D; cin++) {
            const float* xc = xb + (long)cin * HWc;
            f32x4 a0, b0v, a1, b1v, a2, b2v;
            float h00, h01, h10, h11, h20, h21;
            om_issue12(xc + yo[0], xc + yo[1], xc + yo[2],
                       a0, b0v, h00, h01, a1, b1v, h10, h11, a2, b2v, h20, h21);
            float3 wr[9];
#pragma unroll
            for (int t9 = 0; t9 < 9; t9++) {
                const float* wp = &sw[(cin * 9 + t9) * 12 + jbase];
                wr[t9] = make_float3(wp[0], wp[1], wp[2]);
            }
            om_wait();
            float xs[3][10];
#pragma unroll
            for (int ky = 0; ky < 3; ky++) {
                const f32x4 a = (ky == 0) ? a0 : (ky == 1) ? a1 : a2;
                const f32x4 bb = (ky == 0) ? b0v : (ky == 1) ? b1v : b2v;
                const float hh0 = (ky == 0) ? h00 : (ky == 1) ? h10 : h20;
                const float hh1 = (ky == 0) ? h01 : (ky == 1) ? h11 : h21;
                xs[ky][0] = hh0 * vm[ky] * m0;
                xs[ky][1] = a.x * vm[ky]; xs[ky][2] = a.y * vm[ky];
                xs[ky][3] = a.z * vm[ky]; xs[ky][4] = a.w * vm[ky];
                xs[ky][5] = bb.x * vm[ky]; xs[ky][6] = bb.y * vm[ky];
                xs[ky][7] = bb.z * vm[ky]; xs[ky][8] = bb.w * vm[ky];
                xs[ky][9] = hh1 * vm[ky] * m1;
            }
#pragma unroll
            for (int ky = 0; ky < 3; ky++) {
#pragma unroll
                for (int kx = 0; kx < 3; kx++) {
                    const float3 wq = wr[ky * 3 + kx];
#pragma unroll
                    for (int px = 0; px < 8; px++) {
                        float v = xs[ky][px + kx];
                        acc[0][px] += wq.x * v;
                        acc[1][px] += wq.y * v;
                        acc[2][px] += wq.z * v;
                    }
                }
            }
        }
    }

    long pbase = (long)y * Wc + x0;
#pragma unroll
    for (int j = 0; j < 4; j++) {
        if (j >= per) break;
        int o = (type ? 16 : 0) + jbase + j;
        if (o >= 27) break;
        if (o < 18) {
            float* dst = offbuf + ((long)b * 18 + o) * HWc + pbase;
            *(float4*)dst = make_float4(acc[j][0], acc[j][1], acc[j][2], acc[j][3]);
            *(float4*)(dst + 4) = make_float4(acc[j][4], acc[j][5], acc[j][6], acc[j][7]);
        } else {
            float* dst = maskbuf + ((long)b * 9 + (o - 18)) * HWc + pbase;
            *(float4*)dst = make_float4(2.0f * sigm(acc[j][0]), 2.0f * sigm(acc[j][1]),
                                        2.0f * sigm(acc[j][2]), 2.0f * sigm(acc[j][3]));
            *(float4*)(dst + 4) = make_float4(2.0f * sigm(acc[j][4]), 2.0f * sigm(acc[j][5]),
                                              2.0f * sigm(acc[j][6]), 2.0f * sigm(acc[j][7]));
        }
    }
}

__global__ void __launch_bounds__(256) k_offmod(
    const float* xcat, const void* off_w, const void* off_b,
    const void* mod_w, const void* mod_b, const int* __restrict__ flag,
    float* offbuf, float* maskbuf)
{
    __shared__ float sw[TAPS_D * 16];  // 36.9 KB (type A); type B uses 27.6 KB
    __shared__ float sb[16];
    if (flag[0])
        offmod12_body<bf16>(xcat, (const bf16*)off_w, (const bf16*)off_b,
                            (const bf16*)mod_w, (const bf16*)mod_b, offbuf, maskbuf, sw, sb);
    else
        offmod12_body<float>(xcat, (const float*)off_w, (const float*)off_b,
                             (const float*)mod_w, (const float*)mod_b, offbuf, maskbuf, sw, sb);
}

// ---------------------------------------------------------------------------
// deform v3 (R11 body + R17 swizzle; untouched).
// ---------------------------------------------------------------------------
template <typename T>
__device__ __forceinline__ void deform3_body(
    const float* __restrict__ xcat, const float* __restrict__ offbuf,
    const float* __restrict__ maskbuf,
    const T* __restrict__ def_w, const T* __restrict__ def_b,
    float* __restrict__ dcout, float* sw, float* sb)
{
    for (int i = threadIdx.x; i < NKc * TAPS_D; i += 256) {
        int co = i / TAPS_D;
        int tap = i - co * TAPS_D;
        sw[tap * NKc + co] = getv(def_w, i);
    }
    if (threadIdx.x < NKc) sb[threadIdx.x] = getv(def_b, threadIdx.x);
    __syncthreads();

    int idx = xcd_chunked(blockIdx.x, NPIX / 256) * 256 + threadIdx.x;
    int b = idx / HWc;
    int p = idx - b * HWc;
    int y = p / Wc, x = p - (p / Wc) * Wc;

    float w00[9], w01[9], w10[9], w11[9];
    int i00[9], i01[9], i10[9], i11[9];
#pragma unroll
    for (int k = 0; k < 9; k++) {
        int ky = k / 3, kx = k - (k / 3) * 3;
        float dy = offbuf[((long)b * 18 + 2 * k) * HWc + p];
        float dx = offbuf[((long)b * 18 + 2 * k + 1) * HWc + p];
        float m = maskbuf[((long)b * 9 + k) * HWc + p];
        float py = (float)(y - 1 + ky) + dy;
        float px = (float)(x - 1 + kx) + dx;
        float y0f = floorf(py), x0f = floorf(px);
        int y0 = (int)y0f, x0 = (int)x0f;
        float wy1 = py - y0f, wx1 = px - x0f;
        float a00 = (1.0f - wy1) * (1.0f - wx1) * m;
        float a01 = (1.0f - wy1) * wx1 * m;
        float a10 = wy1 * (1.0f - wx1) * m;
        float a11 = wy1 * wx1 * m;
        bool vy0 = (y0 >= 0) && (y0 < Hc);
        bool vy1 = (y0 + 1 >= 0) && (y0 + 1 < Hc);
        bool vx0 = (x0 >= 0) && (x0 < Wc);
        bool vx1 = (x0 + 1 >= 0) && (x0 + 1 < Wc);
        w00[k] = (vy0 && vx0) ? a00 : 0.0f;
        w01[k] = (vy0 && vx1) ? a01 : 0.0f;
        w10[k] = (vy1 && vx0) ? a10 : 0.0f;
        w11[k] = (vy1 && vx1) ? a11 : 0.0f;
        int yc0 = min(max(y0, 0), Hc - 1);
        int yc1 = min(max(y0 + 1, 0), Hc - 1);
        int xc0 = min(max(x0, 0), Wc - 1);
        int xc1 = min(max(x0 + 1, 0), Wc - 1);
        i00[k] = yc0 * Wc + xc0; i01[k] = yc0 * Wc + xc1;
        i10[k] = yc1 * Wc + xc0; i11[k] = yc1 * Wc + xc1;
    }

    float acc[NKc];
#pragma unroll
    for (int i = 0; i < NKc; i++) acc[i] = sb[i];

    const float* xb = xcat + (long)b * CIN_D * HWc;
#pragma unroll 1
    for (int cin = 0; cin < CIN_D; cin++) {
        const float* xc = xb + (long)cin * HWc;
        float s[9];
#pragma unroll
        for (int k = 0; k < 9; k++)
            s[k] = w00[k] * xc[i00[k]] + w01[k] * xc[i01[k]] +
                   w10[k] * xc[i10[k]] + w11[k] * xc[i11[k]];
#pragma unroll
        for (int k = 0; k < 9; k++) {
            const float* wrow = &sw[(cin * 9 + k) * NKc];
#pragma unroll
            for (int co = 0; co < NKc; co++) acc[co] += wrow[co] * s[k];
        }
    }

#pragma unroll
    for (int co = 0; co < NKc; co++)
        dcout[((long)b * NKc + co) * HWc + p] = acc[co];
}

__global__ void __launch_bounds__(256) k_deform(
    const float* xcat, const float* offbuf, const float* maskbuf,
    const void* def_w, const void* def_b, const int* __restrict__ flag,
    float* dcout)
{
    __shared__ float sw[TAPS_D * NKc];  // 36.9 KB
    __shared__ float sb[NKc];
    if (flag[0])
        deform3_body<bf16>(xcat, offbuf, maskbuf, (const bf16*)def_w, (const bf16*)def_b,
                           dcout, sw, sb);
    else
        deform3_body<float>(xcat, offbuf, maskbuf, (const float*)def_w, (const float*)def_b,
                            dcout, sw, sb);
}

// ---------------------------------------------------------------------------
// outconv v8 (R19 proven form: register-staged weights + hoisted xs rows).
// ---------------------------------------------------------------------------
template <typename T>
__device__ __forceinline__ void outconv6_body(
    const float* __restrict__ dcout, const T* __restrict__ out_w,
    const T* __restrict__ out_b, T* __restrict__ out, float* sw, float* sb)
{
    int rb = xcd_chunked(blockIdx.x, 900);
    int type = rb & 1;
    int chunk = rb >> 1;

    for (int i = threadIdx.x; i < 24 * TAPS_O; i += 256) {
        int o = i / TAPS_O, tap = i - o * TAPS_O;
        int slot = (o / 6) * 8 + (o % 6);
        sw[tap * 32 + slot] = getv(out_w, (long)(type * 24 + o) * TAPS_O + tap);
    }
    if (threadIdx.x < 24) sb[threadIdx.x] = getv(out_b, type * 24 + threadIdx.x);
    __syncthreads();

    int og = threadIdx.x >> 6, lane = threadIdx.x & 63;
    long p0 = ((long)chunk * 64 + lane) * 4;
    int b = (int)(p0 / HWc);
    int p = (int)(p0 - (long)b * HWc);
    int y = p / Wc, x0 = p - (p / Wc) * Wc;

    float acc[6][4];
#pragma unroll
    for (int j = 0; j < 6; j++) {
        float bv = sb[og * 6 + j];
#pragma unroll
        for (int px = 0; px < 4; px++) acc[j][px] = bv;
    }

    const float* xb = dcout + (long)b * NKc * HWc;
#pragma unroll 1
    for (int cin = 0; cin < NKc; cin++) {
        const float* xc = xb + (long)cin * HWc;
        float xs[3][6];
#pragma unroll
        for (int ky = 0; ky < 3; ky++) {
            int yy = y + ky - 1;
            if (yy >= 0 && yy < Hc) {
                const float* row = xc + (long)yy * Wc;
                xs[ky][0] = (x0 > 0) ? row[x0 - 1] : 0.0f;
                load4(row, x0, &xs[ky][1]);
                xs[ky][5] = (x0 + 4 < Wc) ? row[x0 + 4] : 0.0f;
            } else {
#pragma unroll
                for (int j = 0; j < 6; j++) xs[ky][j] = 0.0f;
            }
        }
        float4 wa[9]; float2 wb[9];
#pragma unroll
        for (int t9 = 0; t9 < 9; t9++) {
            const float* wp = &sw[(cin * 9 + t9) * 32 + og * 8];
            wa[t9] = *(const float4*)wp;
            wb[t9] = *(const float2*)(wp + 4);
        }
#pragma unroll
        for (int ky = 0; ky < 3; ky++) {
#pragma unroll
            for (int kx = 0; kx < 3; kx++) {
                const float4 w0 = wa[ky * 3 + kx];
                const float2 w1 = wb[ky * 3 + kx];
#pragma unroll
                for (int px = 0; px < 4; px++) {
                    float v = xs[ky][px + kx];
                    acc[0][px] += w0.x * v;  acc[1][px] += w0.y * v;
                    acc[2][px] += w0.z * v;  acc[3][px] += w0.w * v;
                    acc[4][px] += w1.x * v;  acc[5][px] += w1.y * v;
                }
            }
        }
    }

#pragma unroll
    for (int j = 0; j < 6; j++) {
        int co = type * 24 + og * 6 + j;
        int cc = co >> 4;
        int r = co & 15;
        int ii = r >> 2, jj = r & 3;
        long ob = (((long)b * 3 + cc) * (Hc * 4) + (y * 4 + ii)) * (long)(Wc * 4);
#pragma unroll
        for (int px = 0; px < 4; px++) {
            float v = fminf(fmaxf(acc[j][px], 0.0f), 255.0f);
            putv(out, ob + (x0 + px) * 4 + jj, v);
        }
    }
}

__global__ void __launch_bounds__(256) k_outconv(
    const float* dcout, const void* out_w, const void* out_b,
    const int* __restrict__ flag, void* out)
{
    __shared__ float sw[TAPS_O * 32];  // 18.4 KB
    __shared__ float sb[24];
    if (flag[0])
        outconv6_body<bf16>(dcout, (const bf16*)out_w, (const bf16*)out_b, (bf16*)out, sw, sb);
    else
        outconv6_body<float>(dcout, (const float*)out_w, (const float*)out_b, (float*)out, sw, sb);
}

extern "C" void kernel_launch(void* const* d_in, const int* in_sizes, int n_in,
                              void* d_out, int out_size, void* d_ws, size_t ws_size,
                              hipStream_t stream) {
    const void* X      = d_in[0];
    const void* lstm_w = d_in[1];
    const void* lstm_b = d_in[2];
    const void* Wci    = d_in[3];
    const void* Wcf    = d_in[4];
    const void* Wco    = d_in[5];
    const void* off_w  = d_in[6];
    const void* off_b  = d_in[7];
    const void* mod_w  = d_in[8];
    const void* mod_b  = d_in[9];
    const void* def_w  = d_in[10];
    const void* def_b  = d_in[11];
    const void* out_w  = d_in[12];
    const void* out_b  = d_in[13];

    int* flag = (int*)d_ws;
    float* W = (float*)d_ws + 64;
    size_t o = 0;
    float* c_buf   = W + o; o += (size_t)Bn * NKc * HWc;
    float* xcat    = W + o; o += (size_t)Bn * CIN_D * HWc;
    float* offbuf  = W + o; o += (size_t)Bn * 18 * HWc;
    float* maskbuf = W + o; o += (size_t)Bn * 9 * HWc;
    float* dcout   = W + o; o += (size_t)Bn * NKc * HWc;

    dim3 blk(256);
    dim3 gridP(NPIX / 256);           // 450
    dim3 gridL2(Bn * (Hc / 2) * 5);   // 900: 2-row lstm blocks
    dim3 gridOM(2 * (NPIX / 512));    // 450: fat-thread offmod (8px/lane)
    dim3 gridC2(2 * (NPIX / 4 / 64)); // 900

    k_detect<<<1, blk, 0, stream>>>(lstm_w, flag);
    for (int t = 0; t < Tn; t++) {
        k_lstm2<<<gridL2, blk, 0, stream>>>(X, lstm_w, lstm_b, Wci, Wcf, Wco,
                                            flag, c_buf, xcat, t);
    }
    k_offmod<<<gridOM, blk, 0, stream>>>(xcat, off_w, off_b, mod_w, mod_b, flag,
                                         offbuf, maskbuf);
    k_deform<<<gridP, blk, 0, stream>>>(xcat, offbuf, maskbuf, def_w, def_b, flag, dcout);
    k_outconv<<<gridC2, blk, 0, stream>>>(dcout, out_w, out_b, flag, d_out);
}

// Round 9
// 622.665 us; speedup vs baseline: 1.3937x; 1.1182x over previous
//
#include <hip/hip_runtime.h>
#include <hip/hip_bf16.h>

// Problem dims
#define Bn 2
#define Tn 4
#define NCc 3
#define NKc 16
#define Hc 180
#define Wc 320
#define HWc (Hc * Wc)          // 57600
#define NPIX (Bn * HWc)        // 115200
#define CIN_LSTM 19            // NC + NK
#define GATES 64               // 4*NK
#define CIN_D 64               // T*NK
#define TAPS_L (CIN_LSTM * 9)  // 171
#define TAPS_D (CIN_D * 9)     // 576
#define TAPS_O (NKc * 9)       // 144

typedef __hip_bfloat16 bf16;
typedef float f32x4 __attribute__((ext_vector_type(4)));

__device__ __forceinline__ float getv(const float* p, long i) { return p[i]; }
__device__ __forceinline__ float getv(const bf16* p, long i) {
    unsigned int u = ((unsigned int)((const unsigned short*)p)[i]) << 16;
    return __uint_as_float(u);
}
__device__ __forceinline__ void putv(float* p, long i, float v) { p[i] = v; }
__device__ __forceinline__ void putv(bf16* p, long i, float v) { p[i] = __float2bfloat16(v); }
__device__ __forceinline__ float sigm(float x) { return 1.0f / (1.0f + __expf(-x)); }
__device__ __forceinline__ float tanh_(float x) { return 1.0f - 2.0f / (__expf(2.0f * x) + 1.0f); }

__device__ __forceinline__ void load4(const float* row, int x0, float* d) {
    const float4 v = *(const float4*)(row + x0);
    d[0] = v.x; d[1] = v.y; d[2] = v.z; d[3] = v.w;
}
__device__ __forceinline__ void load4(const bf16* row, int x0, float* d) {
    ushort4 u = *(const ushort4*)((const unsigned short*)row + x0);
    d[0] = __uint_as_float(((unsigned int)u.x) << 16);
    d[1] = __uint_as_float(((unsigned int)u.y) << 16);
    d[2] = __uint_as_float(((unsigned int)u.z) << 16);
    d[3] = __uint_as_float(((unsigned int)u.w) << 16);
}

// ---------------------------------------------------------------------------
// XCD-aware bijective chunked swizzle (T1, m204 formula). Proven R17.
// ---------------------------------------------------------------------------
__device__ __forceinline__ int xcd_chunked(int i, int nwg) {
    int q = nwg >> 3, r = nwg & 7;
    int xcd = i & 7, idx = i >> 3;
    return (xcd < r ? xcd * (q + 1) : r * (q + 1) + (xcd - r) * q) + idx;
}

// ---------------------------------------------------------------------------
// R21-PROVEN TECHNIQUE: force-batched loads via inline asm with early-clobber
// outputs — the one structure the compiler cannot re-serialize (its
// load-sinking was the ~70-90% stall in every conv kernel: R19 staged loads
// re-sunk at VGPR=60; R21 asm batching took offmod out of the top-5).
// ---------------------------------------------------------------------------
__device__ __forceinline__ void om_wait()
{
    asm volatile("s_waitcnt vmcnt(0)" ::: "memory");
    __builtin_amdgcn_sched_barrier(0);   // rule #18
}

// 12 loads, 3 rows (offmod: window [x0-1, x0+8] per row).
__device__ __forceinline__ void om_issue12(
    const float* p0, const float* p1, const float* p2,
    f32x4& a0, f32x4& b0, float& h00, float& h01,
    f32x4& a1, f32x4& b1, float& h10, float& h11,
    f32x4& a2, f32x4& b2, float& h20, float& h21)
{
    asm volatile(
        "global_load_dwordx4 %[A0], %[p0], off\n\t"
        "global_load_dwordx4 %[B0], %[p0], off offset:16\n\t"
        "global_load_dword   %[H00], %[p0], off offset:-4\n\t"
        "global_load_dword   %[H01], %[p0], off offset:32\n\t"
        "global_load_dwordx4 %[A1], %[p1], off\n\t"
        "global_load_dwordx4 %[B1], %[p1], off offset:16\n\t"
        "global_load_dword   %[H10], %[p1], off offset:-4\n\t"
        "global_load_dword   %[H11], %[p1], off offset:32\n\t"
        "global_load_dwordx4 %[A2], %[p2], off\n\t"
        "global_load_dwordx4 %[B2], %[p2], off offset:16\n\t"
        "global_load_dword   %[H20], %[p2], off offset:-4\n\t"
        "global_load_dword   %[H21], %[p2], off offset:32\n\t"
        : [A0]"=&v"(a0), [B0]"=&v"(b0), [H00]"=&v"(h00), [H01]"=&v"(h01),
          [A1]"=&v"(a1), [B1]"=&v"(b1), [H10]"=&v"(h10), [H11]"=&v"(h11),
          [A2]"=&v"(a2), [B2]"=&v"(b2), [H20]"=&v"(h20), [H21]"=&v"(h21)
        : [p0]"v"(p0), [p1]"v"(p1), [p2]"v"(p2));
}

// 12 loads, 4 rows (lstm hp: window [x0-1, x0+4] per row).
__device__ __forceinline__ void lstm_issue12(
    const float* p0, const float* p1, const float* p2, const float* p3,
    f32x4& a0, float& l0, float& r0,
    f32x4& a1, float& l1, float& r1,
    f32x4& a2, float& l2, float& r2,
    f32x4& a3, float& l3, float& r3)
{
    asm volatile(
        "global_load_dwordx4 %[A0], %[P0], off\n\t"
        "global_load_dword   %[L0], %[P0], off offset:-4\n\t"
        "global_load_dword   %[R0], %[P0], off offset:16\n\t"
        "global_load_dwordx4 %[A1], %[P1], off\n\t"
        "global_load_dword   %[L1], %[P1], off offset:-4\n\t"
        "global_load_dword   %[R1], %[P1], off offset:16\n\t"
        "global_load_dwordx4 %[A2], %[P2], off\n\t"
        "global_load_dword   %[L2], %[P2], off offset:-4\n\t"
        "global_load_dword   %[R2], %[P2], off offset:16\n\t"
        "global_load_dwordx4 %[A3], %[P3], off\n\t"
        "global_load_dword   %[L3], %[P3], off offset:-4\n\t"
        "global_load_dword   %[R3], %[P3], off offset:16\n\t"
        : [A0]"=&v"(a0), [L0]"=&v"(l0), [R0]"=&v"(r0),
          [A1]"=&v"(a1), [L1]"=&v"(l1), [R1]"=&v"(r1),
          [A2]"=&v"(a2), [L2]"=&v"(l2), [R2]"=&v"(r2),
          [A3]"=&v"(a3), [L3]"=&v"(l3), [R3]"=&v"(r3)
        : [P0]"v"(p0), [P1]"v"(p1), [P2]"v"(p2), [P3]"v"(p3));
}

// 9 gathers with wave-uniform SGPR base + per-lane 32-bit byte offsets (deform).
__device__ __forceinline__ void dfm_issue9(
    const float* base, const int (&o)[9], float (&v)[9])
{
    asm volatile(
        "global_load_dword %[V0], %[O0], %[B]\n\t"
        "global_load_dword %[V1], %[O1], %[B]\n\t"
        "global_load_dword %[V2], %[O2], %[B]\n\t"
        "global_load_dword %[V3], %[O3], %[B]\n\t"
        "global_load_dword %[V4], %[O4], %[B]\n\t"
        "global_load_dword %[V5], %[O5], %[B]\n\t"
        "global_load_dword %[V6], %[O6], %[B]\n\t"
        "global_load_dword %[V7], %[O7], %[B]\n\t"
        "global_load_dword %[V8], %[O8], %[B]\n\t"
        : [V0]"=&v"(v[0]), [V1]"=&v"(v[1]), [V2]"=&v"(v[2]),
          [V3]"=&v"(v[3]), [V4]"=&v"(v[4]), [V5]"=&v"(v[5]),
          [V6]"=&v"(v[6]), [V7]"=&v"(v[7]), [V8]"=&v"(v[8])
        : [B]"s"(base),
          [O0]"v"(o[0]), [O1]"v"(o[1]), [O2]"v"(o[2]),
          [O3]"v"(o[3]), [O4]"v"(o[4]), [O5]"v"(o[5]),
          [O6]"v"(o[6]), [O7]"v"(o[7]), [O8]"v"(o[8]));
}

// ---------------------------------------------------------------------------
// Dtype probe (bf16 vs float32 inputs) -> flag in d_ws.
// ---------------------------------------------------------------------------
__global__ void __launch_bounds__(256) k_detect(const void* lstm_w_raw, int* flag)
{
    __shared__ int bad;
    if (threadIdx.x == 0) bad = 0;
    __syncthreads();
    const unsigned short* u = (const unsigned short*)lstm_w_raw;
    int local = 0;
    for (int i = threadIdx.x; i < GATES * TAPS_L; i += 256) {
        unsigned int f32 = ((unsigned int)u[i]) << 16;
        float v = __uint_as_float(f32);
        if (!(fabsf(v) <= 64.0f)) local = 1;
    }
    if (local) atomicOr(&bad, 1);
    __syncthreads();
    if (threadIdx.x == 0) flag[0] = bad ? 0 : 1;
}

// ---------------------------------------------------------------------------
// ConvLSTM step.  ROUND-22: hp loop (16 float cins = 84% of work) uses the
// proven asm 12-load batch per cin (clamped row ptrs + 0/1 mask multiplies,
// no divergent branch).  X loop (3 cins, dtype-templated) unchanged.
// ---------------------------------------------------------------------------
template <typename S>
__device__ __forceinline__ void conv_plane2r(
    const S* __restrict__ src, int cin, int y0, int x0, int kc,
    const float* __restrict__ sw, float (&acc)[2][4][4])
{
    float xs[4][6];  // rows y0-1 .. y0+2
#pragma unroll
    for (int r = 0; r < 4; r++) {
        int yy = y0 - 1 + r;
        if (yy >= 0 && yy < Hc) {
            const S* row = src + (long)yy * Wc;
            xs[r][0] = (x0 > 0) ? getv(row, x0 - 1) : 0.0f;
            load4(row, x0, &xs[r][1]);
            xs[r][5] = (x0 + 4 < Wc) ? getv(row, x0 + 4) : 0.0f;
        } else {
#pragma unroll
            for (int j = 0; j < 6; j++) xs[r][j] = 0.0f;
        }
    }
    float4 wq[9];
#pragma unroll
    for (int t9 = 0; t9 < 9; t9++)
        wq[t9] = *(const float4*)&sw[(((cin * 9 + t9) * 16) + kc) * 4];
#pragma unroll
    for (int ky = 0; ky < 3; ky++) {
#pragma unroll
        for (int kx = 0; kx < 3; kx++) {
            const float4 w = wq[ky * 3 + kx];
#pragma unroll
            for (int px = 0; px < 4; px++) {
                float v0 = xs[ky][px + kx];
                float v1 = xs[ky + 1][px + kx];
                acc[0][0][px] += w.x * v0;  acc[1][0][px] += w.x * v1;
                acc[0][1][px] += w.y * v0;  acc[1][1][px] += w.y * v1;
                acc[0][2][px] += w.z * v0;  acc[1][2][px] += w.z * v1;
                acc[0][3][px] += w.w * v0;  acc[1][3][px] += w.w * v1;
            }
        }
    }
}

template <typename T>
__device__ __forceinline__ void lstm2r_body(
    const T* __restrict__ X, const T* __restrict__ lstm_w, const T* __restrict__ lstm_b,
    const T* __restrict__ Wci, const T* __restrict__ Wcf, const T* __restrict__ Wco,
    float* __restrict__ c_buf, float* __restrict__ xcat, int t,
    float* sw, float* sb)
{
    for (int i = threadIdx.x; i < GATES * TAPS_L; i += 256) {
        int co = i / TAPS_L, tap = i - co * TAPS_L;
        int kc = co & 15, g = co >> 4;
        sw[(tap * 16 + kc) * 4 + g] = getv(lstm_w, i);
    }
    if (threadIdx.x < GATES) sb[threadIdx.x] = getv(lstm_b, threadIdx.x);
    __syncthreads();

    int blk = xcd_chunked(blockIdx.x, Bn * 90 * 5);  // 900; row-sharers same XCD
    int seg = blk % 5; int rem = blk / 5;
    int yp = rem % 90; int b = rem / 90;
    int y0 = yp * 2;
    int kc = threadIdx.x >> 4, pl = threadIdx.x & 15;
    int x0 = seg * 64 + pl * 4;

    float acc[2][4][4];  // [row][gate][px]
#pragma unroll
    for (int px = 0; px < 4; px++) {
#pragma unroll
        for (int r = 0; r < 2; r++) {
            acc[r][0][px] = sb[kc];
            acc[r][1][px] = sb[16 + kc];
            acc[r][2][px] = sb[32 + kc];
            acc[r][3][px] = sb[48 + kc];
        }
    }

    const T* xt = X + (long)(b * Tn + t) * NCc * HWc;
#pragma unroll 1
    for (int cin = 0; cin < NCc; cin++)
        conv_plane2r(xt + (long)cin * HWc, cin, y0, x0, kc, sw, acc);

    if (t > 0) {
        const float* hp = xcat + ((long)b * CIN_D + (t - 1) * NKc) * HWc;
        // row geometry: clamped offsets + masks (y0 block-uniform, x0 per-lane)
        long ro[4]; float vm[4];
#pragma unroll
        for (int r = 0; r < 4; r++) {
            int yy = y0 - 1 + r;
            vm[r] = (yy >= 0 && yy < Hc) ? 1.0f : 0.0f;
            ro[r] = (long)min(max(yy, 0), Hc - 1) * Wc + x0;
        }
        const float m0 = (x0 > 0) ? 1.0f : 0.0f;
        const float m1 = (x0 + 4 < Wc) ? 1.0f : 0.0f;

#pragma unroll 1
        for (int cin = 0; cin < NKc; cin++) {
            const float* xc = hp + (long)cin * HWc;
            f32x4 a0, a1, a2, a3;
            float l0, l1, l2, l3, rh0, rh1, rh2, rh3;
            lstm_issue12(xc + ro[0], xc + ro[1], xc + ro[2], xc + ro[3],
                         a0, l0, rh0, a1, l1, rh1, a2, l2, rh2, a3, l3, rh3);
            float4 wq[9];   // LDS reads overlap the vmem latency (before wait)
#pragma unroll
            for (int t9 = 0; t9 < 9; t9++)
                wq[t9] = *(const float4*)&sw[((((cin + NCc) * 9 + t9) * 16) + kc) * 4];
            om_wait();
            float xs[4][6];
#pragma unroll
            for (int r = 0; r < 4; r++) {
                const f32x4 a = (r == 0) ? a0 : (r == 1) ? a1 : (r == 2) ? a2 : a3;
                const float ll = (r == 0) ? l0 : (r == 1) ? l1 : (r == 2) ? l2 : l3;
                const float rr = (r == 0) ? rh0 : (r == 1) ? rh1 : (r == 2) ? rh2 : rh3;
                xs[r][0] = ll * vm[r] * m0;
                xs[r][1] = a.x * vm[r]; xs[r][2] = a.y * vm[r];
                xs[r][3] = a.z * vm[r]; xs[r][4] = a.w * vm[r];
                xs[r][5] = rr * vm[r] * m1;
            }
#pragma unroll
            for (int ky = 0; ky < 3; ky++) {
#pragma unroll
                for (int kx = 0; kx < 3; kx++) {
                    const float4 w = wq[ky * 3 + kx];
#pragma unroll
                    for (int px = 0; px < 4; px++) {
                        float v0 = xs[ky][px + kx];
                        float v1 = xs[ky + 1][px + kx];
                        acc[0][0][px] += w.x * v0;  acc[1][0][px] += w.x * v1;
                        acc[0][1][px] += w.y * v0;  acc[1][1][px] += w.y * v1;
                        acc[0][2][px] += w.z * v0;  acc[1][2][px] += w.z * v1;
                        acc[0][3][px] += w.w * v0;  acc[1][3][px] += w.w * v1;
                    }
                }
            }
        }
    }

#pragma unroll
    for (int r = 0; r < 2; r++) {
        int y = y0 + r;
        long pbase = (long)y * Wc + x0;
        float* cb = c_buf + (long)(b * NKc + kc) * HWc + pbase;
        float cprev[4];
        if (t > 0) {
            const float4 cv = *(const float4*)cb;
            cprev[0] = cv.x; cprev[1] = cv.y; cprev[2] = cv.z; cprev[3] = cv.w;
        } else {
            cprev[0] = cprev[1] = cprev[2] = cprev[3] = 0.0f;
        }
        float wci[4], wcf[4], wco[4];
        load4(Wci + (long)kc * HWc + pbase, 0, wci);
        load4(Wcf + (long)kc * HWc + pbase, 0, wcf);
        load4(Wco + (long)kc * HWc + pbase, 0, wco);

        float cn4[4], h4[4];
#pragma unroll
        for (int px = 0; px < 4; px++) {
            float ii = sigm(acc[r][0][px] + wci[px] * cprev[px]);
            float ff = sigm(acc[r][1][px] + wcf[px] * cprev[px]);
            float cn = ff * cprev[px] + ii * tanh_(acc[r][2][px]);
            float oo = sigm(acc[r][3][px] + wco[px] * cn);
            cn4[px] = cn; h4[px] = oo * tanh_(cn);
        }
        *(float4*)cb = make_float4(cn4[0], cn4[1], cn4[2], cn4[3]);
        *(float4*)(xcat + ((long)b * CIN_D + t * NKc + kc) * HWc + pbase) =
            make_float4(h4[0], h4[1], h4[2], h4[3]);
    }
}

__global__ void __launch_bounds__(256) k_lstm2(
    const void* X, const void* lstm_w, const void* lstm_b,
    const void* Wci, const void* Wcf, const void* Wco,
    const int* __restrict__ flag,
    float* c_buf, float* xcat, int t)
{
    __shared__ float sw[TAPS_L * GATES];  // 43.8 KB
    __shared__ float sb[GATES];
    if (flag[0])
        lstm2r_body<bf16>((const bf16*)X, (const bf16*)lstm_w, (const bf16*)lstm_b,
                          (const bf16*)Wci, (const bf16*)Wcf, (const bf16*)Wco,
                          c_buf, xcat, t, sw, sb);
    else
        lstm2r_body<float>((const float*)X, (const float*)lstm_w, (const float*)lstm_b,
                           (const float*)Wci, (const float*)Wcf, (const float*)Wco,
                           c_buf, xcat, t, sw, sb);
}

// ---------------------------------------------------------------------------
// offmod v12 (R21 proven: fat 8px threads + asm-batched row loads). Unchanged.
// ---------------------------------------------------------------------------
template <typename T>
__device__ __forceinline__ void offmod12_body(
    const float* __restrict__ xcat,
    const T* __restrict__ off_w, const T* __restrict__ off_b,
    const T* __restrict__ mod_w, const T* __restrict__ mod_b,
    float* __restrict__ offbuf, float* __restrict__ maskbuf,
    float* sw, float* sb)
{
    int rb = xcd_chunked(blockIdx.x, 450);
    int type = rb & 1;
    int chunk = rb >> 1;          // [0,225)
    const int nslot = type ? 12 : 16;

    for (int i = threadIdx.x; i < TAPS_D * nslot; i += 256) {
        int tap = i / nslot, j = i - tap * nslot;
        int o = type ? 16 + j : j;
        float v = 0.0f;
        if (o < 18) v = getv(off_w, (long)o * TAPS_D + tap);
        else if (o < 27) v = getv(mod_w, (long)(o - 18) * TAPS_D + tap);
        sw[tap * nslot + j] = v;
    }
    if (threadIdx.x < nslot) {
        int o = (type ? 16 : 0) + threadIdx.x;
        sb[threadIdx.x] = (o < 18) ? getv(off_b, o)
                        : (o < 27 ? getv(mod_b, o - 18) : 0.0f);
    }
    __syncthreads();

    int og = threadIdx.x >> 6, lane = threadIdx.x & 63;
    long p0 = (long)chunk * 512 + lane * 8;
    int b = (int)(p0 / HWc);
    int p = (int)(p0 - (long)b * HWc);
    int y = p / Wc, x0 = p - (p / Wc) * Wc;   // x0 multiple of 8

    const int per = type ? 3 : 4;
    int jbase = og * per;

    const float* xb = xcat + (long)b * CIN_D * HWc;
    long yo[3]; float vm[3];
#pragma unroll
    for (int ky = 0; ky < 3; ky++) {
        int yy = y + ky - 1;
        vm[ky] = (yy >= 0 && yy < Hc) ? 1.0f : 0.0f;
        yo[ky] = (long)min(max(yy, 0), Hc - 1) * Wc + x0;
    }
    const float m0 = (x0 > 0) ? 1.0f : 0.0f;
    const float m1 = (x0 + 8 < Wc) ? 1.0f : 0.0f;

    float acc[4][8];
#pragma unroll
    for (int j = 0; j < 4; j++) {
        float bv = (j < per) ? sb[jbase + j] : 0.0f;
#pragma unroll
        for (int px = 0; px < 8; px++) acc[j][px] = bv;
    }

    if (type == 0) {
#pragma unroll 1
        for (int cin = 0; cin < CIN_D; cin++) {
            const float* xc = xb + (long)cin * HWc;
            f32x4 a0, b0v, a1, b1v, a2, b2v;
            float h00, h01, h10, h11, h20, h21;
            om_issue12(xc + yo[0], xc + yo[1], xc + yo[2],
                       a0, b0v, h00, h01, a1, b1v, h10, h11, a2, b2v, h20, h21);
            float4 wr[9];
#pragma unroll
            for (int t9 = 0; t9 < 9; t9++)
                wr[t9] = *(const float4*)&sw[(cin * 9 + t9) * 16 + jbase];
            om_wait();
            float xs[3][10];
#pragma unroll
            for (int ky = 0; ky < 3; ky++) {
                const f32x4 a = (ky == 0) ? a0 : (ky == 1) ? a1 : a2;
                const f32x4 bb = (ky == 0) ? b0v : (ky == 1) ? b1v : b2v;
                const float hh0 = (ky == 0) ? h00 : (ky == 1) ? h10 : h20;
                const float hh1 = (ky == 0) ? h01 : (ky == 1) ? h11 : h21;
                xs[ky][0] = hh0 * vm[ky] * m0;
                xs[ky][1] = a.x * vm[ky]; xs[ky][2] = a.y * vm[ky];
                xs[ky][3] = a.z * vm[ky]; xs[ky][4] = a.w * vm[ky];
                xs[ky][5] = bb.x * vm[ky]; xs[ky][6] = bb.y * vm[ky];
                xs[ky][7] = bb.z * vm[ky]; xs[ky][8] = bb.w * vm[ky];
                xs[ky][9] = hh1 * vm[ky] * m1;
            }
#pragma unroll
            for (int ky = 0; ky < 3; ky++) {
#pragma unroll
                for (int kx = 0; kx < 3; kx++) {
                    const float4 wq = wr[ky * 3 + kx];
#pragma unroll
                    for (int px = 0; px < 8; px++) {
                        float v = xs[ky][px + kx];
                        acc[0][px] += wq.x * v;
                        acc[1][px] += wq.y * v;
                        acc[2][px] += wq.z * v;
                        acc[3][px] += wq.w * v;
                    }
                }
            }
        }
    } else {
#pragma unroll 1
        for (int cin = 0; cin < CIN_D; cin++) {
            const float* xc = xb + (long)cin * HWc;
            f32x4 a0, b0v, a1, b1v, a2, b2v;
            float h00, h01, h10, h11, h20, h21;
            om_issue12(xc + yo[0], xc + yo[1], xc + yo[2],
                       a0, b0v, h00, h01, a1, b1v, h10, h11, a2, b2v, h20, h21);
            float3 wr[9];
#pragma unroll
            for (int t9 = 0; t9 < 9; t9++) {
                const float* wp = &sw[(cin * 9 + t9) * 12 + jbase];
                wr[t9] = make_float3(wp[0], wp[1], wp[2]);
            }
            om_wait();
            float xs[3][10];
#pragma unroll
            for (int ky = 0; ky < 3; ky++) {
                const f32x4 a = (ky == 0) ? a0 : (ky == 1) ? a1 : a2;
                const f32x4 bb = (ky == 0) ? b0v : (ky == 1) ? b1v : b2v;
                const float hh0 = (ky == 0) ? h00 : (ky == 1) ? h10 : h20;
                const float hh1 = (ky == 0) ? h01 : (ky == 1) ? h11 : h21;
                xs[ky][0] = hh0 * vm[ky] * m0;
                xs[ky][1] = a.x * vm[ky]; xs[ky][2] = a.y * vm[ky];
                xs[ky][3] = a.z * vm[ky]; xs[ky][4] = a.w * vm[ky];
                xs[ky][5] = bb.x * vm[ky]; xs[ky][6] = bb.y * vm[ky];
                xs[ky][7] = bb.z * vm[ky]; xs[ky][8] = bb.w * vm[ky];
                xs[ky][9] = hh1 * vm[ky] * m1;
            }
#pragma unroll
            for (int ky = 0; ky < 3; ky++) {
#pragma unroll
                for (int kx = 0; kx < 3; kx++) {
                    const float3 wq = wr[ky * 3 + kx];
#pragma unroll
                    for (int px = 0; px < 8; px++) {
                        float v = xs[ky][px + kx];
                        acc[0][px] += wq.x * v;
                        acc[1][px] += wq.y * v;
                        acc[2][px] += wq.z * v;
                    }
                }
            }
        }
    }

    long pbase = (long)y * Wc + x0;
#pragma unroll
    for (int j = 0; j < 4; j++) {
        if (j >= per) break;
        int o = (type ? 16 : 0) + jbase + j;
        if (o >= 27) break;
        if (o < 18) {
            float* dst = offbuf + ((long)b * 18 + o) * HWc + pbase;
            *(float4*)dst = make_float4(acc[j][0], acc[j][1], acc[j][2], acc[j][3]);
            *(float4*)(dst + 4) = make_float4(acc[j][4], acc[j][5], acc[j][6], acc[j][7]);
        } else {
            float* dst = maskbuf + ((long)b * 9 + (o - 18)) * HWc + pbase;
            *(float4*)dst = make_float4(2.0f * sigm(acc[j][0]), 2.0f * sigm(acc[j][1]),
                                        2.0f * sigm(acc[j][2]), 2.0f * sigm(acc[j][3]));
            *(float4*)(dst + 4) = make_float4(2.0f * sigm(acc[j][4]), 2.0f * sigm(acc[j][5]),
                                              2.0f * sigm(acc[j][6]), 2.0f * sigm(acc[j][7]));
        }
    }
}

__global__ void __launch_bounds__(256) k_offmod(
    const float* xcat, const void* off_w, const void* off_b,
    const void* mod_w, const void* mod_b, const int* __restrict__ flag,
    float* offbuf, float* maskbuf)
{
    __shared__ float sw[TAPS_D * 16];  // 36.9 KB (type A); type B uses 27.6 KB
    __shared__ float sb[16];
    if (flag[0])
        offmod12_body<bf16>(xcat, (const bf16*)off_w, (const bf16*)off_b,
                            (const bf16*)mod_w, (const bf16*)mod_b, offbuf, maskbuf, sw, sb);
    else
        offmod12_body<float>(xcat, (const float*)off_w, (const float*)off_b,
                             (const float*)mod_w, (const float*)mod_b, offbuf, maskbuf, sw, sb);
}

// ---------------------------------------------------------------------------
// deform v4 (ROUND-22): asm-batched gathers.  b/xc are block-uniform
// (HWc % 256 == 0), recomputed from blockIdx only so they live in SGPRs;
// the 36 gather loads per cin go out as 4 blobs of 9 with SGPR base +
// per-lane byte offsets, ONE vmcnt wait, then the FMA block.
// ---------------------------------------------------------------------------
template <typename T>
__device__ __forceinline__ void deform4_body(
    const float* __restrict__ xcat, const float* __restrict__ offbuf,
    const float* __restrict__ maskbuf,
    const T* __restrict__ def_w, const T* __restrict__ def_b,
    float* __restrict__ dcout, float* sw, float* sb)
{
    for (int i = threadIdx.x; i < NKc * TAPS_D; i += 256) {
        int co = i / TAPS_D;
        int tap = i - co * TAPS_D;
        sw[tap * NKc + co] = getv(def_w, i);
    }
    if (threadIdx.x < NKc) sb[threadIdx.x] = getv(def_b, threadIdx.x);
    __syncthreads();

    int blk = xcd_chunked(blockIdx.x, NPIX / 256);
    int idx0 = blk * 256;            // block-uniform
    int b = idx0 / HWc;              // uniform -> SGPR
    int p = idx0 - b * HWc + threadIdx.x;
    int y = p / Wc, x = p - (p / Wc) * Wc;

    float w00[9], w01[9], w10[9], w11[9];
    int o00[9], o01[9], o10[9], o11[9];   // byte offsets
#pragma unroll
    for (int k = 0; k < 9; k++) {
        int ky = k / 3, kx = k - (k / 3) * 3;
        float dy = offbuf[((long)b * 18 + 2 * k) * HWc + p];
        float dx = offbuf[((long)b * 18 + 2 * k + 1) * HWc + p];
        float m = maskbuf[((long)b * 9 + k) * HWc + p];
        float py = (float)(y - 1 + ky) + dy;
        float px = (float)(x - 1 + kx) + dx;
        float y0f = floorf(py), x0f = floorf(px);
        int y0 = (int)y0f, x0 = (int)x0f;
        float wy1 = py - y0f, wx1 = px - x0f;
        float a00 = (1.0f - wy1) * (1.0f - wx1) * m;
        float a01 = (1.0f - wy1) * wx1 * m;
        float a10 = wy1 * (1.0f - wx1) * m;
        float a11 = wy1 * wx1 * m;
        bool vy0 = (y0 >= 0) && (y0 < Hc);
        bool vy1 = (y0 + 1 >= 0) && (y0 + 1 < Hc);
        bool vx0 = (x0 >= 0) && (x0 < Wc);
        bool vx1 = (x0 + 1 >= 0) && (x0 + 1 < Wc);
        w00[k] = (vy0 && vx0) ? a00 : 0.0f;
        w01[k] = (vy0 && vx1) ? a01 : 0.0f;
        w10[k] = (vy1 && vx0) ? a10 : 0.0f;
        w11[k] = (vy1 && vx1) ? a11 : 0.0f;
        int yc0 = min(max(y0, 0), Hc - 1);
        int yc1 = min(max(y0 + 1, 0), Hc - 1);
        int xc0 = min(max(x0, 0), Wc - 1);
        int xc1 = min(max(x0 + 1, 0), Wc - 1);
        o00[k] = (yc0 * Wc + xc0) * 4; o01[k] = (yc0 * Wc + xc1) * 4;
        o10[k] = (yc1 * Wc + xc0) * 4; o11[k] = (yc1 * Wc + xc1) * 4;
    }

    float acc[NKc];
#pragma unroll
    for (int i = 0; i < NKc; i++) acc[i] = sb[i];

    const float* xb = xcat + (long)b * CIN_D * HWc;   // uniform -> SGPR
#pragma unroll 1
    for (int cin = 0; cin < CIN_D; cin++) {
        const float* xc = xb + (long)cin * HWc;       // uniform -> SGPR
        float v00[9], v01[9], v10[9], v11[9];
        dfm_issue9(xc, o00, v00);
        dfm_issue9(xc, o01, v01);
        dfm_issue9(xc, o10, v10);
        dfm_issue9(xc, o11, v11);
        om_wait();
        float s[9];
#pragma unroll
        for (int k = 0; k < 9; k++)
            s[k] = w00[k] * v00[k] + w01[k] * v01[k] +
                   w10[k] * v10[k] + w11[k] * v11[k];
#pragma unroll
        for (int k = 0; k < 9; k++) {
            const float* wrow = &sw[(cin * 9 + k) * NKc];
#pragma unroll
            for (int co = 0; co < NKc; co++) acc[co] += wrow[co] * s[k];
        }
    }

#pragma unroll
    for (int co = 0; co < NKc; co++)
        dcout[((long)b * NKc + co) * HWc + p] = acc[co];
}

__global__ void __launch_bounds__(256) k_deform(
    const float* xcat, const float* offbuf, const float* maskbuf,
    const void* def_w, const void* def_b, const int* __restrict__ flag,
    float* dcout)
{
    __shared__ float sw[TAPS_D * NKc];  // 36.9 KB
    __shared__ float sb[NKc];
    if (flag[0])
        deform4_body<bf16>(xcat, offbuf, maskbuf, (const bf16*)def_w, (const bf16*)def_b,
                           dcout, sw, sb);
    else
        deform4_body<float>(xcat, offbuf, maskbuf, (const float*)def_w, (const float*)def_b,
                            dcout, sw, sb);
}

// ---------------------------------------------------------------------------
// outconv v8 (R19 proven form). Unchanged.
// ---------------------------------------------------------------------------
template <typename T>
__device__ __forceinline__ void outconv6_body(
    const float* __restrict__ dcout, const T* __restrict__ out_w,
    const T* __restrict__ out_b, T* __restrict__ out, float* sw, float* sb)
{
    int rb = xcd_chunked(blockIdx.x, 900);
    int type = rb & 1;
    int chunk = rb >> 1;

    for (int i = threadIdx.x; i < 24 * TAPS_O; i += 256) {
        int o = i / TAPS_O, tap = i - o * TAPS_O;
        int slot = (o / 6) * 8 + (o % 6);
        sw[tap * 32 + slot] = getv(out_w, (long)(type * 24 + o) * TAPS_O + tap);
    }
    if (threadIdx.x < 24) sb[threadIdx.x] = getv(out_b, type * 24 + threadIdx.x);
    __syncthreads();

    int og = threadIdx.x >> 6, lane = threadIdx.x & 63;
    long p0 = ((long)chunk * 64 + lane) * 4;
    int b = (int)(p0 / HWc);
    int p = (int)(p0 - (long)b * HWc);
    int y = p / Wc, x0 = p - (p / Wc) * Wc;

    float acc[6][4];
#pragma unroll
    for (int j = 0; j < 6; j++) {
        float bv = sb[og * 6 + j];
#pragma unroll
        for (int px = 0; px < 4; px++) acc[j][px] = bv;
    }

    const float* xb = dcout + (long)b * NKc * HWc;
#pragma unroll 1
    for (int cin = 0; cin < NKc; cin++) {
        const float* xc = xb + (long)cin * HWc;
        float xs[3][6];
#pragma unroll
        for (int ky = 0; ky < 3; ky++) {
            int yy = y + ky - 1;
            if (yy >= 0 && yy < Hc) {
                const float* row = xc + (long)yy * Wc;
                xs[ky][0] = (x0 > 0) ? row[x0 - 1] : 0.0f;
                load4(row, x0, &xs[ky][1]);
                xs[ky][5] = (x0 + 4 < Wc) ? row[x0 + 4] : 0.0f;
            } else {
#pragma unroll
                for (int j = 0; j < 6; j++) xs[ky][j] = 0.0f;
            }
        }
        float4 wa[9]; float2 wb[9];
#pragma unroll
        for (int t9 = 0; t9 < 9; t9++) {
            const float* wp = &sw[(cin * 9 + t9) * 32 + og * 8];
            wa[t9] = *(const float4*)wp;
            wb[t9] = *(const float2*)(wp + 4);
        }
#pragma unroll
        for (int ky = 0; ky < 3; ky++) {
#pragma unroll
            for (int kx = 0; kx < 3; kx++) {
                const float4 w0 = wa[ky * 3 + kx];
                const float2 w1 = wb[ky * 3 + kx];
#pragma unroll
                for (int px = 0; px < 4; px++) {
                    float v = xs[ky][px + kx];
                    acc[0][px] += w0.x * v;  acc[1][px] += w0.y * v;
                    acc[2][px] += w0.z * v;  acc[3][px] += w0.w * v;
                    acc[4][px] += w1.x * v;  acc[5][px] += w1.y * v;
                }
            }
        }
    }

#pragma unroll
    for (int j = 0; j < 6; j++) {
        int co = type * 24 + og * 6 + j;
        int cc = co >> 4;
        int r = co & 15;
        int ii = r >> 2, jj = r & 3;
        long ob = (((long)b * 3 + cc) * (Hc * 4) + (y * 4 + ii)) * (long)(Wc * 4);
#pragma unroll
        for (int px = 0; px < 4; px++) {
            float v = fminf(fmaxf(acc[j][px], 0.0f), 255.0f);
            putv(out, ob + (x0 + px) * 4 + jj, v);
        }
    }
}

__global__ void __launch_bounds__(256) k_outconv(
    const float* dcout, const void* out_w, const void* out_b,
    const int* __restrict__ flag, void* out)
{
    __shared__ float sw[TAPS_O * 32];  // 18.4 KB
    __shared__ float sb[24];
    if (flag[0])
        outconv6_body<bf16>(dcout, (const bf16*)out_w, (const bf16*)out_b, (bf16*)out, sw, sb);
    else
        outconv6_body<float>(dcout, (const float*)out_w, (const float*)out_b, (float*)out, sw, sb);
}

extern "C" void kernel_launch(void* const* d_in, const int* in_sizes, int n_in,
                              void* d_out, int out_size, void* d_ws, size_t ws_size,
                              hipStream_t stream) {
    const void* X      = d_in[0];
    const void* lstm_w = d_in[1];
    const void* lstm_b = d_in[2];
    const void* Wci    = d_in[3];
    const void* Wcf    = d_in[4];
    const void* Wco    = d_in[5];
    const void* off_w  = d_in[6];
    const void* off_b  = d_in[7];
    const void* mod_w  = d_in[8];
    const void* mod_b  = d_in[9];
    const void* def_w  = d_in[10];
    const void* def_b  = d_in[11];
    const void* out_w  = d_in[12];
    const void* out_b  = d_in[13];

    int* flag = (int*)d_ws;
    float* W = (float*)d_ws + 64;
    size_t o = 0;
    float* c_buf   = W + o; o += (size_t)Bn * NKc * HWc;
    float* xcat    = W + o; o += (size_t)Bn * CIN_D * HWc;
    float* offbuf  = W + o; o += (size_t)Bn * 18 * HWc;
    float* maskbuf = W + o; o += (size_t)Bn * 9 * HWc;
    float* dcout   = W + o; o += (size_t)Bn * NKc * HWc;

    dim3 blk(256);
    dim3 gridP(NPIX / 256);           // 450
    dim3 gridL2(Bn * (Hc / 2) * 5);   // 900: 2-row lstm blocks
    dim3 gridOM(2 * (NPIX / 512));    // 450: fat-thread offmod (8px/lane)
    dim3 gridC2(2 * (NPIX / 4 / 64)); // 900

    k_detect<<<1, blk, 0, stream>>>(lstm_w, flag);
    for (int t = 0; t < Tn; t++) {
        k_lstm2<<<gridL2, blk, 0, stream>>>(X, lstm_w, lstm_b, Wci, Wcf, Wco,
                                            flag, c_buf, xcat, t);
    }
    k_offmod<<<gridOM, blk, 0, stream>>>(xcat, off_w, off_b, mod_w, mod_b, flag,
                                         offbuf, maskbuf);
    k_deform<<<gridP, blk, 0, stream>>>(xcat, offbuf, maskbuf, def_w, def_b, flag, dcout);
    k_outconv<<<gridC2, blk, 0, stream>>>(dcout, out_w, out_b, flag, d_out);
}

// Round 10
// 592.133 us; speedup vs baseline: 1.4655x; 1.0516x over previous
//
#include <hip/hip_runtime.h>
#include <hip/hip_bf16.h>

// Problem dims
#define Bn 2
#define Tn 4
#define NCc 3
#define NKc 16
#define Hc 180
#define Wc 320
#define HWc (Hc * Wc)          // 57600
#define NPIX (Bn * HWc)        // 115200
#define CIN_LSTM 19            // NC + NK
#define GATES 64               // 4*NK
#define CIN_D 64               // T*NK
#define TAPS_L (CIN_LSTM * 9)  // 171
#define TAPS_D (CIN_D * 9)     // 576
#define TAPS_O (NKc * 9)       // 144

typedef __hip_bfloat16 bf16;
typedef float f32x4 __attribute__((ext_vector_type(4)));
typedef float f32x2 __attribute__((ext_vector_type(2)));

__device__ __forceinline__ float getv(const float* p, long i) { return p[i]; }
__device__ __forceinline__ float getv(const bf16* p, long i) {
    unsigned int u = ((unsigned int)((const unsigned short*)p)[i]) << 16;
    return __uint_as_float(u);
}
__device__ __forceinline__ void putv(float* p, long i, float v) { p[i] = v; }
__device__ __forceinline__ void putv(bf16* p, long i, float v) { p[i] = __float2bfloat16(v); }
__device__ __forceinline__ float sigm(float x) { return 1.0f / (1.0f + __expf(-x)); }
__device__ __forceinline__ float tanh_(float x) { return 1.0f - 2.0f / (__expf(2.0f * x) + 1.0f); }

__device__ __forceinline__ void load4(const float* row, int x0, float* d) {
    const float4 v = *(const float4*)(row + x0);
    d[0] = v.x; d[1] = v.y; d[2] = v.z; d[3] = v.w;
}
__device__ __forceinline__ void load4(const bf16* row, int x0, float* d) {
    ushort4 u = *(const ushort4*)((const unsigned short*)row + x0);
    d[0] = __uint_as_float(((unsigned int)u.x) << 16);
    d[1] = __uint_as_float(((unsigned int)u.y) << 16);
    d[2] = __uint_as_float(((unsigned int)u.z) << 16);
    d[3] = __uint_as_float(((unsigned int)u.w) << 16);
}

// ---------------------------------------------------------------------------
// XCD-aware bijective chunked swizzle (T1, m204 formula). Proven R17.
// ---------------------------------------------------------------------------
__device__ __forceinline__ int xcd_chunked(int i, int nwg) {
    int q = nwg >> 3, r = nwg & 7;
    int xcd = i & 7, idx = i >> 3;
    return (xcd < r ? xcd * (q + 1) : r * (q + 1) + (xcd - r) * q) + idx;
}

// ---------------------------------------------------------------------------
// R21-PROVEN TECHNIQUE: force-batched loads via inline asm (early-clobber
// outputs defeat the compiler's load re-serialization).
// ---------------------------------------------------------------------------
__device__ __forceinline__ void om_wait()
{
    asm volatile("s_waitcnt vmcnt(0)" ::: "memory");
    __builtin_amdgcn_sched_barrier(0);   // rule #18
}

// 12 loads, 3 rows (offmod: window [x0-1, x0+8] per row).
__device__ __forceinline__ void om_issue12(
    const float* p0, const float* p1, const float* p2,
    f32x4& a0, f32x4& b0, float& h00, float& h01,
    f32x4& a1, f32x4& b1, float& h10, float& h11,
    f32x4& a2, f32x4& b2, float& h20, float& h21)
{
    asm volatile(
        "global_load_dwordx4 %[A0], %[p0], off\n\t"
        "global_load_dwordx4 %[B0], %[p0], off offset:16\n\t"
        "global_load_dword   %[H00], %[p0], off offset:-4\n\t"
        "global_load_dword   %[H01], %[p0], off offset:32\n\t"
        "global_load_dwordx4 %[A1], %[p1], off\n\t"
        "global_load_dwordx4 %[B1], %[p1], off offset:16\n\t"
        "global_load_dword   %[H10], %[p1], off offset:-4\n\t"
        "global_load_dword   %[H11], %[p1], off offset:32\n\t"
        "global_load_dwordx4 %[A2], %[p2], off\n\t"
        "global_load_dwordx4 %[B2], %[p2], off offset:16\n\t"
        "global_load_dword   %[H20], %[p2], off offset:-4\n\t"
        "global_load_dword   %[H21], %[p2], off offset:32\n\t"
        : [A0]"=&v"(a0), [B0]"=&v"(b0), [H00]"=&v"(h00), [H01]"=&v"(h01),
          [A1]"=&v"(a1), [B1]"=&v"(b1), [H10]"=&v"(h10), [H11]"=&v"(h11),
          [A2]"=&v"(a2), [B2]"=&v"(b2), [H20]"=&v"(h20), [H21]"=&v"(h21)
        : [p0]"v"(p0), [p1]"v"(p1), [p2]"v"(p2));
}

// 12 loads, 4 rows (lstm hp: window [x0-1, x0+4] per row).
__device__ __forceinline__ void lstm_issue12(
    const float* p0, const float* p1, const float* p2, const float* p3,
    f32x4& a0, float& l0, float& r0,
    f32x4& a1, float& l1, float& r1,
    f32x4& a2, float& l2, float& r2,
    f32x4& a3, float& l3, float& r3)
{
    asm volatile(
        "global_load_dwordx4 %[A0], %[P0], off\n\t"
        "global_load_dword   %[L0], %[P0], off offset:-4\n\t"
        "global_load_dword   %[R0], %[P0], off offset:16\n\t"
        "global_load_dwordx4 %[A1], %[P1], off\n\t"
        "global_load_dword   %[L1], %[P1], off offset:-4\n\t"
        "global_load_dword   %[R1], %[P1], off offset:16\n\t"
        "global_load_dwordx4 %[A2], %[P2], off\n\t"
        "global_load_dword   %[L2], %[P2], off offset:-4\n\t"
        "global_load_dword   %[R2], %[P2], off offset:16\n\t"
        "global_load_dwordx4 %[A3], %[P3], off\n\t"
        "global_load_dword   %[L3], %[P3], off offset:-4\n\t"
        "global_load_dword   %[R3], %[P3], off offset:16\n\t"
        : [A0]"=&v"(a0), [L0]"=&v"(l0), [R0]"=&v"(r0),
          [A1]"=&v"(a1), [L1]"=&v"(l1), [R1]"=&v"(r1),
          [A2]"=&v"(a2), [L2]"=&v"(l2), [R2]"=&v"(r2),
          [A3]"=&v"(a3), [L3]"=&v"(l3), [R3]"=&v"(r3)
        : [P0]"v"(p0), [P1]"v"(p1), [P2]"v"(p2), [P3]"v"(p3));
}

// 9 paired-corner gathers: dwordx2 with SGPR base + per-lane byte offsets.
// ROUND-23: deform is TA-ADDRESS-throughput bound (2304 addr/cin/wave);
// merging each horizontal corner pair (xc1 in {xc0, xc0+1}) into one 8B
// load halves the address count. Edge collapse handled by hi/lo select.
__device__ __forceinline__ void dfm_issue9w(
    const float* base, const int (&o)[9], f32x2 (&v)[9])
{
    asm volatile(
        "global_load_dwordx2 %[V0], %[O0], %[B]\n\t"
        "global_load_dwordx2 %[V1], %[O1], %[B]\n\t"
        "global_load_dwordx2 %[V2], %[O2], %[B]\n\t"
        "global_load_dwordx2 %[V3], %[O3], %[B]\n\t"
        "global_load_dwordx2 %[V4], %[O4], %[B]\n\t"
        "global_load_dwordx2 %[V5], %[O5], %[B]\n\t"
        "global_load_dwordx2 %[V6], %[O6], %[B]\n\t"
        "global_load_dwordx2 %[V7], %[O7], %[B]\n\t"
        "global_load_dwordx2 %[V8], %[O8], %[B]\n\t"
        : [V0]"=&v"(v[0]), [V1]"=&v"(v[1]), [V2]"=&v"(v[2]),
          [V3]"=&v"(v[3]), [V4]"=&v"(v[4]), [V5]"=&v"(v[5]),
          [V6]"=&v"(v[6]), [V7]"=&v"(v[7]), [V8]"=&v"(v[8])
        : [B]"s"(base),
          [O0]"v"(o[0]), [O1]"v"(o[1]), [O2]"v"(o[2]),
          [O3]"v"(o[3]), [O4]"v"(o[4]), [O5]"v"(o[5]),
          [O6]"v"(o[6]), [O7]"v"(o[7]), [O8]"v"(o[8]));
}

// ---------------------------------------------------------------------------
// Dtype probe (bf16 vs float32 inputs) -> flag in d_ws.
// ---------------------------------------------------------------------------
__global__ void __launch_bounds__(256) k_detect(const void* lstm_w_raw, int* flag)
{
    __shared__ int bad;
    if (threadIdx.x == 0) bad = 0;
    __syncthreads();
    const unsigned short* u = (const unsigned short*)lstm_w_raw;
    int local = 0;
    for (int i = threadIdx.x; i < GATES * TAPS_L; i += 256) {
        unsigned int f32 = ((unsigned int)u[i]) << 16;
        float v = __uint_as_float(f32);
        if (!(fabsf(v) <= 64.0f)) local = 1;
    }
    if (local) atomicOr(&bad, 1);
    __syncthreads();
    if (threadIdx.x == 0) flag[0] = bad ? 0 : 1;
}

// ---------------------------------------------------------------------------
// ConvLSTM step (R22 proven: asm-batched hp loop). Unchanged.
// ---------------------------------------------------------------------------
template <typename S>
__device__ __forceinline__ void conv_plane2r(
    const S* __restrict__ src, int cin, int y0, int x0, int kc,
    const float* __restrict__ sw, float (&acc)[2][4][4])
{
    float xs[4][6];  // rows y0-1 .. y0+2
#pragma unroll
    for (int r = 0; r < 4; r++) {
        int yy = y0 - 1 + r;
        if (yy >= 0 && yy < Hc) {
            const S* row = src + (long)yy * Wc;
            xs[r][0] = (x0 > 0) ? getv(row, x0 - 1) : 0.0f;
            load4(row, x0, &xs[r][1]);
            xs[r][5] = (x0 + 4 < Wc) ? getv(row, x0 + 4) : 0.0f;
        } else {
#pragma unroll
            for (int j = 0; j < 6; j++) xs[r][j] = 0.0f;
        }
    }
    float4 wq[9];
#pragma unroll
    for (int t9 = 0; t9 < 9; t9++)
        wq[t9] = *(const float4*)&sw[(((cin * 9 + t9) * 16) + kc) * 4];
#pragma unroll
    for (int ky = 0; ky < 3; ky++) {
#pragma unroll
        for (int kx = 0; kx < 3; kx++) {
            const float4 w = wq[ky * 3 + kx];
#pragma unroll
            for (int px = 0; px < 4; px++) {
                float v0 = xs[ky][px + kx];
                float v1 = xs[ky + 1][px + kx];
                acc[0][0][px] += w.x * v0;  acc[1][0][px] += w.x * v1;
                acc[0][1][px] += w.y * v0;  acc[1][1][px] += w.y * v1;
                acc[0][2][px] += w.z * v0;  acc[1][2][px] += w.z * v1;
                acc[0][3][px] += w.w * v0;  acc[1][3][px] += w.w * v1;
            }
        }
    }
}

template <typename T>
__device__ __forceinline__ void lstm2r_body(
    const T* __restrict__ X, const T* __restrict__ lstm_w, const T* __restrict__ lstm_b,
    const T* __restrict__ Wci, const T* __restrict__ Wcf, const T* __restrict__ Wco,
    float* __restrict__ c_buf, float* __restrict__ xcat, int t,
    float* sw, float* sb)
{
    for (int i = threadIdx.x; i < GATES * TAPS_L; i += 256) {
        int co = i / TAPS_L, tap = i - co * TAPS_L;
        int kc = co & 15, g = co >> 4;
        sw[(tap * 16 + kc) * 4 + g] = getv(lstm_w, i);
    }
    if (threadIdx.x < GATES) sb[threadIdx.x] = getv(lstm_b, threadIdx.x);
    __syncthreads();

    int blk = xcd_chunked(blockIdx.x, Bn * 90 * 5);  // 900; row-sharers same XCD
    int seg = blk % 5; int rem = blk / 5;
    int yp = rem % 90; int b = rem / 90;
    int y0 = yp * 2;
    int kc = threadIdx.x >> 4, pl = threadIdx.x & 15;
    int x0 = seg * 64 + pl * 4;

    float acc[2][4][4];  // [row][gate][px]
#pragma unroll
    for (int px = 0; px < 4; px++) {
#pragma unroll
        for (int r = 0; r < 2; r++) {
            acc[r][0][px] = sb[kc];
            acc[r][1][px] = sb[16 + kc];
            acc[r][2][px] = sb[32 + kc];
            acc[r][3][px] = sb[48 + kc];
        }
    }

    const T* xt = X + (long)(b * Tn + t) * NCc * HWc;
#pragma unroll 1
    for (int cin = 0; cin < NCc; cin++)
        conv_plane2r(xt + (long)cin * HWc, cin, y0, x0, kc, sw, acc);

    if (t > 0) {
        const float* hp = xcat + ((long)b * CIN_D + (t - 1) * NKc) * HWc;
        long ro[4]; float vm[4];
#pragma unroll
        for (int r = 0; r < 4; r++) {
            int yy = y0 - 1 + r;
            vm[r] = (yy >= 0 && yy < Hc) ? 1.0f : 0.0f;
            ro[r] = (long)min(max(yy, 0), Hc - 1) * Wc + x0;
        }
        const float m0 = (x0 > 0) ? 1.0f : 0.0f;
        const float m1 = (x0 + 4 < Wc) ? 1.0f : 0.0f;

#pragma unroll 1
        for (int cin = 0; cin < NKc; cin++) {
            const float* xc = hp + (long)cin * HWc;
            f32x4 a0, a1, a2, a3;
            float l0, l1, l2, l3, rh0, rh1, rh2, rh3;
            lstm_issue12(xc + ro[0], xc + ro[1], xc + ro[2], xc + ro[3],
                         a0, l0, rh0, a1, l1, rh1, a2, l2, rh2, a3, l3, rh3);
            float4 wq[9];   // LDS reads overlap the vmem latency (before wait)
#pragma unroll
            for (int t9 = 0; t9 < 9; t9++)
                wq[t9] = *(const float4*)&sw[((((cin + NCc) * 9 + t9) * 16) + kc) * 4];
            om_wait();
            float xs[4][6];
#pragma unroll
            for (int r = 0; r < 4; r++) {
                const f32x4 a = (r == 0) ? a0 : (r == 1) ? a1 : (r == 2) ? a2 : a3;
                const float ll = (r == 0) ? l0 : (r == 1) ? l1 : (r == 2) ? l2 : l3;
                const float rr = (r == 0) ? rh0 : (r == 1) ? rh1 : (r == 2) ? rh2 : rh3;
                xs[r][0] = ll * vm[r] * m0;
                xs[r][1] = a.x * vm[r]; xs[r][2] = a.y * vm[r];
                xs[r][3] = a.z * vm[r]; xs[r][4] = a.w * vm[r];
                xs[r][5] = rr * vm[r] * m1;
            }
#pragma unroll
            for (int ky = 0; ky < 3; ky++) {
#pragma unroll
                for (int kx = 0; kx < 3; kx++) {
                    const float4 w = wq[ky * 3 + kx];
#pragma unroll
                    for (int px = 0; px < 4; px++) {
                        float v0 = xs[ky][px + kx];
                        float v1 = xs[ky + 1][px + kx];
                        acc[0][0][px] += w.x * v0;  acc[1][0][px] += w.x * v1;
                        acc[0][1][px] += w.y * v0;  acc[1][1][px] += w.y * v1;
                        acc[0][2][px] += w.z * v0;  acc[1][2][px] += w.z * v1;
                        acc[0][3][px] += w.w * v0;  acc[1][3][px] += w.w * v1;
                    }
                }
            }
        }
    }

#pragma unroll
    for (int r = 0; r < 2; r++) {
        int y = y0 + r;
        long pbase = (long)y * Wc + x0;
        float* cb = c_buf + (long)(b * NKc + kc) * HWc + pbase;
        float cprev[4];
        if (t > 0) {
            const float4 cv = *(const float4*)cb;
            cprev[0] = cv.x; cprev[1] = cv.y; cprev[2] = cv.z; cprev[3] = cv.w;
        } else {
            cprev[0] = cprev[1] = cprev[2] = cprev[3] = 0.0f;
        }
        float wci[4], wcf[4], wco[4];
        load4(Wci + (long)kc * HWc + pbase, 0, wci);
        load4(Wcf + (long)kc * HWc + pbase, 0, wcf);
        load4(Wco + (long)kc * HWc + pbase, 0, wco);

        float cn4[4], h4[4];
#pragma unroll
        for (int px = 0; px < 4; px++) {
            float ii = sigm(acc[r][0][px] + wci[px] * cprev[px]);
            float ff = sigm(acc[r][1][px] + wcf[px] * cprev[px]);
            float cn = ff * cprev[px] + ii * tanh_(acc[r][2][px]);
            float oo = sigm(acc[r][3][px] + wco[px] * cn);
            cn4[px] = cn; h4[px] = oo * tanh_(cn);
        }
        *(float4*)cb = make_float4(cn4[0], cn4[1], cn4[2], cn4[3]);
        *(float4*)(xcat + ((long)b * CIN_D + t * NKc + kc) * HWc + pbase) =
            make_float4(h4[0], h4[1], h4[2], h4[3]);
    }
}

__global__ void __launch_bounds__(256) k_lstm2(
    const void* X, const void* lstm_w, const void* lstm_b,
    const void* Wci, const void* Wcf, const void* Wco,
    const int* __restrict__ flag,
    float* c_buf, float* xcat, int t)
{
    __shared__ float sw[TAPS_L * GATES];  // 43.8 KB
    __shared__ float sb[GATES];
    if (flag[0])
        lstm2r_body<bf16>((const bf16*)X, (const bf16*)lstm_w, (const bf16*)lstm_b,
                          (const bf16*)Wci, (const bf16*)Wcf, (const bf16*)Wco,
                          c_buf, xcat, t, sw, sb);
    else
        lstm2r_body<float>((const float*)X, (const float*)lstm_w, (const float*)lstm_b,
                           (const float*)Wci, (const float*)Wcf, (const float*)Wco,
                           c_buf, xcat, t, sw, sb);
}

// ---------------------------------------------------------------------------
// offmod v12 (R21 proven: fat 8px threads + asm-batched row loads). Unchanged.
// ---------------------------------------------------------------------------
template <typename T>
__device__ __forceinline__ void offmod12_body(
    const float* __restrict__ xcat,
    const T* __restrict__ off_w, const T* __restrict__ off_b,
    const T* __restrict__ mod_w, const T* __restrict__ mod_b,
    float* __restrict__ offbuf, float* __restrict__ maskbuf,
    float* sw, float* sb)
{
    int rb = xcd_chunked(blockIdx.x, 450);
    int type = rb & 1;
    int chunk = rb >> 1;          // [0,225)
    const int nslot = type ? 12 : 16;

    for (int i = threadIdx.x; i < TAPS_D * nslot; i += 256) {
        int tap = i / nslot, j = i - tap * nslot;
        int o = type ? 16 + j : j;
        float v = 0.0f;
        if (o < 18) v = getv(off_w, (long)o * TAPS_D + tap);
        else if (o < 27) v = getv(mod_w, (long)(o - 18) * TAPS_D + tap);
        sw[tap * nslot + j] = v;
    }
    if (threadIdx.x < nslot) {
        int o = (type ? 16 : 0) + threadIdx.x;
        sb[threadIdx.x] = (o < 18) ? getv(off_b, o)
                        : (o < 27 ? getv(mod_b, o - 18) : 0.0f);
    }
    __syncthreads();

    int og = threadIdx.x >> 6, lane = threadIdx.x & 63;
    long p0 = (long)chunk * 512 + lane * 8;
    int b = (int)(p0 / HWc);
    int p = (int)(p0 - (long)b * HWc);
    int y = p / Wc, x0 = p - (p / Wc) * Wc;   // x0 multiple of 8

    const int per = type ? 3 : 4;
    int jbase = og * per;

    const float* xb = xcat + (long)b * CIN_D * HWc;
    long yo[3]; float vm[3];
#pragma unroll
    for (int ky = 0; ky < 3; ky++) {
        int yy = y + ky - 1;
        vm[ky] = (yy >= 0 && yy < Hc) ? 1.0f : 0.0f;
        yo[ky] = (long)min(max(yy, 0), Hc - 1) * Wc + x0;
    }
    const float m0 = (x0 > 0) ? 1.0f : 0.0f;
    const float m1 = (x0 + 8 < Wc) ? 1.0f : 0.0f;

    float acc[4][8];
#pragma unroll
    for (int j = 0; j < 4; j++) {
        float bv = (j < per) ? sb[jbase + j] : 0.0f;
#pragma unroll
        for (int px = 0; px < 8; px++) acc[j][px] = bv;
    }

    if (type == 0) {
#pragma unroll 1
        for (int cin = 0; cin < CIN_D; cin++) {
            const float* xc = xb + (long)cin * HWc;
            f32x4 a0, b0v, a1, b1v, a2, b2v;
            float h00, h01, h10, h11, h20, h21;
            om_issue12(xc + yo[0], xc + yo[1], xc + yo[2],
                       a0, b0v, h00, h01, a1, b1v, h10, h11, a2, b2v, h20, h21);
            float4 wr[9];
#pragma unroll
            for (int t9 = 0; t9 < 9; t9++)
                wr[t9] = *(const float4*)&sw[(cin * 9 + t9) * 16 + jbase];
            om_wait();
            float xs[3][10];
#pragma unroll
            for (int ky = 0; ky < 3; ky++) {
                const f32x4 a = (ky == 0) ? a0 : (ky == 1) ? a1 : a2;
                const f32x4 bb = (ky == 0) ? b0v : (ky == 1) ? b1v : b2v;
                const float hh0 = (ky == 0) ? h00 : (ky == 1) ? h10 : h20;
                const float hh1 = (ky == 0) ? h01 : (ky == 1) ? h11 : h21;
                xs[ky][0] = hh0 * vm[ky] * m0;
                xs[ky][1] = a.x * vm[ky]; xs[ky][2] = a.y * vm[ky];
                xs[ky][3] = a.z * vm[ky]; xs[ky][4] = a.w * vm[ky];
                xs[ky][5] = bb.x * vm[ky]; xs[ky][6] = bb.y * vm[ky];
                xs[ky][7] = bb.z * vm[ky]; xs[ky][8] = bb.w * vm[ky];
                xs[ky][9] = hh1 * vm[ky] * m1;
            }
#pragma unroll
            for (int ky = 0; ky < 3; ky++) {
#pragma unroll
                for (int kx = 0; kx < 3; kx++) {
                    const float4 wq = wr[ky * 3 + kx];
#pragma unroll
                    for (int px = 0; px < 8; px++) {
                        float v = xs[ky][px + kx];
                        acc[0][px] += wq.x * v;
                        acc[1][px] += wq.y * v;
                        acc[2][px] += wq.z * v;
                        acc[3][px] += wq.w * v;
                    }
                }
            }
        }
    } else {
#pragma unroll 1
        for (int cin = 0; cin < CIN_D; cin++) {
            const float* xc = xb + (long)cin * HWc;
            f32x4 a0, b0v, a1, b1v, a2, b2v;
            float h00, h01, h10, h11, h20, h21;
            om_issue12(xc + yo[0], xc + yo[1], xc + yo[2],
                       a0, b0v, h00, h01, a1, b1v, h10, h11, a2, b2v, h20, h21);
            float3 wr[9];
#pragma unroll
            for (int t9 = 0; t9 < 9; t9++) {
                const float* wp = &sw[(cin * 9 + t9) * 12 + jbase];
                wr[t9] = make_float3(wp[0], wp[1], wp[2]);
            }
            om_wait();
            float xs[3][10];
#pragma unroll
            for (int ky = 0; ky < 3; ky++) {
                const f32x4 a = (ky == 0) ? a0 : (ky == 1) ? a1 : a2;
                const f32x4 bb = (ky == 0) ? b0v : (ky == 1) ? b1v : b2v;
                const float hh0 = (ky == 0) ? h00 : (ky == 1) ? h10 : h20;
                const float hh1 = (ky == 0) ? h01 : (ky == 1) ? h11 : h21;
                xs[ky][0] = hh0 * vm[ky] * m0;
                xs[ky][1] = a.x * vm[ky]; xs[ky][2] = a.y * vm[ky];
                xs[ky][3] = a.z * vm[ky]; xs[ky][4] = a.w * vm[ky];
                xs[ky][5] = bb.x * vm[ky]; xs[ky][6] = bb.y * vm[ky];
                xs[ky][7] = bb.z * vm[ky]; xs[ky][8] = bb.w * vm[ky];
                xs[ky][9] = hh1 * vm[ky] * m1;
            }
#pragma unroll
            for (int ky = 0; ky < 3; ky++) {
#pragma unroll
                for (int kx = 0; kx < 3; kx++) {
                    const float3 wq = wr[ky * 3 + kx];
#pragma unroll
                    for (int px = 0; px < 8; px++) {
                        float v = xs[ky][px + kx];
                        acc[0][px] += wq.x * v;
                        acc[1][px] += wq.y * v;
                        acc[2][px] += wq.z * v;
                    }
                }
            }
        }
    }

    long pbase = (long)y * Wc + x0;
#pragma unroll
    for (int j = 0; j < 4; j++) {
        if (j >= per) break;
        int o = (type ? 16 : 0) + jbase + j;
        if (o >= 27) break;
        if (o < 18) {
            float* dst = offbuf + ((long)b * 18 + o) * HWc + pbase;
            *(float4*)dst = make_float4(acc[j][0], acc[j][1], acc[j][2], acc[j][3]);
            *(float4*)(dst + 4) = make_float4(acc[j][4], acc[j][5], acc[j][6], acc[j][7]);
        } else {
            float* dst = maskbuf + ((long)b * 9 + (o - 18)) * HWc + pbase;
            *(float4*)dst = make_float4(2.0f * sigm(acc[j][0]), 2.0f * sigm(acc[j][1]),
                                        2.0f * sigm(acc[j][2]), 2.0f * sigm(acc[j][3]));
            *(float4*)(dst + 4) = make_float4(2.0f * sigm(acc[j][4]), 2.0f * sigm(acc[j][5]),
                                              2.0f * sigm(acc[j][6]), 2.0f * sigm(acc[j][7]));
        }
    }
}

__global__ void __launch_bounds__(256) k_offmod(
    const float* xcat, const void* off_w, const void* off_b,
    const void* mod_w, const void* mod_b, const int* __restrict__ flag,
    float* offbuf, float* maskbuf)
{
    __shared__ float sw[TAPS_D * 16];  // 36.9 KB (type A); type B uses 27.6 KB
    __shared__ float sb[16];
    if (flag[0])
        offmod12_body<bf16>(xcat, (const bf16*)off_w, (const bf16*)off_b,
                            (const bf16*)mod_w, (const bf16*)mod_b, offbuf, maskbuf, sw, sb);
    else
        offmod12_body<float>(xcat, (const float*)off_w, (const float*)off_b,
                             (const float*)mod_w, (const float*)mod_b, offbuf, maskbuf, sw, sb);
}

// ---------------------------------------------------------------------------
// deform v5 (ROUND-23): paired-corner dwordx2 gathers — 18 loads/cin instead
// of 36, halving the TA address stream that bounds this kernel.
// v01 corner = (xc1>xc0) ? hi : lo of the 8B load at xc0 (clamp-collapse).
// ---------------------------------------------------------------------------
template <typename T>
__device__ __forceinline__ void deform5_body(
    const float* __restrict__ xcat, const float* __restrict__ offbuf,
    const float* __restrict__ maskbuf,
    const T* __restrict__ def_w, const T* __restrict__ def_b,
    float* __restrict__ dcout, float* sw, float* sb)
{
    for (int i = threadIdx.x; i < NKc * TAPS_D; i += 256) {
        int co = i / TAPS_D;
        int tap = i - co * TAPS_D;
        sw[tap * NKc + co] = getv(def_w, i);
    }
    if (threadIdx.x < NKc) sb[threadIdx.x] = getv(def_b, threadIdx.x);
    __syncthreads();

    int blk = xcd_chunked(blockIdx.x, NPIX / 256);
    int idx0 = blk * 256;            // block-uniform
    int b = idx0 / HWc;              // uniform -> SGPR
    int p = idx0 - b * HWc + threadIdx.x;
    int y = p / Wc, x = p - (p / Wc) * Wc;

    float w00[9], w01[9], w10[9], w11[9];
    int o0[9], o1[9];                // byte offsets of the 8B pair loads
    float sel[9];                    // 1.0 if xc1 == xc0+1 else 0.0
#pragma unroll
    for (int k = 0; k < 9; k++) {
        int ky = k / 3, kx = k - (k / 3) * 3;
        float dy = offbuf[((long)b * 18 + 2 * k) * HWc + p];
        float dx = offbuf[((long)b * 18 + 2 * k + 1) * HWc + p];
        float m = maskbuf[((long)b * 9 + k) * HWc + p];
        float py = (float)(y - 1 + ky) + dy;
        float px = (float)(x - 1 + kx) + dx;
        float y0f = floorf(py), x0f = floorf(px);
        int y0 = (int)y0f, x0 = (int)x0f;
        float wy1 = py - y0f, wx1 = px - x0f;
        float a00 = (1.0f - wy1) * (1.0f - wx1) * m;
        float a01 = (1.0f - wy1) * wx1 * m;
        float a10 = wy1 * (1.0f - wx1) * m;
        float a11 = wy1 * wx1 * m;
        bool vy0 = (y0 >= 0) && (y0 < Hc);
        bool vy1 = (y0 + 1 >= 0) && (y0 + 1 < Hc);
        bool vx0 = (x0 >= 0) && (x0 < Wc);
        bool vx1 = (x0 + 1 >= 0) && (x0 + 1 < Wc);
        w00[k] = (vy0 && vx0) ? a00 : 0.0f;
        w01[k] = (vy0 && vx1) ? a01 : 0.0f;
        w10[k] = (vy1 && vx0) ? a10 : 0.0f;
        w11[k] = (vy1 && vx1) ? a11 : 0.0f;
        int yc0 = min(max(y0, 0), Hc - 1);
        int yc1 = min(max(y0 + 1, 0), Hc - 1);
        int xc0 = min(max(x0, 0), Wc - 1);
        int xc1 = min(max(x0 + 1, 0), Wc - 1);
        o0[k] = (yc0 * Wc + xc0) * 4;
        o1[k] = (yc1 * Wc + xc0) * 4;
        sel[k] = (xc1 > xc0) ? 1.0f : 0.0f;
    }

    float acc[NKc];
#pragma unroll
    for (int i = 0; i < NKc; i++) acc[i] = sb[i];

    const float* xb = xcat + (long)b * CIN_D * HWc;   // uniform -> SGPR
#pragma unroll 1
    for (int cin = 0; cin < CIN_D; cin++) {
        const float* xc = xb + (long)cin * HWc;       // uniform -> SGPR
        f32x2 u0[9], u1[9];
        dfm_issue9w(xc, o0, u0);
        dfm_issue9w(xc, o1, u1);
        om_wait();
        float s[9];
#pragma unroll
        for (int k = 0; k < 9; k++) {
            float v01 = u0[k].x + sel[k] * (u0[k].y - u0[k].x);
            float v11 = u1[k].x + sel[k] * (u1[k].y - u1[k].x);
            s[k] = w00[k] * u0[k].x + w01[k] * v01 +
                   w10[k] * u1[k].x + w11[k] * v11;
        }
#pragma unroll
        for (int k = 0; k < 9; k++) {
            const float* wrow = &sw[(cin * 9 + k) * NKc];
#pragma unroll
            for (int co = 0; co < NKc; co++) acc[co] += wrow[co] * s[k];
        }
    }

#pragma unroll
    for (int co = 0; co < NKc; co++)
        dcout[((long)b * NKc + co) * HWc + p] = acc[co];
}

__global__ void __launch_bounds__(256) k_deform(
    const float* xcat, const float* offbuf, const float* maskbuf,
    const void* def_w, const void* def_b, const int* __restrict__ flag,
    float* dcout)
{
    __shared__ float sw[TAPS_D * NKc];  // 36.9 KB
    __shared__ float sb[NKc];
    if (flag[0])
        deform5_body<bf16>(xcat, offbuf, maskbuf, (const bf16*)def_w, (const bf16*)def_b,
                           dcout, sw, sb);
    else
        deform5_body<float>(xcat, offbuf, maskbuf, (const float*)def_w, (const float*)def_b,
                            dcout, sw, sb);
}

// ---------------------------------------------------------------------------
// outconv v8 (R19 proven form). Unchanged.
// ---------------------------------------------------------------------------
template <typename T>
__device__ __forceinline__ void outconv6_body(
    const float* __restrict__ dcout, const T* __restrict__ out_w,
    const T* __restrict__ out_b, T* __restrict__ out, float* sw, float* sb)
{
    int rb = xcd_chunked(blockIdx.x, 900);
    int type = rb & 1;
    int chunk = rb >> 1;

    for (int i = threadIdx.x; i < 24 * TAPS_O; i += 256) {
        int o = i / TAPS_O, tap = i - o * TAPS_O;
        int slot = (o / 6) * 8 + (o % 6);
        sw[tap * 32 + slot] = getv(out_w, (long)(type * 24 + o) * TAPS_O + tap);
    }
    if (threadIdx.x < 24) sb[threadIdx.x] = getv(out_b, type * 24 + threadIdx.x);
    __syncthreads();

    int og = threadIdx.x >> 6, lane = threadIdx.x & 63;
    long p0 = ((long)chunk * 64 + lane) * 4;
    int b = (int)(p0 / HWc);
    int p = (int)(p0 - (long)b * HWc);
    int y = p / Wc, x0 = p - (p / Wc) * Wc;

    float acc[6][4];
#pragma unroll
    for (int j = 0; j < 6; j++) {
        float bv = sb[og * 6 + j];
#pragma unroll
        for (int px = 0; px < 4; px++) acc[j][px] = bv;
    }

    const float* xb = dcout + (long)b * NKc * HWc;
#pragma unroll 1
    for (int cin = 0; cin < NKc; cin++) {
        const float* xc = xb + (long)cin * HWc;
        float xs[3][6];
#pragma unroll
        for (int ky = 0; ky < 3; ky++) {
            int yy = y + ky - 1;
            if (yy >= 0 && yy < Hc) {
                const float* row = xc + (long)yy * Wc;
                xs[ky][0] = (x0 > 0) ? row[x0 - 1] : 0.0f;
                load4(row, x0, &xs[ky][1]);
                xs[ky][5] = (x0 + 4 < Wc) ? row[x0 + 4] : 0.0f;
            } else {
#pragma unroll
                for (int j = 0; j < 6; j++) xs[ky][j] = 0.0f;
            }
        }
        float4 wa[9]; float2 wb[9];
#pragma unroll
        for (int t9 = 0; t9 < 9; t9++) {
            const float* wp = &sw[(cin * 9 + t9) * 32 + og * 8];
            wa[t9] = *(const float4*)wp;
            wb[t9] = *(const float2*)(wp + 4);
        }
#pragma unroll
        for (int ky = 0; ky < 3; ky++) {
#pragma unroll
            for (int kx = 0; kx < 3; kx++) {
                const float4 w0 = wa[ky * 3 + kx];
                const float2 w1 = wb[ky * 3 + kx];
#pragma unroll
                for (int px = 0; px < 4; px++) {
                    float v = xs[ky][px + kx];
                    acc[0][px] += w0.x * v;  acc[1][px] += w0.y * v;
                    acc[2][px] += w0.z * v;  acc[3][px] += w0.w * v;
                    acc[4][px] += w1.x * v;  acc[5][px] += w1.y * v;
                }
            }
        }
    }

#pragma unroll
    for (int j = 0; j < 6; j++) {
        int co = type * 24 + og * 6 + j;
        int cc = co >> 4;
        int r = co & 15;
        int ii = r >> 2, jj = r & 3;
        long ob = (((long)b * 3 + cc) * (Hc * 4) + (y * 4 + ii)) * (long)(Wc * 4);
#pragma unroll
        for (int px = 0; px < 4; px++) {
            float v = fminf(fmaxf(acc[j][px], 0.0f), 255.0f);
            putv(out, ob + (x0 + px) * 4 + jj, v);
        }
    }
}

__global__ void __launch_bounds__(256) k_outconv(
    const float* dcout, const void* out_w, const void* out_b,
    const int* __restrict__ flag, void* out)
{
    __shared__ float sw[TAPS_O * 32];  // 18.4 KB
    __shared__ float sb[24];
    if (flag[0])
        outconv6_body<bf16>(dcout, (const bf16*)out_w, (const bf16*)out_b, (bf16*)out, sw, sb);
    else
        outconv6_body<float>(dcout, (const float*)out_w, (const float*)out_b, (float*)out, sw, sb);
}

extern "C" void kernel_launch(void* const* d_in, const int* in_sizes, int n_in,
                              void* d_out, int out_size, void* d_ws, size_t ws_size,
                              hipStream_t stream) {
    const void* X      = d_in[0];
    const void* lstm_w = d_in[1];
    const void* lstm_b = d_in[2];
    const void* Wci    = d_in[3];
    const void* Wcf    = d_in[4];
    const void* Wco    = d_in[5];
    const void* off_w  = d_in[6];
    const void* off_b  = d_in[7];
    const void* mod_w  = d_in[8];
    const void* mod_b  = d_in[9];
    const void* def_w  = d_in[10];
    const void* def_b  = d_in[11];
    const void* out_w  = d_in[12];
    const void* out_b  = d_in[13];

    int* flag = (int*)d_ws;
    float* W = (float*)d_ws + 64;
    size_t o = 0;
    float* c_buf   = W + o; o += (size_t)Bn * NKc * HWc;
    float* xcat    = W + o; o += (size_t)Bn * CIN_D * HWc;
    float* offbuf  = W + o; o += (size_t)Bn * 18 * HWc;
    float* maskbuf = W + o; o += (size_t)Bn * 9 * HWc;
    float* dcout   = W + o; o += (size_t)Bn * NKc * HWc;

    dim3 blk(256);
    dim3 gridP(NPIX / 256);           // 450
    dim3 gridL2(Bn * (Hc / 2) * 5);   // 900: 2-row lstm blocks
    dim3 gridOM(2 * (NPIX / 512));    // 450: fat-thread offmod (8px/lane)
    dim3 gridC2(2 * (NPIX / 4 / 64)); // 900

    k_detect<<<1, blk, 0, stream>>>(lstm_w, flag);
    for (int t = 0; t < Tn; t++) {
        k_lstm2<<<gridL2, blk, 0, stream>>>(X, lstm_w, lstm_b, Wci, Wcf, Wco,
                                            flag, c_buf, xcat, t);
    }
    k_offmod<<<gridOM, blk, 0, stream>>>(xcat, off_w, off_b, mod_w, mod_b, flag,
                                         offbuf, maskbuf);
    k_deform<<<gridP, blk, 0, stream>>>(xcat, offbuf, maskbuf, def_w, def_b, flag, dcout);
    k_outconv<<<gridC2, blk, 0, stream>>>(dcout, out_w, out_b, flag, d_out);
}

// Round 12
// 575.623 us; speedup vs baseline: 1.5076x; 1.0287x over previous
//
#include <hip/hip_runtime.h>
#include <hip/hip_bf16.h>

// Problem dims
#define Bn 2
#define Tn 4
#define NCc 3
#define NKc 16
#define Hc 180
#define Wc 320
#define HWc (Hc * Wc)          // 57600
#define NPIX (Bn * HWc)        // 115200
#define CIN_LSTM 19            // NC + NK
#define GATES 64               // 4*NK
#define CIN_D 64               // T*NK
#define TAPS_L (CIN_LSTM * 9)  // 171
#define TAPS_D (CIN_D * 9)     // 576
#define TAPS_O (NKc * 9)       // 144

typedef __hip_bfloat16 bf16;
typedef float f32x4 __attribute__((ext_vector_type(4)));
typedef float f32x2 __attribute__((ext_vector_type(2)));

__device__ __forceinline__ float getv(const float* p, long i) { return p[i]; }
__device__ __forceinline__ float getv(const bf16* p, long i) {
    unsigned int u = ((unsigned int)((const unsigned short*)p)[i]) << 16;
    return __uint_as_float(u);
}
__device__ __forceinline__ void putv(float* p, long i, float v) { p[i] = v; }
__device__ __forceinline__ void putv(bf16* p, long i, float v) { p[i] = __float2bfloat16(v); }
__device__ __forceinline__ float sigm(float x) { return 1.0f / (1.0f + __expf(-x)); }
__device__ __forceinline__ float tanh_(float x) { return 1.0f - 2.0f / (__expf(2.0f * x) + 1.0f); }

__device__ __forceinline__ void load4(const float* row, int x0, float* d) {
    const float4 v = *(const float4*)(row + x0);
    d[0] = v.x; d[1] = v.y; d[2] = v.z; d[3] = v.w;
}
__device__ __forceinline__ void load4(const bf16* row, int x0, float* d) {
    ushort4 u = *(const ushort4*)((const unsigned short*)row + x0);
    d[0] = __uint_as_float(((unsigned int)u.x) << 16);
    d[1] = __uint_as_float(((unsigned int)u.y) << 16);
    d[2] = __uint_as_float(((unsigned int)u.z) << 16);
    d[3] = __uint_as_float(((unsigned int)u.w) << 16);
}

// ---------------------------------------------------------------------------
// XCD-aware bijective chunked swizzle (T1, m204 formula). Proven R17.
// ---------------------------------------------------------------------------
__device__ __forceinline__ int xcd_chunked(int i, int nwg) {
    int q = nwg >> 3, r = nwg & 7;
    int xcd = i & 7, idx = i >> 3;
    return (xcd < r ? xcd * (q + 1) : r * (q + 1) + (xcd - r) * q) + idx;
}

// ---------------------------------------------------------------------------
// R21-PROVEN: force-batched loads via inline asm (early-clobber outputs
// defeat the compiler's load re-serialization).
// ---------------------------------------------------------------------------
__device__ __forceinline__ void om_wait()
{
    asm volatile("s_waitcnt vmcnt(0)" ::: "memory");
    __builtin_amdgcn_sched_barrier(0);   // rule #18
}

// ROUND-24b offmod batch: 6 lane-contiguous dwordx4 (16B lane stride, 4
// lanes/line) + 6 wave-uniform edge dwords.  Edge pointers passed as plain
// "v" 64-bit pointers (R24 compile fail: "s"-constraint on pointer-array
// elements degraded to VGPR saddr — clang can't prove uniformity through
// indexed pointer arrays).  Uniform-address loads broadcast: 1 line each.
__device__ __forceinline__ void om13_issue(
    const float* a0p, const float* a1p, const float* a2p,
    const float* b0p, const float* b1p, const float* b2p,
    const float* l0p, const float* l1p, const float* l2p,
    const float* r0p, const float* r1p, const float* r2p,
    f32x4& A0, f32x4& A1, f32x4& A2, f32x4& B0, f32x4& B1, f32x4& B2,
    float& l0, float& l1, float& l2, float& r0, float& r1, float& r2)
{
    asm volatile(
        "global_load_dwordx4 %[A0], %[a0], off\n\t"
        "global_load_dwordx4 %[A1], %[a1], off\n\t"
        "global_load_dwordx4 %[A2], %[a2], off\n\t"
        "global_load_dwordx4 %[B0], %[b0], off\n\t"
        "global_load_dwordx4 %[B1], %[b1], off\n\t"
        "global_load_dwordx4 %[B2], %[b2], off\n\t"
        "global_load_dword %[L0], %[l0p], off\n\t"
        "global_load_dword %[L1], %[l1p], off\n\t"
        "global_load_dword %[L2], %[l2p], off\n\t"
        "global_load_dword %[R0], %[r0p], off\n\t"
        "global_load_dword %[R1], %[r1p], off\n\t"
        "global_load_dword %[R2], %[r2p], off\n\t"
        : [A0]"=&v"(A0), [A1]"=&v"(A1), [A2]"=&v"(A2),
          [B0]"=&v"(B0), [B1]"=&v"(B1), [B2]"=&v"(B2),
          [L0]"=&v"(l0), [L1]"=&v"(l1), [L2]"=&v"(l2),
          [R0]"=&v"(r0), [R1]"=&v"(r1), [R2]"=&v"(r2)
        : [a0]"v"(a0p), [a1]"v"(a1p), [a2]"v"(a2p),
          [b0]"v"(b0p), [b1]"v"(b1p), [b2]"v"(b2p),
          [l0p]"v"(l0p), [l1p]"v"(l1p), [l2p]"v"(l2p),
          [r0p]"v"(r0p), [r1p]"v"(r1p), [r2p]"v"(r2p));
}

// 12 loads, 4 rows (lstm hp: window [x0-1, x0+4] per row).
__device__ __forceinline__ void lstm_issue12(
    const float* p0, const float* p1, const float* p2, const float* p3,
    f32x4& a0, float& l0, float& r0,
    f32x4& a1, float& l1, float& r1,
    f32x4& a2, float& l2, float& r2,
    f32x4& a3, float& l3, float& r3)
{
    asm volatile(
        "global_load_dwordx4 %[A0], %[P0], off\n\t"
        "global_load_dword   %[L0], %[P0], off offset:-4\n\t"
        "global_load_dword   %[R0], %[P0], off offset:16\n\t"
        "global_load_dwordx4 %[A1], %[P1], off\n\t"
        "global_load_dword   %[L1], %[P1], off offset:-4\n\t"
        "global_load_dword   %[R1], %[P1], off offset:16\n\t"
        "global_load_dwordx4 %[A2], %[P2], off\n\t"
        "global_load_dword   %[L2], %[P2], off offset:-4\n\t"
        "global_load_dword   %[R2], %[P2], off offset:16\n\t"
        "global_load_dwordx4 %[A3], %[P3], off\n\t"
        "global_load_dword   %[L3], %[P3], off offset:-4\n\t"
        "global_load_dword   %[R3], %[P3], off offset:16\n\t"
        : [A0]"=&v"(a0), [L0]"=&v"(l0), [R0]"=&v"(r0),
          [A1]"=&v"(a1), [L1]"=&v"(l1), [R1]"=&v"(r1),
          [A2]"=&v"(a2), [L2]"=&v"(l2), [R2]"=&v"(r2),
          [A3]"=&v"(a3), [L3]"=&v"(l3), [R3]"=&v"(r3)
        : [P0]"v"(p0), [P1]"v"(p1), [P2]"v"(p2), [P3]"v"(p3));
}

// 9 paired-corner gathers (deform, R23 proven).
__device__ __forceinline__ void dfm_issue9w(
    const float* base, const int (&o)[9], f32x2 (&v)[9])
{
    asm volatile(
        "global_load_dwordx2 %[V0], %[O0], %[B]\n\t"
        "global_load_dwordx2 %[V1], %[O1], %[B]\n\t"
        "global_load_dwordx2 %[V2], %[O2], %[B]\n\t"
        "global_load_dwordx2 %[V3], %[O3], %[B]\n\t"
        "global_load_dwordx2 %[V4], %[O4], %[B]\n\t"
        "global_load_dwordx2 %[V5], %[O5], %[B]\n\t"
        "global_load_dwordx2 %[V6], %[O6], %[B]\n\t"
        "global_load_dwordx2 %[V7], %[O7], %[B]\n\t"
        "global_load_dwordx2 %[V8], %[O8], %[B]\n\t"
        : [V0]"=&v"(v[0]), [V1]"=&v"(v[1]), [V2]"=&v"(v[2]),
          [V3]"=&v"(v[3]), [V4]"=&v"(v[4]), [V5]"=&v"(v[5]),
          [V6]"=&v"(v[6]), [V7]"=&v"(v[7]), [V8]"=&v"(v[8])
        : [B]"s"(base),
          [O0]"v"(o[0]), [O1]"v"(o[1]), [O2]"v"(o[2]),
          [O3]"v"(o[3]), [O4]"v"(o[4]), [O5]"v"(o[5]),
          [O6]"v"(o[6]), [O7]"v"(o[7]), [O8]"v"(o[8]));
}

// ---------------------------------------------------------------------------
// Dtype probe (bf16 vs float32 inputs) -> flag in d_ws.
// ---------------------------------------------------------------------------
__global__ void __launch_bounds__(256) k_detect(const void* lstm_w_raw, int* flag)
{
    __shared__ int bad;
    if (threadIdx.x == 0) bad = 0;
    __syncthreads();
    const unsigned short* u = (const unsigned short*)lstm_w_raw;
    int local = 0;
    for (int i = threadIdx.x; i < GATES * TAPS_L; i += 256) {
        unsigned int f32 = ((unsigned int)u[i]) << 16;
        float v = __uint_as_float(f32);
        if (!(fabsf(v) <= 64.0f)) local = 1;
    }
    if (local) atomicOr(&bad, 1);
    __syncthreads();
    if (threadIdx.x == 0) flag[0] = bad ? 0 : 1;
}

// ---------------------------------------------------------------------------
// ConvLSTM step (R22 proven: asm-batched hp loop). Unchanged.
// ---------------------------------------------------------------------------
template <typename S>
__device__ __forceinline__ void conv_plane2r(
    const S* __restrict__ src, int cin, int y0, int x0, int kc,
    const float* __restrict__ sw, float (&acc)[2][4][4])
{
    float xs[4][6];  // rows y0-1 .. y0+2
#pragma unroll
    for (int r = 0; r < 4; r++) {
        int yy = y0 - 1 + r;
        if (yy >= 0 && yy < Hc) {
            const S* row = src + (long)yy * Wc;
            xs[r][0] = (x0 > 0) ? getv(row, x0 - 1) : 0.0f;
            load4(row, x0, &xs[r][1]);
            xs[r][5] = (x0 + 4 < Wc) ? getv(row, x0 + 4) : 0.0f;
        } else {
#pragma unroll
            for (int j = 0; j < 6; j++) xs[r][j] = 0.0f;
        }
    }
    float4 wq[9];
#pragma unroll
    for (int t9 = 0; t9 < 9; t9++)
        wq[t9] = *(const float4*)&sw[(((cin * 9 + t9) * 16) + kc) * 4];
#pragma unroll
    for (int ky = 0; ky < 3; ky++) {
#pragma unroll
        for (int kx = 0; kx < 3; kx++) {
            const float4 w = wq[ky * 3 + kx];
#pragma unroll
            for (int px = 0; px < 4; px++) {
                float v0 = xs[ky][px + kx];
                float v1 = xs[ky + 1][px + kx];
                acc[0][0][px] += w.x * v0;  acc[1][0][px] += w.x * v1;
                acc[0][1][px] += w.y * v0;  acc[1][1][px] += w.y * v1;
                acc[0][2][px] += w.z * v0;  acc[1][2][px] += w.z * v1;
                acc[0][3][px] += w.w * v0;  acc[1][3][px] += w.w * v1;
            }
        }
    }
}

template <typename T>
__device__ __forceinline__ void lstm2r_body(
    const T* __restrict__ X, const T* __restrict__ lstm_w, const T* __restrict__ lstm_b,
    const T* __restrict__ Wci, const T* __restrict__ Wcf, const T* __restrict__ Wco,
    float* __restrict__ c_buf, float* __restrict__ xcat, int t,
    float* sw, float* sb)
{
    for (int i = threadIdx.x; i < GATES * TAPS_L; i += 256) {
        int co = i / TAPS_L, tap = i - co * TAPS_L;
        int kc = co & 15, g = co >> 4;
        sw[(tap * 16 + kc) * 4 + g] = getv(lstm_w, i);
    }
    if (threadIdx.x < GATES) sb[threadIdx.x] = getv(lstm_b, threadIdx.x);
    __syncthreads();

    int blk = xcd_chunked(blockIdx.x, Bn * 90 * 5);  // 900; row-sharers same XCD
    int seg = blk % 5; int rem = blk / 5;
    int yp = rem % 90; int b = rem / 90;
    int y0 = yp * 2;
    int kc = threadIdx.x >> 4, pl = threadIdx.x & 15;
    int x0 = seg * 64 + pl * 4;

    float acc[2][4][4];  // [row][gate][px]
#pragma unroll
    for (int px = 0; px < 4; px++) {
#pragma unroll
        for (int r = 0; r < 2; r++) {
            acc[r][0][px] = sb[kc];
            acc[r][1][px] = sb[16 + kc];
            acc[r][2][px] = sb[32 + kc];
            acc[r][3][px] = sb[48 + kc];
        }
    }

    const T* xt = X + (long)(b * Tn + t) * NCc * HWc;
#pragma unroll 1
    for (int cin = 0; cin < NCc; cin++)
        conv_plane2r(xt + (long)cin * HWc, cin, y0, x0, kc, sw, acc);

    if (t > 0) {
        const float* hp = xcat + ((long)b * CIN_D + (t - 1) * NKc) * HWc;
        long ro[4]; float vm[4];
#pragma unroll
        for (int r = 0; r < 4; r++) {
            int yy = y0 - 1 + r;
            vm[r] = (yy >= 0 && yy < Hc) ? 1.0f : 0.0f;
            ro[r] = (long)min(max(yy, 0), Hc - 1) * Wc + x0;
        }
        const float m0 = (x0 > 0) ? 1.0f : 0.0f;
        const float m1 = (x0 + 4 < Wc) ? 1.0f : 0.0f;

#pragma unroll 1
        for (int cin = 0; cin < NKc; cin++) {
            const float* xc = hp + (long)cin * HWc;
            f32x4 a0, a1, a2, a3;
            float l0, l1, l2, l3, rh0, rh1, rh2, rh3;
            lstm_issue12(xc + ro[0], xc + ro[1], xc + ro[2], xc + ro[3],
                         a0, l0, rh0, a1, l1, rh1, a2, l2, rh2, a3, l3, rh3);
            float4 wq[9];   // LDS reads overlap the vmem latency (before wait)
#pragma unroll
            for (int t9 = 0; t9 < 9; t9++)
                wq[t9] = *(const float4*)&sw[((((cin + NCc) * 9 + t9) * 16) + kc) * 4];
            om_wait();
            float xs[4][6];
#pragma unroll
            for (int r = 0; r < 4; r++) {
                const f32x4 a = (r == 0) ? a0 : (r == 1) ? a1 : (r == 2) ? a2 : a3;
                const float ll = (r == 0) ? l0 : (r == 1) ? l1 : (r == 2) ? l2 : l3;
                const float rr = (r == 0) ? rh0 : (r == 1) ? rh1 : (r == 2) ? rh2 : rh3;
                xs[r][0] = ll * vm[r] * m0;
                xs[r][1] = a.x * vm[r]; xs[r][2] = a.y * vm[r];
                xs[r][3] = a.z * vm[r]; xs[r][4] = a.w * vm[r];
                xs[r][5] = rr * vm[r] * m1;
            }
#pragma unroll
            for (int ky = 0; ky < 3; ky++) {
#pragma unroll
                for (int kx = 0; kx < 3; kx++) {
                    const float4 w = wq[ky * 3 + kx];
#pragma unroll
                    for (int px = 0; px < 4; px++) {
                        float v0 = xs[ky][px + kx];
                        float v1 = xs[ky + 1][px + kx];
                        acc[0][0][px] += w.x * v0;  acc[1][0][px] += w.x * v1;
                        acc[0][1][px] += w.y * v0;  acc[1][1][px] += w.y * v1;
                        acc[0][2][px] += w.z * v0;  acc[1][2][px] += w.z * v1;
                        acc[0][3][px] += w.w * v0;  acc[1][3][px] += w.w * v1;
                    }
                }
            }
        }
    }

#pragma unroll
    for (int r = 0; r < 2; r++) {
        int y = y0 + r;
        long pbase = (long)y * Wc + x0;
        float* cb = c_buf + (long)(b * NKc + kc) * HWc + pbase;
        float cprev[4];
        if (t > 0) {
            const float4 cv = *(const float4*)cb;
            cprev[0] = cv.x; cprev[1] = cv.y; cprev[2] = cv.z; cprev[3] = cv.w;
        } else {
            cprev[0] = cprev[1] = cprev[2] = cprev[3] = 0.0f;
        }
        float wci[4], wcf[4], wco[4];
        load4(Wci + (long)kc * HWc + pbase, 0, wci);
        load4(Wcf + (long)kc * HWc + pbase, 0, wcf);
        load4(Wco + (long)kc * HWc + pbase, 0, wco);

        float cn4[4], h4[4];
#pragma unroll
        for (int px = 0; px < 4; px++) {
            float ii = sigm(acc[r][0][px] + wci[px] * cprev[px]);
            float ff = sigm(acc[r][1][px] + wcf[px] * cprev[px]);
            float cn = ff * cprev[px] + ii * tanh_(acc[r][2][px]);
            float oo = sigm(acc[r][3][px] + wco[px] * cn);
            cn4[px] = cn; h4[px] = oo * tanh_(cn);
        }
        *(float4*)cb = make_float4(cn4[0], cn4[1], cn4[2], cn4[3]);
        *(float4*)(xcat + ((long)b * CIN_D + t * NKc + kc) * HWc + pbase) =
            make_float4(h4[0], h4[1], h4[2], h4[3]);
    }
}

__global__ void __launch_bounds__(256) k_lstm2(
    const void* X, const void* lstm_w, const void* lstm_b,
    const void* Wci, const void* Wcf, const void* Wco,
    const int* __restrict__ flag,
    float* c_buf, float* xcat, int t)
{
    __shared__ float sw[TAPS_L * GATES];  // 43.8 KB
    __shared__ float sb[GATES];
    if (flag[0])
        lstm2r_body<bf16>((const bf16*)X, (const bf16*)lstm_w, (const bf16*)lstm_b,
                          (const bf16*)Wci, (const bf16*)Wcf, (const bf16*)Wco,
                          c_buf, xcat, t, sw, sb);
    else
        lstm2r_body<float>((const float*)X, (const float*)lstm_w, (const float*)lstm_b,
                           (const float*)Wci, (const float*)Wcf, (const float*)Wco,
                           c_buf, xcat, t, sw, sb);
}

// ---------------------------------------------------------------------------
// offmod v13 (ROUND-24b): LANE-CONTIGUOUS loads + SHUFFLE halos.
// 8px/lane at 32B stride touched each 64B L1 line 2-3x per row (~384
// line-accesses/cin/wave) — L1 line throughput is the theorized stall.
// Each lane owns px {4i} and {256+4i}: 6 dwordx4 at 16B lane stride
// (4 lanes/line, 96 lines/cin) + horizontal halos via __shfl (no L1) +
// 6 wave-uniform edge dwords (broadcast, 1 line each).  Straddle halos are
// exactly the lanes the mL/mR masks already zero.
// ---------------------------------------------------------------------------
template <typename T>
__device__ __forceinline__ void offmod13_body(
    const float* __restrict__ xcat,
    const T* __restrict__ off_w, const T* __restrict__ off_b,
    const T* __restrict__ mod_w, const T* __restrict__ mod_b,
    float* __restrict__ offbuf, float* __restrict__ maskbuf,
    float* sw, float* sb)
{
    int rb = xcd_chunked(blockIdx.x, 450);
    int type = rb & 1;
    int chunk = rb >> 1;          // [0,225)
    const int nslot = type ? 12 : 16;

    for (int i = threadIdx.x; i < TAPS_D * nslot; i += 256) {
        int tap = i / nslot, j = i - tap * nslot;
        int o = type ? 16 + j : j;
        float v = 0.0f;
        if (o < 18) v = getv(off_w, (long)o * TAPS_D + tap);
        else if (o < 27) v = getv(mod_w, (long)(o - 18) * TAPS_D + tap);
        sw[tap * nslot + j] = v;
    }
    if (threadIdx.x < nslot) {
        int o = (type ? 16 : 0) + threadIdx.x;
        sb[threadIdx.x] = (o < 18) ? getv(off_b, o)
                        : (o < 27 ? getv(mod_b, o - 18) : 0.0f);
    }
    __syncthreads();

    int og = threadIdx.x >> 6, lane = threadIdx.x & 63;

    // Two 4-px groups per lane: px base p0+4*lane and p0+256+4*lane.
    long pg[2]; pg[0] = (long)chunk * 512 + 4 * lane; pg[1] = pg[0] + 256;
    int bg[2], ppg[2];
    int yo[2][3]; float vm[2][3], mL[2], mR[2];
    const float* xbg[2];
#pragma unroll
    for (int g = 0; g < 2; g++) {
        int b = (int)(pg[g] / HWc);
        int pp = (int)(pg[g] - (long)b * HWc);
        int y = pp / Wc, x = pp - (pp / Wc) * Wc;
        bg[g] = b; ppg[g] = pp;
        xbg[g] = xcat + (long)b * CIN_D * HWc;
#pragma unroll
        for (int ky = 0; ky < 3; ky++) {
            int yy = y + ky - 1;
            vm[g][ky] = (yy >= 0 && yy < Hc) ? 1.0f : 0.0f;
            yo[g][ky] = min(max(yy, 0), Hc - 1) * Wc + x;
        }
        mL[g] = (x > 0) ? 1.0f : 0.0f;
        mR[g] = (x + 4 < Wc) ? 1.0f : 0.0f;
    }
    // Edge element offsets (cin=0 addresses; advanced by cin*HWc per iter).
    const float *eLp[3], *eRp[3];
    {
        long pL = (long)chunk * 512;
        int b = (int)(pL / HWc); int pp = (int)(pL - (long)b * HWc);
        int y = pp / Wc, x = pp - (pp / Wc) * Wc;
#pragma unroll
        for (int ky = 0; ky < 3; ky++)
            eLp[ky] = xcat + (long)b * CIN_D * HWc
                    + (long)min(max(y + ky - 1, 0), Hc - 1) * Wc + x - 1;
        long pR = (long)chunk * 512 + 511;
        b = (int)(pR / HWc); pp = (int)(pR - (long)b * HWc);
        y = pp / Wc; x = pp - (pp / Wc) * Wc;
#pragma unroll
        for (int ky = 0; ky < 3; ky++)
            eRp[ky] = xcat + (long)b * CIN_D * HWc
                    + (long)min(max(y + ky - 1, 0), Hc - 1) * Wc + x + 1;
    }

    const int per = type ? 3 : 4;
    int jbase = og * per;
    const int upl = (lane + 63) & 63, dnl = (lane + 1) & 63;

    float acc[4][2][4];
#pragma unroll
    for (int j = 0; j < 4; j++) {
        float bv = (j < per) ? sb[jbase + j] : 0.0f;
#pragma unroll
        for (int g = 0; g < 2; g++)
#pragma unroll
            for (int px = 0; px < 4; px++) acc[j][g][px] = bv;
    }

#pragma unroll 1
    for (int cin = 0; cin < CIN_D; cin++) {
        const long coff = (long)cin * HWc;
        const float* c0 = xbg[0] + coff;
        const float* c1 = xbg[1] + coff;
        f32x4 A[3], B[3]; float el[3], er[3];
        om13_issue(c0 + yo[0][0], c0 + yo[0][1], c0 + yo[0][2],
                   c1 + yo[1][0], c1 + yo[1][1], c1 + yo[1][2],
                   eLp[0] + coff, eLp[1] + coff, eLp[2] + coff,
                   eRp[0] + coff, eRp[1] + coff, eRp[2] + coff,
                   A[0], A[1], A[2], B[0], B[1], B[2],
                   el[0], el[1], el[2], er[0], er[1], er[2]);
        // stage weights during vmem latency
        float4 wr4[9]; float3 wr3[9];
        if (type == 0) {
#pragma unroll
            for (int t9 = 0; t9 < 9; t9++)
                wr4[t9] = *(const float4*)&sw[(cin * 9 + t9) * 16 + jbase];
        } else {
#pragma unroll
            for (int t9 = 0; t9 < 9; t9++) {
                const float* wp = &sw[(cin * 9 + t9) * 12 + jbase];
                wr3[t9] = make_float3(wp[0], wp[1], wp[2]);
            }
        }
        om_wait();

        float xs0[3][6], xs1[3][6];
#pragma unroll
        for (int ky = 0; ky < 3; ky++) {
            float aw = A[ky].w, ax = A[ky].x, bw = B[ky].w, bx = B[ky].x;
            float sAw = __shfl(aw, upl);
            float sAx = __shfl(ax, dnl);
            float sBw = __shfl(bw, upl);
            float sBx = __shfl(bx, dnl);
            float B0x = __shfl(bx, 0);
            float A63w = __shfl(aw, 63);
            float g0l = (lane == 0) ? el[ky] : sAw;
            float g0r = (lane == 63) ? B0x : sAx;
            float g1l = (lane == 0) ? A63w : sBw;
            float g1r = (lane == 63) ? er[ky] : sBx;
            float v0 = vm[0][ky], v1 = vm[1][ky];
            xs0[ky][0] = g0l * v0 * mL[0];
            xs0[ky][1] = A[ky].x * v0; xs0[ky][2] = A[ky].y * v0;
            xs0[ky][3] = A[ky].z * v0; xs0[ky][4] = A[ky].w * v0;
            xs0[ky][5] = g0r * v0 * mR[0];
            xs1[ky][0] = g1l * v1 * mL[1];
            xs1[ky][1] = B[ky].x * v1; xs1[ky][2] = B[ky].y * v1;
            xs1[ky][3] = B[ky].z * v1; xs1[ky][4] = B[ky].w * v1;
            xs1[ky][5] = g1r * v1 * mR[1];
        }

        if (type == 0) {
#pragma unroll
            for (int ky = 0; ky < 3; ky++) {
#pragma unroll
                for (int kx = 0; kx < 3; kx++) {
                    const float4 wq = wr4[ky * 3 + kx];
#pragma unroll
                    for (int px = 0; px < 4; px++) {
                        float u = xs0[ky][px + kx];
                        acc[0][0][px] += wq.x * u;
                        acc[1][0][px] += wq.y * u;
                        acc[2][0][px] += wq.z * u;
                        acc[3][0][px] += wq.w * u;
                        float w2 = xs1[ky][px + kx];
                        acc[0][1][px] += wq.x * w2;
                        acc[1][1][px] += wq.y * w2;
                        acc[2][1][px] += wq.z * w2;
                        acc[3][1][px] += wq.w * w2;
                    }
                }
            }
        } else {
#pragma unroll
            for (int ky = 0; ky < 3; ky++) {
#pragma unroll
                for (int kx = 0; kx < 3; kx++) {
                    const float3 wq = wr3[ky * 3 + kx];
#pragma unroll
                    for (int px = 0; px < 4; px++) {
                        float u = xs0[ky][px + kx];
                        acc[0][0][px] += wq.x * u;
                        acc[1][0][px] += wq.y * u;
                        acc[2][0][px] += wq.z * u;
                        float w2 = xs1[ky][px + kx];
                        acc[0][1][px] += wq.x * w2;
                        acc[1][1][px] += wq.y * w2;
                        acc[2][1][px] += wq.z * w2;
                    }
                }
            }
        }
    }

#pragma unroll
    for (int j = 0; j < 4; j++) {
        if (j >= per) break;
        int o = (type ? 16 : 0) + jbase + j;
        if (o >= 27) break;
        if (o < 18) {
#pragma unroll
            for (int g = 0; g < 2; g++) {
                float* dst = offbuf + ((long)bg[g] * 18 + o) * HWc + ppg[g];
                *(float4*)dst = make_float4(acc[j][g][0], acc[j][g][1],
                                            acc[j][g][2], acc[j][g][3]);
            }
        } else {
#pragma unroll
            for (int g = 0; g < 2; g++) {
                float* dst = maskbuf + ((long)bg[g] * 9 + (o - 18)) * HWc + ppg[g];
                *(float4*)dst = make_float4(
                    2.0f * sigm(acc[j][g][0]), 2.0f * sigm(acc[j][g][1]),
                    2.0f * sigm(acc[j][g][2]), 2.0f * sigm(acc[j][g][3]));
            }
        }
    }
}

__global__ void __launch_bounds__(256) k_offmod(
    const float* xcat, const void* off_w, const void* off_b,
    const void* mod_w, const void* mod_b, const int* __restrict__ flag,
    float* offbuf, float* maskbuf)
{
    __shared__ float sw[TAPS_D * 16];  // 36.9 KB (type A); type B uses 27.6 KB
    __shared__ float sb[16];
    if (flag[0])
        offmod13_body<bf16>(xcat, (const bf16*)off_w, (const bf16*)off_b,
                            (const bf16*)mod_w, (const bf16*)mod_b, offbuf, maskbuf, sw, sb);
    else
        offmod13_body<float>(xcat, (const float*)off_w, (const float*)off_b,
                             (const float*)mod_w, (const float*)mod_b, offbuf, maskbuf, sw, sb);
}

// ---------------------------------------------------------------------------
// deform v5 (R23 proven: paired-corner dwordx2 gathers). Unchanged.
// ---------------------------------------------------------------------------
template <typename T>
__device__ __forceinline__ void deform5_body(
    const float* __restrict__ xcat, const float* __restrict__ offbuf,
    const float* __restrict__ maskbuf,
    const T* __restrict__ def_w, const T* __restrict__ def_b,
    float* __restrict__ dcout, float* sw, float* sb)
{
    for (int i = threadIdx.x; i < NKc * TAPS_D; i += 256) {
        int co = i / TAPS_D;
        int tap = i - co * TAPS_D;
        sw[tap * NKc + co] = getv(def_w, i);
    }
    if (threadIdx.x < NKc) sb[threadIdx.x] = getv(def_b, threadIdx.x);
    __syncthreads();

    int blk = xcd_chunked(blockIdx.x, NPIX / 256);
    int idx0 = blk * 256;            // block-uniform
    int b = idx0 / HWc;              // uniform -> SGPR
    int p = idx0 - b * HWc + threadIdx.x;
    int y = p / Wc, x = p - (p / Wc) * Wc;

    float w00[9], w01[9], w10[9], w11[9];
    int o0[9], o1[9];
    float sel[9];
#pragma unroll
    for (int k = 0; k < 9; k++) {
        int ky = k / 3, kx = k - (k / 3) * 3;
        float dy = offbuf[((long)b * 18 + 2 * k) * HWc + p];
        float dx = offbuf[((long)b * 18 + 2 * k + 1) * HWc + p];
        float m = maskbuf[((long)b * 9 + k) * HWc + p];
        float py = (float)(y - 1 + ky) + dy;
        float px = (float)(x - 1 + kx) + dx;
        float y0f = floorf(py), x0f = floorf(px);
        int y0 = (int)y0f, x0 = (int)x0f;
        float wy1 = py - y0f, wx1 = px - x0f;
        float a00 = (1.0f - wy1) * (1.0f - wx1) * m;
        float a01 = (1.0f - wy1) * wx1 * m;
        float a10 = wy1 * (1.0f - wx1) * m;
        float a11 = wy1 * wx1 * m;
        bool vy0 = (y0 >= 0) && (y0 < Hc);
        bool vy1 = (y0 + 1 >= 0) && (y0 + 1 < Hc);
        bool vx0 = (x0 >= 0) && (x0 < Wc);
        bool vx1 = (x0 + 1 >= 0) && (x0 + 1 < Wc);
        w00[k] = (vy0 && vx0) ? a00 : 0.0f;
        w01[k] = (vy0 && vx1) ? a01 : 0.0f;
        w10[k] = (vy1 && vx0) ? a10 : 0.0f;
        w11[k] = (vy1 && vx1) ? a11 : 0.0f;
        int yc0 = min(max(y0, 0), Hc - 1);
        int yc1 = min(max(y0 + 1, 0), Hc - 1);
        int xc0 = min(max(x0, 0), Wc - 1);
        int xc1 = min(max(x0 + 1, 0), Wc - 1);
        o0[k] = (yc0 * Wc + xc0) * 4;
        o1[k] = (yc1 * Wc + xc0) * 4;
        sel[k] = (xc1 > xc0) ? 1.0f : 0.0f;
    }

    float acc[NKc];
#pragma unroll
    for (int i = 0; i < NKc; i++) acc[i] = sb[i];

    const float* xb = xcat + (long)b * CIN_D * HWc;
#pragma unroll 1
    for (int cin = 0; cin < CIN_D; cin++) {
        const float* xc = xb + (long)cin * HWc;
        f32x2 u0[9], u1[9];
        dfm_issue9w(xc, o0, u0);
        dfm_issue9w(xc, o1, u1);
        om_wait();
        float s[9];
#pragma unroll
        for (int k = 0; k < 9; k++) {
            float v01 = u0[k].x + sel[k] * (u0[k].y - u0[k].x);
            float v11 = u1[k].x + sel[k] * (u1[k].y - u1[k].x);
            s[k] = w00[k] * u0[k].x + w01[k] * v01 +
                   w10[k] * u1[k].x + w11[k] * v11;
        }
#pragma unroll
        for (int k = 0; k < 9; k++) {
            const float* wrow = &sw[(cin * 9 + k) * NKc];
#pragma unroll
            for (int co = 0; co < NKc; co++) acc[co] += wrow[co] * s[k];
        }
    }

#pragma unroll
    for (int co = 0; co < NKc; co++)
        dcout[((long)b * NKc + co) * HWc + p] = acc[co];
}

__global__ void __launch_bounds__(256) k_deform(
    const float* xcat, const float* offbuf, const float* maskbuf,
    const void* def_w, const void* def_b, const int* __restrict__ flag,
    float* dcout)
{
    __shared__ float sw[TAPS_D * NKc];  // 36.9 KB
    __shared__ float sb[NKc];
    if (flag[0])
        deform5_body<bf16>(xcat, offbuf, maskbuf, (const bf16*)def_w, (const bf16*)def_b,
                           dcout, sw, sb);
    else
        deform5_body<float>(xcat, offbuf, maskbuf, (const float*)def_w, (const float*)def_b,
                            dcout, sw, sb);
}

// ---------------------------------------------------------------------------
// outconv v8 (R19 proven form). Unchanged.
// ---------------------------------------------------------------------------
template <typename T>
__device__ __forceinline__ void outconv6_body(
    const float* __restrict__ dcout, const T* __restrict__ out_w,
    const T* __restrict__ out_b, T* __restrict__ out, float* sw, float* sb)
{
    int rb = xcd_chunked(blockIdx.x, 900);
    int type = rb & 1;
    int chunk = rb >> 1;

    for (int i = threadIdx.x; i < 24 * TAPS_O; i += 256) {
        int o = i / TAPS_O, tap = i - o * TAPS_O;
        int slot = (o / 6) * 8 + (o % 6);
        sw[tap * 32 + slot] = getv(out_w, (long)(type * 24 + o) * TAPS_O + tap);
    }
    if (threadIdx.x < 24) sb[threadIdx.x] = getv(out_b, type * 24 + threadIdx.x);
    __syncthreads();

    int og = threadIdx.x >> 6, lane = threadIdx.x & 63;
    long p0 = ((long)chunk * 64 + lane) * 4;
    int b = (int)(p0 / HWc);
    int p = (int)(p0 - (long)b * HWc);
    int y = p / Wc, x0 = p - (p / Wc) * Wc;

    float acc[6][4];
#pragma unroll
    for (int j = 0; j < 6; j++) {
        float bv = sb[og * 6 + j];
#pragma unroll
        for (int px = 0; px < 4; px++) acc[j][px] = bv;
    }

    const float* xb = dcout + (long)b * NKc * HWc;
#pragma unroll 1
    for (int cin = 0; cin < NKc; cin++) {
        const float* xc = xb + (long)cin * HWc;
        float xs[3][6];
#pragma unroll
        for (int ky = 0; ky < 3; ky++) {
            int yy = y + ky - 1;
            if (yy >= 0 && yy < Hc) {
                const float* row = xc + (long)yy * Wc;
                xs[ky][0] = (x0 > 0) ? row[x0 - 1] : 0.0f;
                load4(row, x0, &xs[ky][1]);
                xs[ky][5] = (x0 + 4 < Wc) ? row[x0 + 4] : 0.0f;
            } else {
#pragma unroll
                for (int j = 0; j < 6; j++) xs[ky][j] = 0.0f;
            }
        }
        float4 wa[9]; float2 wb[9];
#pragma unroll
        for (int t9 = 0; t9 < 9; t9++) {
            const float* wp = &sw[(cin * 9 + t9) * 32 + og * 8];
            wa[t9] = *(const float4*)wp;
            wb[t9] = *(const float2*)(wp + 4);
        }
#pragma unroll
        for (int ky = 0; ky < 3; ky++) {
#pragma unroll
            for (int kx = 0; kx < 3; kx++) {
                const float4 w0 = wa[ky * 3 + kx];
                const float2 w1 = wb[ky * 3 + kx];
#pragma unroll
                for (int px = 0; px < 4; px++) {
                    float v = xs[ky][px + kx];
                    acc[0][px] += w0.x * v;  acc[1][px] += w0.y * v;
                    acc[2][px] += w0.z * v;  acc[3][px] += w0.w * v;
                    acc[4][px] += w1.x * v;  acc[5][px] += w1.y * v;
                }
            }
        }
    }

#pragma unroll
    for (int j = 0; j < 6; j++) {
        int co = type * 24 + og * 6 + j;
        int cc = co >> 4;
        int r = co & 15;
        int ii = r >> 2, jj = r & 3;
        long ob = (((long)b * 3 + cc) * (Hc * 4) + (y * 4 + ii)) * (long)(Wc * 4);
#pragma unroll
        for (int px = 0; px < 4; px++) {
            float v = fminf(fmaxf(acc[j][px], 0.0f), 255.0f);
            putv(out, ob + (x0 + px) * 4 + jj, v);
        }
    }
}

__global__ void __launch_bounds__(256) k_outconv(
    const float* dcout, const void* out_w, const void* out_b,
    const int* __restrict__ flag, void* out)
{
    __shared__ float sw[TAPS_O * 32];  // 18.4 KB
    __shared__ float sb[24];
    if (flag[0])
        outconv6_body<bf16>(dcout, (const bf16*)out_w, (const bf16*)out_b, (bf16*)out, sw, sb);
    else
        outconv6_body<float>(dcout, (const float*)out_w, (const float*)out_b, (float*)out, sw, sb);
}

extern "C" void kernel_launch(void* const* d_in, const int* in_sizes, int n_in,
                              void* d_out, int out_size, void* d_ws, size_t ws_size,
                              hipStream_t stream) {
    const void* X      = d_in[0];
    const void* lstm_w = d_in[1];
    const void* lstm_b = d_in[2];
    const void* Wci    = d_in[3];
    const void* Wcf    = d_in[4];
    const void* Wco    = d_in[5];
    const void* off_w  = d_in[6];
    const void* off_b  = d_in[7];
    const void* mod_w  = d_in[8];
    const void* mod_b  = d_in[9];
    const void* def_w  = d_in[10];
    const void* def_b  = d_in[11];
    const void* out_w  = d_in[12];
    const void* out_b  = d_in[13];

    int* flag = (int*)d_ws;
    float* W = (float*)d_ws + 64;
    size_t o = 0;
    float* c_buf   = W + o; o += (size_t)Bn * NKc * HWc;
    float* xcat    = W + o; o += (size_t)Bn * CIN_D * HWc;
    float* offbuf  = W + o; o += (size_t)Bn * 18 * HWc;
    float* maskbuf = W + o; o += (size_t)Bn * 9 * HWc;
    float* dcout   = W + o; o += (size_t)Bn * NKc * HWc;

    dim3 blk(256);
    dim3 gridP(NPIX / 256);           // 450
    dim3 gridL2(Bn * (Hc / 2) * 5);   // 900: 2-row lstm blocks
    dim3 gridOM(2 * (NPIX / 512));    // 450: offmod, 2x4px groups/lane
    dim3 gridC2(2 * (NPIX / 4 / 64)); // 900

    k_detect<<<1, blk, 0, stream>>>(lstm_w, flag);
    for (int t = 0; t < Tn; t++) {
        k_lstm2<<<gridL2, blk, 0, stream>>>(X, lstm_w, lstm_b, Wci, Wcf, Wco,
                                            flag, c_buf, xcat, t);
    }
    k_offmod<<<gridOM, blk, 0, stream>>>(xcat, off_w, off_b, mod_w, mod_b, flag,
                                         offbuf, maskbuf);
    k_deform<<<gridP, blk, 0, stream>>>(xcat, offbuf, maskbuf, def_w, def_b, flag, dcout);
    k_outconv<<<gridC2, blk, 0, stream>>>(dcout, out_w, out_b, flag, d_out);
}